// Round 1
// baseline (5070.193 us; speedup 1.0000x reference)
//
#include <hip/hip_runtime.h>
#include <hip/hip_bf16.h>
#include <math.h>

// Dims (fixed by the reference): B=8, S=512, H=1024, NH=16, DK=64, FF=4096.
// All f32 this round: correctness-first baseline. GEMMs move to bf16 MFMA next.

#define BDIM 256

// ---------------------------------------------------------------------------
// LayerNorm over last dim (1024). One block per row.
// ---------------------------------------------------------------------------
__global__ __launch_bounds__(256) void ln_rows(const float* __restrict__ X,
                                               const float* __restrict__ G,
                                               const float* __restrict__ Bt,
                                               float* __restrict__ O) {
  long row = blockIdx.x;
  int t = threadIdx.x;
  const float4 xv = ((const float4*)(X + row * 1024))[t];
  float s = xv.x + xv.y + xv.z + xv.w;
  float q = xv.x * xv.x + xv.y * xv.y + xv.z * xv.z + xv.w * xv.w;
#pragma unroll
  for (int o = 32; o; o >>= 1) {
    s += __shfl_xor(s, o);
    q += __shfl_xor(q, o);
  }
  __shared__ float rs[4], rq[4];
  int wid = t >> 6;
  if ((t & 63) == 0) { rs[wid] = s; rq[wid] = q; }
  __syncthreads();
  s = rs[0] + rs[1] + rs[2] + rs[3];
  q = rq[0] + rq[1] + rq[2] + rq[3];
  float mean = s * (1.f / 1024.f);
  float var = q * (1.f / 1024.f) - mean * mean;
  float rstd = rsqrtf(var + 1e-5f);
  const float4 gv = ((const float4*)G)[t];
  const float4 bv = ((const float4*)Bt)[t];
  float4 o;
  o.x = (xv.x - mean) * rstd * gv.x + bv.x;
  o.y = (xv.y - mean) * rstd * gv.y + bv.y;
  o.z = (xv.z - mean) * rstd * gv.z + bv.z;
  o.w = (xv.w - mean) * rstd * gv.w + bv.w;
  ((float4*)(O + row * 1024))[t] = o;
}

// ---------------------------------------------------------------------------
// Tiled f32 GEMM: C = alpha*(A@B + bias) + E1 + E2, optional exact GELU.
// TRANSB=0: B is [K,N] (ldb). TRANSB=1: B is [N,K] (ldb) -> C = A @ B^T.
// Batched via blockIdx.z with strides sA/sB/sC/sE. E matrices share ldc.
// 256 threads = 16x16, micro-tile (BM/16)x(BN/16). BK=16. LDS padded +1.
// ---------------------------------------------------------------------------
template <int BMt, int BNt, int TRANSB>
__global__ __launch_bounds__(256) void gemm_f32(
    const float* __restrict__ A, const float* __restrict__ B,
    const float* __restrict__ bias, const float* __restrict__ E1,
    const float* __restrict__ E2, float* __restrict__ C, int M, int N, int K,
    int lda, int ldb, int ldc, long sA, long sB, long sC, long sE, float alpha,
    int act) {
  constexpr int MR = BMt / 16, NR = BNt / 16;
  __shared__ float As[16][BMt + 1];
  __shared__ float Bs[16][BNt + 1];
  int bz = blockIdx.z;
  const float* Ab = A + (long)bz * sA;
  const float* Bb = B + (long)bz * sB;
  float* Cb = C + (long)bz * sC;
  int m0 = blockIdx.y * BMt, n0 = blockIdx.x * BNt;
  int tid = threadIdx.x, tx = tid & 15, ty = tid >> 4;
  float acc[MR][NR];
#pragma unroll
  for (int r = 0; r < MR; ++r)
#pragma unroll
    for (int i = 0; i < NR; ++i) acc[r][i] = 0.f;

  for (int k0 = 0; k0 < K; k0 += 16) {
#pragma unroll
    for (int idx = tid; idx < BMt * 16; idx += 256) {
      int m = idx >> 4, kk = idx & 15;
      As[kk][m] = Ab[(long)(m0 + m) * lda + k0 + kk];
    }
    if (TRANSB) {
#pragma unroll
      for (int idx = tid; idx < BNt * 16; idx += 256) {
        int n = idx >> 4, kk = idx & 15;
        Bs[kk][n] = Bb[(long)(n0 + n) * ldb + k0 + kk];
      }
    } else {
#pragma unroll
      for (int idx = tid; idx < BNt * 16; idx += 256) {
        int n = idx % BNt, kk = idx / BNt;
        Bs[kk][n] = Bb[(long)(k0 + kk) * ldb + n0 + n];
      }
    }
    __syncthreads();
#pragma unroll
    for (int kk = 0; kk < 16; ++kk) {
      float a[MR], bb[NR];
#pragma unroll
      for (int r = 0; r < MR; ++r) a[r] = As[kk][ty + 16 * r];
#pragma unroll
      for (int i = 0; i < NR; ++i) bb[i] = Bs[kk][tx + 16 * i];
#pragma unroll
      for (int r = 0; r < MR; ++r)
#pragma unroll
        for (int i = 0; i < NR; ++i) acc[r][i] += a[r] * bb[i];
    }
    __syncthreads();
  }

#pragma unroll
  for (int r = 0; r < MR; ++r) {
    int m = m0 + ty + 16 * r;
#pragma unroll
    for (int i = 0; i < NR; ++i) {
      int n = n0 + tx + 16 * i;
      float v = acc[r][i];
      if (bias) v += bias[n];
      v *= alpha;
      if (E1) v += E1[(long)bz * sE + (long)m * ldc + n];
      if (E2) v += E2[(long)bz * sE + (long)m * ldc + n];
      if (act == 1) v = v * 0.5f * (1.f + erff(v * 0.70710678118f));
      Cb[(long)m * ldc + n] = v;
    }
  }
}

// ---------------------------------------------------------------------------
// Fused MHA: per block = (b, h, 16 query rows). K/V staged in LDS (64-row
// tiles, pad 65), scores [16][512] in LDS (stride 516), in-block softmax.
// Q already scaled by DK^-0.5 at projection time.
// ---------------------------------------------------------------------------
__global__ __launch_bounds__(256) void attn_fused(
    const float* __restrict__ Q, const float* __restrict__ Km,
    const float* __restrict__ V, const float* __restrict__ bias1,
    const float* __restrict__ mask1, float* __restrict__ O) {
  __shared__ float qs[16][64];
  __shared__ float sc[16][516];
  __shared__ float kv[64][65];
  const int it = blockIdx.x, h = blockIdx.y, b = blockIdx.z;
  const int i0 = it * 16;
  const int tid = threadIdx.x;

  // load Q rows
  for (int idx = tid; idx < 1024; idx += 256) {
    int r = idx >> 6, d = idx & 63;
    qs[r][d] = Q[(long)((b * 512 + i0 + r)) * 1024 + h * 64 + d];
  }

  // scores
  for (int jt = 0; jt < 8; ++jt) {
    int j0 = jt * 64;
    __syncthreads();
    for (int idx = tid; idx < 4096; idx += 256) {
      int jj = idx >> 6, d = idx & 63;
      kv[jj][d] = Km[(long)((b * 512 + j0 + jj)) * 1024 + h * 64 + d];
    }
    __syncthreads();
#pragma unroll
    for (int w = 0; w < 4; ++w) {
      int flat = tid + 256 * w;
      int r = flat >> 6, jj = flat & 63;
      float acc = 0.f;
#pragma unroll
      for (int d = 0; d < 64; ++d) acc += qs[r][d] * kv[jj][d];
      int j = j0 + jj;
      long gi = (long)(b * 512 + i0 + r) * 512 + j;
      acc += bias1[gi] + mask1[gi];
      sc[r][j] = acc;
    }
  }
  __syncthreads();

  // softmax over 512 per row; 16 threads per row
  {
    int r = tid >> 4, c = tid & 15;
    float mx = -3.0e38f;
    for (int j = c; j < 512; j += 16) mx = fmaxf(mx, sc[r][j]);
#pragma unroll
    for (int o = 8; o; o >>= 1) mx = fmaxf(mx, __shfl_xor(mx, o));
    float sum = 0.f;
    for (int j = c; j < 512; j += 16) {
      float e = __expf(sc[r][j] - mx);
      sc[r][j] = e;
      sum += e;
    }
#pragma unroll
    for (int o = 8; o; o >>= 1) sum += __shfl_xor(sum, o);
    float inv = 1.f / sum;
    for (int j = c; j < 512; j += 16) sc[r][j] *= inv;
  }

  // PV
  float acc[4] = {0.f, 0.f, 0.f, 0.f};
  int r = tid >> 4, dd = tid & 15;
  for (int jt = 0; jt < 8; ++jt) {
    int j0 = jt * 64;
    __syncthreads();
    for (int idx = tid; idx < 4096; idx += 256) {
      int jj = idx >> 6, d = idx & 63;
      kv[jj][d] = V[(long)((b * 512 + j0 + jj)) * 1024 + h * 64 + d];
    }
    __syncthreads();
    for (int jj = 0; jj < 64; ++jj) {
      float s = sc[r][j0 + jj];
#pragma unroll
      for (int i = 0; i < 4; ++i) acc[i] += s * kv[jj][dd + 16 * i];
    }
  }
#pragma unroll
  for (int i = 0; i < 4; ++i)
    O[(long)(b * 512 + i0 + r) * 1024 + h * 64 + dd + 16 * i] = acc[i];
}

// ---------------------------------------------------------------------------
// Row softmax for path attention: one block per row of 512.
// ---------------------------------------------------------------------------
__global__ __launch_bounds__(256) void softmax_rows(float* __restrict__ P) {
  float* row = P + (long)blockIdx.x * 512;
  int t = threadIdx.x;
  float v0 = row[t], v1 = row[t + 256];
  float m = fmaxf(v0, v1);
#pragma unroll
  for (int o = 32; o; o >>= 1) m = fmaxf(m, __shfl_xor(m, o));
  __shared__ float red[8];
  int wid = t >> 6, lane = t & 63;
  if (!lane) red[wid] = m;
  __syncthreads();
  m = fmaxf(fmaxf(red[0], red[1]), fmaxf(red[2], red[3]));
  float e0 = __expf(v0 - m), e1 = __expf(v1 - m);
  float s = e0 + e1;
#pragma unroll
  for (int o = 32; o; o >>= 1) s += __shfl_xor(s, o);
  if (!lane) red[4 + wid] = s;
  __syncthreads();
  s = red[4] + red[5] + red[6] + red[7];
  float inv = 1.f / s;
  row[t] = e0 * inv;
  row[t + 256] = e1 * inv;
}

// ---------------------------------------------------------------------------
// Gather-mean over predicate positions -> path[b, h].
// grid (8, 4) x 256 threads; thread owns one h channel.
// ---------------------------------------------------------------------------
__global__ __launch_bounds__(256) void path_mean(const float* __restrict__ xp,
                                                 const int* __restrict__ pp,
                                                 float* __restrict__ path) {
  int b = blockIdx.x;
  int h = blockIdx.y * 256 + threadIdx.x;
  const int* ppb = pp + b * 512;
  const float* xb = xp + (long)b * 512 * 1024;
  float wsum = 0.f;
  for (int i = 0; i < 512; ++i) wsum += (ppb[i] == 1) ? 1.f : 0.f;
  float acc = 0.f;
  for (int i = 0; i < 512; ++i) {
    if (ppb[i] != 1) continue;  // uniform across block (same b)
    float cur = xb[(long)i * 1024 + h];
    float a;
    if (i == 0) {
      a = 0.5f * (cur + xb[1024 + h]);
    } else if (i == 1) {
      a = (xb[h] + cur + xb[2 * 1024 + h]) * (1.f / 3.f);
    } else {
      int inx = (i + 1 < 512) ? i + 1 : 511;
      float nx = xb[(long)inx * 1024 + h];
      if (ppb[i - 2] == 1) {
        a = 0.5f * (cur + nx);
      } else {
        float pv = xb[(long)(i - 1) * 1024 + h];
        a = (pv + cur + nx) * (1.f / 3.f);
      }
    }
    acc += a;
  }
  path[b * 1024 + h] = acc / wsum;
}

// ---------------------------------------------------------------------------
// x2 = x + 0.5*(y_self + path[b,:])  (float4 per thread)
// ---------------------------------------------------------------------------
__global__ __launch_bounds__(256) void combine(const float* __restrict__ X,
                                               const float* __restrict__ YS,
                                               const float* __restrict__ PT,
                                               float* __restrict__ X2) {
  int i = blockIdx.x * 256 + threadIdx.x;  // float4 index; total 1048576
  const float4 xv = ((const float4*)X)[i];
  const float4 sv = ((const float4*)YS)[i];
  int e = i * 4;
  int b = e >> 19;       // / (512*1024)
  int h = e & 1023;
  const float4 pv = *(const float4*)(PT + b * 1024 + h);
  float4 o;
  o.x = xv.x + 0.5f * (sv.x + pv.x);
  o.y = xv.y + 0.5f * (sv.y + pv.y);
  o.z = xv.z + 0.5f * (sv.z + pv.z);
  o.w = xv.w + 0.5f * (sv.w + pv.w);
  ((float4*)X2)[i] = o;
}

// ---------------------------------------------------------------------------
extern "C" void kernel_launch(void* const* d_in, const int* in_sizes, int n_in,
                              void* d_out, int out_size, void* d_ws,
                              size_t ws_size, hipStream_t stream) {
  const float* x = (const float*)d_in[0];
  const int* pp = (const int*)d_in[1];
  // d_in[2] = variable_tags (unused)
  const float* abias = (const float*)d_in[3];
  const float* amask = (const float*)d_in[4];
  const float* agraph = (const float*)d_in[5];
  const float* vgraph = (const float*)d_in[6];
  const float* ln1g = (const float*)d_in[7];
  const float* ln1b = (const float*)d_in[8];
  const float* wq = (const float*)d_in[9];
  const float* bq = (const float*)d_in[10];
  const float* wk = (const float*)d_in[11];
  const float* bk = (const float*)d_in[12];
  const float* wv = (const float*)d_in[13];
  const float* bv = (const float*)d_in[14];
  const float* wo = (const float*)d_in[15];
  const float* bo = (const float*)d_in[16];
  const float* pqw = (const float*)d_in[17];
  const float* pqb = (const float*)d_in[18];
  const float* pkw = (const float*)d_in[19];
  const float* pkb = (const float*)d_in[20];
  const float* pvw = (const float*)d_in[21];
  const float* pvb = (const float*)d_in[22];
  const float* ln2g = (const float*)d_in[23];
  const float* ln2b = (const float*)d_in[24];
  const float* w1 = (const float*)d_in[25];
  const float* b1 = (const float*)d_in[26];
  const float* w2 = (const float*)d_in[27];
  const float* b2 = (const float*)d_in[28];

  float* ws = (float*)d_ws;
  const long MH = 4194304;  // 4096*1024
  float* Y = ws;            // also X2 later
  float* Qb = ws + MH;      // HMID later spans Qb..PQ (16M floats)
  float* Kb = ws + 2 * MH;
  float* Vb = ws + 3 * MH;
  float* PQ = ws + 4 * MH;
  float* PK = ws + 5 * MH;  // Y2 later
  float* PV = ws + 6 * MH;
  float* ATT = ws + 7 * MH;
  float* PATT = ws + 8 * MH;                   // 2,097,152
  float* XP = ws + 8 * MH + 2097152;           // 4M
  float* PATH = ws + 9 * MH + 2097152;         // 8192
  float* YSELF = ws + 9 * MH + 2105344;        // 4M ; total 44,048,384 f32 = 168MB
  float* X2 = Y;
  float* Y2 = PK;
  float* HMID = Qb;
  float* OUT = (float*)d_out;

  const float qscale = 0.125f;    // DK^-0.5
  const float pscale = 0.03125f;  // H^-0.5

  // 1) LN1: x -> Y
  ln_rows<<<dim3(4096), dim3(256), 0, stream>>>(x, ln1g, ln1b, Y);

  // 2) projections  (grid: N/128, M/128)
  gemm_f32<128, 128, 0><<<dim3(8, 32, 1), dim3(256), 0, stream>>>(
      Y, wq, bq, nullptr, nullptr, Qb, 4096, 1024, 1024, 1024, 1024, 1024, 0,
      0, 0, 0, qscale, 0);
  gemm_f32<128, 128, 0><<<dim3(8, 32, 1), dim3(256), 0, stream>>>(
      Y, wk, bk, nullptr, nullptr, Kb, 4096, 1024, 1024, 1024, 1024, 1024, 0,
      0, 0, 0, 1.f, 0);
  gemm_f32<128, 128, 0><<<dim3(8, 32, 1), dim3(256), 0, stream>>>(
      Y, wv, bv, nullptr, nullptr, Vb, 4096, 1024, 1024, 1024, 1024, 1024, 0,
      0, 0, 0, 1.f, 0);
  gemm_f32<128, 128, 0><<<dim3(8, 32, 1), dim3(256), 0, stream>>>(
      Y, pqw, pqb, nullptr, nullptr, PQ, 4096, 1024, 1024, 1024, 1024, 1024, 0,
      0, 0, 0, pscale, 0);
  gemm_f32<128, 128, 0><<<dim3(8, 32, 1), dim3(256), 0, stream>>>(
      Y, pkw, pkb, nullptr, nullptr, PK, 4096, 1024, 1024, 1024, 1024, 1024, 0,
      0, 0, 0, 1.f, 0);
  gemm_f32<128, 128, 0><<<dim3(8, 32, 1), dim3(256), 0, stream>>>(
      Y, pvw, pvb, nullptr, nullptr, PV, 4096, 1024, 1024, 1024, 1024, 1024, 0,
      0, 0, 0, 1.f, 0);

  // 3) fused MHA: Q,K,V -> ATT
  attn_fused<<<dim3(32, 16, 8), dim3(256), 0, stream>>>(Qb, Kb, Vb, abias,
                                                        amask, ATT);

  // 4) path attention scores: PATT = PQ @ PK^T + atom_graph + variable_graph
  gemm_f32<64, 64, 1><<<dim3(8, 8, 8), dim3(256), 0, stream>>>(
      PQ, PK, nullptr, agraph, vgraph, PATT, 512, 512, 1024, 1024, 1024, 512,
      524288, 524288, 262144, 262144, 1.f, 0);
  softmax_rows<<<dim3(4096), dim3(256), 0, stream>>>(PATT);

  // 5) XP = PATT @ PV   (batched)
  gemm_f32<128, 128, 0><<<dim3(8, 4, 8), dim3(256), 0, stream>>>(
      PATT, PV, nullptr, nullptr, nullptr, XP, 512, 1024, 512, 512, 1024, 1024,
      262144, 524288, 524288, 0, 1.f, 0);

  // 6) gather-mean -> PATH[b,h]
  path_mean<<<dim3(8, 4), dim3(256), 0, stream>>>(XP, pp, PATH);

  // 7) y_self = ATT @ wo + bo
  gemm_f32<128, 128, 0><<<dim3(8, 32, 1), dim3(256), 0, stream>>>(
      ATT, wo, bo, nullptr, nullptr, YSELF, 4096, 1024, 1024, 1024, 1024, 1024,
      0, 0, 0, 0, 1.f, 0);

  // 8) X2 = x + 0.5*(YSELF + PATH)   (overwrites Y)
  combine<<<dim3(4096), dim3(256), 0, stream>>>(x, YSELF, PATH, X2);

  // 9) LN2: X2 -> Y2 (@PK)
  ln_rows<<<dim3(4096), dim3(256), 0, stream>>>(X2, ln2g, ln2b, Y2);

  // 10) FFN1: HMID = gelu(Y2 @ w1 + b1)   (HMID overlays Qb..PQ)
  gemm_f32<128, 128, 0><<<dim3(32, 32, 1), dim3(256), 0, stream>>>(
      Y2, w1, b1, nullptr, nullptr, HMID, 4096, 4096, 1024, 1024, 4096, 4096,
      0, 0, 0, 0, 1.f, 1);

  // 11) FFN2: OUT = HMID @ w2 + b2 + X2
  gemm_f32<128, 128, 0><<<dim3(8, 32, 1), dim3(256), 0, stream>>>(
      HMID, w2, b2, X2, nullptr, OUT, 4096, 1024, 4096, 4096, 1024, 1024, 0, 0,
      0, 0, 1.f, 0);
}

// Round 3
// 1265.249 us; speedup vs baseline: 4.0073x; 4.0073x over previous
//
#include <hip/hip_runtime.h>
#include <hip/hip_bf16.h>
#include <math.h>

// B=8, S=512, H=1024, NH=16, DK=64, FF=4096.
// Round 3: same as round 2 (all GEMMs -> bf16 MFMA, m97 structure) with the
// comment-line-continuation bug fixed (trailing backslash ate PKb's decl).

typedef __bf16 bf16x8 __attribute__((ext_vector_type(8)));
typedef float f32x4 __attribute__((ext_vector_type(4)));

__device__ __forceinline__ void async_copy16(void* lds, const void* g) {
  __builtin_amdgcn_global_load_lds(
      (__attribute__((address_space(1))) void*)(void*)g,
      (__attribute__((address_space(3))) void*)lds, 16, 0, 0);
}

// ---------------------------------------------------------------------------
// LayerNorm over last dim (1024) -> bf16. One block (256 thr) per row.
// ---------------------------------------------------------------------------
__global__ __launch_bounds__(256) void ln_rows_bf16(
    const float* __restrict__ X, const float* __restrict__ G,
    const float* __restrict__ Bt, __hip_bfloat16* __restrict__ O) {
  long row = blockIdx.x;
  int t = threadIdx.x;
  const float4 xv = ((const float4*)(X + row * 1024))[t];
  float s = xv.x + xv.y + xv.z + xv.w;
  float q = xv.x * xv.x + xv.y * xv.y + xv.z * xv.z + xv.w * xv.w;
#pragma unroll
  for (int o = 32; o; o >>= 1) {
    s += __shfl_xor(s, o);
    q += __shfl_xor(q, o);
  }
  __shared__ float rs[4], rq[4];
  int wid = t >> 6;
  if ((t & 63) == 0) { rs[wid] = s; rq[wid] = q; }
  __syncthreads();
  s = rs[0] + rs[1] + rs[2] + rs[3];
  q = rq[0] + rq[1] + rq[2] + rq[3];
  float mean = s * (1.f / 1024.f);
  float var = q * (1.f / 1024.f) - mean * mean;
  float rstd = rsqrtf(var + 1e-5f);
  const float4 gv = ((const float4*)G)[t];
  const float4 bv = ((const float4*)Bt)[t];
  __hip_bfloat16* o = O + row * 1024 + t * 4;
  o[0] = __float2bfloat16((xv.x - mean) * rstd * gv.x + bv.x);
  o[1] = __float2bfloat16((xv.y - mean) * rstd * gv.y + bv.y);
  o[2] = __float2bfloat16((xv.z - mean) * rstd * gv.z + bv.z);
  o[3] = __float2bfloat16((xv.w - mean) * rstd * gv.w + bv.w);
}

// ---------------------------------------------------------------------------
// Transpose-convert f32 [R,C] -> bf16 [C,R]. grid (C/32, R/32), 256 thr.
// ---------------------------------------------------------------------------
__global__ __launch_bounds__(256) void tconv_f32_bf16(
    const float* __restrict__ in, __hip_bfloat16* __restrict__ out, int R,
    int C) {
  __shared__ float t[32][33];
  int c0 = blockIdx.x * 32, r0 = blockIdx.y * 32;
  int tid = threadIdx.x;
  int lr = tid >> 3, lc = (tid & 7) * 4;
  const float4 v = *(const float4*)&in[(long)(r0 + lr) * C + c0 + lc];
  t[lr][lc] = v.x; t[lr][lc + 1] = v.y; t[lr][lc + 2] = v.z; t[lr][lc + 3] = v.w;
  __syncthreads();
  int oc = tid >> 3, orr = (tid & 7) * 4;
  __hip_bfloat16* o = &out[(long)(c0 + oc) * R + r0 + orr];
  o[0] = __float2bfloat16(t[orr][oc]);
  o[1] = __float2bfloat16(t[orr + 1][oc]);
  o[2] = __float2bfloat16(t[orr + 2][oc]);
  o[3] = __float2bfloat16(t[orr + 3][oc]);
}

// Batched bf16 [bz][R][C] -> bf16 [bz][C][R]. grid (C/32, R/32, bz).
__global__ __launch_bounds__(256) void tconv_bf16(
    const __hip_bfloat16* __restrict__ in, __hip_bfloat16* __restrict__ out,
    int R, int C) {
  __shared__ __hip_bfloat16 t[32][34];
  long base = (long)blockIdx.z * R * C;
  int c0 = blockIdx.x * 32, r0 = blockIdx.y * 32;
  int tid = threadIdx.x;
  int lr = tid >> 3, lc = (tid & 7) * 4;
  const __hip_bfloat16* ip = &in[base + (long)(r0 + lr) * C + c0 + lc];
  t[lr][lc] = ip[0]; t[lr][lc + 1] = ip[1]; t[lr][lc + 2] = ip[2]; t[lr][lc + 3] = ip[3];
  __syncthreads();
  int oc = tid >> 3, orr = (tid & 7) * 4;
  __hip_bfloat16* o = &out[base + (long)(c0 + oc) * R + r0 + orr];
  o[0] = t[orr][oc];
  o[1] = t[orr + 1][oc];
  o[2] = t[orr + 2][oc];
  o[3] = t[orr + 3][oc];
}

// ---------------------------------------------------------------------------
// bf16 MFMA GEMM (NT): C = alpha*(A@Bt^T + bias) + E1 + E2, opt. exact GELU.
// A [M,K] bf16 (lda), Bt [N,K] bf16 (ldb), C f32 or bf16 [M,N].
// 128x128 tile, BK=32, 256 thr = 4 waves (2x2), each wave 64x64 = 4x4 frags.
// ---------------------------------------------------------------------------
__global__ __launch_bounds__(256) void gemm_bf16_nt(
    const __hip_bfloat16* __restrict__ A, const __hip_bfloat16* __restrict__ Bt,
    const float* __restrict__ bias, const float* __restrict__ E1,
    const float* __restrict__ E2, void* __restrict__ C, int K, int lda,
    int ldb, int ldc, long sA, long sB, long sC, long sE, float alpha, int act,
    int obf) {
  __shared__ unsigned short AsU[128 * 32];
  __shared__ unsigned short BsU[128 * 32];
  const int tid = threadIdx.x;
  const int lane = tid & 63, wave = tid >> 6;
  const int wr = wave >> 1, wc = wave & 1;
  const int m0 = blockIdx.y * 128, n0 = blockIdx.x * 128;
  const int bz = blockIdx.z;
  const char* Ab = (const char*)(A + (long)bz * sA);
  const char* Bb = (const char*)(Bt + (long)bz * sB);

  f32x4 acc[4][4];
#pragma unroll
  for (int m = 0; m < 4; ++m)
#pragma unroll
    for (int n = 0; n < 4; ++n) acc[m][n] = (f32x4){0.f, 0.f, 0.f, 0.f};

  const int srow = tid >> 2;            // 0..63
  const int scol = (tid & 3) * 16;      // byte offset within 64B row
  const int wbase = (tid >> 6) * 1024;  // wave-uniform LDS base

  for (int k0 = 0; k0 < K; k0 += 32) {
#pragma unroll
    for (int i = 0; i < 2; ++i) {
      async_copy16((char*)AsU + i * 4096 + wbase,
                   Ab + ((long)(m0 + i * 64 + srow) * lda + k0) * 2 + scol);
      async_copy16((char*)BsU + i * 4096 + wbase,
                   Bb + ((long)(n0 + i * 64 + srow) * ldb + k0) * 2 + scol);
    }
    __syncthreads();  // compiler drains vmcnt(0) before s_barrier

    const int koff = (lane >> 4) * 8;
    bf16x8 a[4], b[4];
#pragma unroll
    for (int m = 0; m < 4; ++m)
      a[m] = *(const bf16x8*)&AsU[(wr * 64 + m * 16 + (lane & 15)) * 32 + koff];
#pragma unroll
    for (int n = 0; n < 4; ++n)
      b[n] = *(const bf16x8*)&BsU[(wc * 64 + n * 16 + (lane & 15)) * 32 + koff];
#pragma unroll
    for (int m = 0; m < 4; ++m)
#pragma unroll
      for (int n = 0; n < 4; ++n)
        acc[m][n] = __builtin_amdgcn_mfma_f32_16x16x32_bf16(a[m], b[n],
                                                            acc[m][n], 0, 0, 0);
    __syncthreads();
  }

  // epilogue: C/D layout col = lane&15, row = (lane>>4)*4 + reg
#pragma unroll
  for (int m = 0; m < 4; ++m) {
    int row = m0 + wr * 64 + m * 16 + (lane >> 4) * 4;
#pragma unroll
    for (int n = 0; n < 4; ++n) {
      int col = n0 + wc * 64 + n * 16 + (lane & 15);
      float bs = bias ? bias[col] : 0.f;
#pragma unroll
      for (int r = 0; r < 4; ++r) {
        float v = (acc[m][n][r] + bs) * alpha;
        long eidx = (long)bz * sE + (long)(row + r) * ldc + col;
        if (E1) v += E1[eidx];
        if (E2) v += E2[eidx];
        if (act) v = v * 0.5f * (1.f + erff(v * 0.70710678118f));
        long cidx = (long)bz * sC + (long)(row + r) * ldc + col;
        if (obf)
          ((__hip_bfloat16*)C)[cidx] = __float2bfloat16(v);
        else
          ((float*)C)[cidx] = v;
      }
    }
  }
}

// ---------------------------------------------------------------------------
// Fused MHA (f32 compute, bf16 out). Block = (i-tile of 16, h, b).
// ---------------------------------------------------------------------------
__global__ __launch_bounds__(256) void attn_fused(
    const float* __restrict__ Q, const float* __restrict__ Km,
    const float* __restrict__ V, const float* __restrict__ bias1,
    const float* __restrict__ mask1, __hip_bfloat16* __restrict__ O) {
  __shared__ float qs[16][64];
  __shared__ float sc[16][516];
  __shared__ float kv[64][65];
  const int it = blockIdx.x, h = blockIdx.y, b = blockIdx.z;
  const int i0 = it * 16;
  const int tid = threadIdx.x;

  for (int idx = tid; idx < 1024; idx += 256) {
    int r = idx >> 6, d = idx & 63;
    qs[r][d] = Q[(long)((b * 512 + i0 + r)) * 1024 + h * 64 + d];
  }

  for (int jt = 0; jt < 8; ++jt) {
    int j0 = jt * 64;
    __syncthreads();
    for (int idx = tid; idx < 4096; idx += 256) {
      int jj = idx >> 6, d = idx & 63;
      kv[jj][d] = Km[(long)((b * 512 + j0 + jj)) * 1024 + h * 64 + d];
    }
    __syncthreads();
#pragma unroll
    for (int w = 0; w < 4; ++w) {
      int flat = tid + 256 * w;
      int r = flat >> 6, jj = flat & 63;
      float acc = 0.f;
#pragma unroll
      for (int d = 0; d < 64; ++d) acc += qs[r][d] * kv[jj][d];
      int j = j0 + jj;
      long gi = (long)(b * 512 + i0 + r) * 512 + j;
      sc[r][j] = acc + bias1[gi] + mask1[gi];
    }
  }
  __syncthreads();

  {
    int r = tid >> 4, c = tid & 15;
    float mx = -3.0e38f;
    for (int j = c; j < 512; j += 16) mx = fmaxf(mx, sc[r][j]);
#pragma unroll
    for (int o = 8; o; o >>= 1) mx = fmaxf(mx, __shfl_xor(mx, o));
    float sum = 0.f;
    for (int j = c; j < 512; j += 16) {
      float e = __expf(sc[r][j] - mx);
      sc[r][j] = e;
      sum += e;
    }
#pragma unroll
    for (int o = 8; o; o >>= 1) sum += __shfl_xor(sum, o);
    float inv = 1.f / sum;
    for (int j = c; j < 512; j += 16) sc[r][j] *= inv;
  }

  float acc[4] = {0.f, 0.f, 0.f, 0.f};
  int r = tid >> 4, dd = tid & 15;
  for (int jt = 0; jt < 8; ++jt) {
    int j0 = jt * 64;
    __syncthreads();
    for (int idx = tid; idx < 4096; idx += 256) {
      int jj = idx >> 6, d = idx & 63;
      kv[jj][d] = V[(long)((b * 512 + j0 + jj)) * 1024 + h * 64 + d];
    }
    __syncthreads();
    for (int jj = 0; jj < 64; ++jj) {
      float s = sc[r][j0 + jj];
#pragma unroll
      for (int i = 0; i < 4; ++i) acc[i] += s * kv[jj][dd + 16 * i];
    }
  }
#pragma unroll
  for (int i = 0; i < 4; ++i)
    O[(long)(b * 512 + i0 + r) * 1024 + h * 64 + dd + 16 * i] =
        __float2bfloat16(acc[i]);
}

// ---------------------------------------------------------------------------
// Row softmax (512) f32 in -> bf16 out. One block per row.
// ---------------------------------------------------------------------------
__global__ __launch_bounds__(256) void softmax_rows(
    const float* __restrict__ P, __hip_bfloat16* __restrict__ Ob) {
  const float* row = P + (long)blockIdx.x * 512;
  __hip_bfloat16* orow = Ob + (long)blockIdx.x * 512;
  int t = threadIdx.x;
  float v0 = row[t], v1 = row[t + 256];
  float m = fmaxf(v0, v1);
#pragma unroll
  for (int o = 32; o; o >>= 1) m = fmaxf(m, __shfl_xor(m, o));
  __shared__ float red[8];
  int wid = t >> 6, lane = t & 63;
  if (!lane) red[wid] = m;
  __syncthreads();
  m = fmaxf(fmaxf(red[0], red[1]), fmaxf(red[2], red[3]));
  float e0 = __expf(v0 - m), e1 = __expf(v1 - m);
  float s = e0 + e1;
#pragma unroll
  for (int o = 32; o; o >>= 1) s += __shfl_xor(s, o);
  if (!lane) red[4 + wid] = s;
  __syncthreads();
  s = red[4] + red[5] + red[6] + red[7];
  float inv = 1.f / s;
  orow[t] = __float2bfloat16(e0 * inv);
  orow[t + 256] = __float2bfloat16(e1 * inv);
}

// ---------------------------------------------------------------------------
__global__ __launch_bounds__(256) void path_mean(const float* __restrict__ xp,
                                                 const int* __restrict__ pp,
                                                 float* __restrict__ path) {
  int b = blockIdx.x;
  int h = blockIdx.y * 256 + threadIdx.x;
  const int* ppb = pp + b * 512;
  const float* xb = xp + (long)b * 512 * 1024;
  float wsum = 0.f;
  for (int i = 0; i < 512; ++i) wsum += (ppb[i] == 1) ? 1.f : 0.f;
  float acc = 0.f;
  for (int i = 0; i < 512; ++i) {
    if (ppb[i] != 1) continue;
    float cur = xb[(long)i * 1024 + h];
    float a;
    if (i == 0) {
      a = 0.5f * (cur + xb[1024 + h]);
    } else if (i == 1) {
      a = (xb[h] + cur + xb[2 * 1024 + h]) * (1.f / 3.f);
    } else {
      int inx = (i + 1 < 512) ? i + 1 : 511;
      float nx = xb[(long)inx * 1024 + h];
      if (ppb[i - 2] == 1) {
        a = 0.5f * (cur + nx);
      } else {
        a = (xb[(long)(i - 1) * 1024 + h] + cur + nx) * (1.f / 3.f);
      }
    }
    acc += a;
  }
  path[b * 1024 + h] = acc / wsum;
}

__global__ __launch_bounds__(256) void combine(const float* __restrict__ X,
                                               const float* __restrict__ YS,
                                               const float* __restrict__ PT,
                                               float* __restrict__ X2) {
  int i = blockIdx.x * 256 + threadIdx.x;
  const float4 xv = ((const float4*)X)[i];
  const float4 sv = ((const float4*)YS)[i];
  int e = i * 4;
  int b = e >> 19;
  int h = e & 1023;
  const float4 pv = *(const float4*)(PT + b * 1024 + h);
  float4 o;
  o.x = xv.x + 0.5f * (sv.x + pv.x);
  o.y = xv.y + 0.5f * (sv.y + pv.y);
  o.z = xv.z + 0.5f * (sv.z + pv.z);
  o.w = xv.w + 0.5f * (sv.w + pv.w);
  ((float4*)X2)[i] = o;
}

// ---------------------------------------------------------------------------
extern "C" void kernel_launch(void* const* d_in, const int* in_sizes, int n_in,
                              void* d_out, int out_size, void* d_ws,
                              size_t ws_size, hipStream_t stream) {
  const float* x = (const float*)d_in[0];
  const int* pp = (const int*)d_in[1];
  const float* abias = (const float*)d_in[3];
  const float* amask = (const float*)d_in[4];
  const float* agraph = (const float*)d_in[5];
  const float* vgraph = (const float*)d_in[6];
  const float* ln1g = (const float*)d_in[7];
  const float* ln1b = (const float*)d_in[8];
  const float* wq = (const float*)d_in[9];
  const float* bq = (const float*)d_in[10];
  const float* wk = (const float*)d_in[11];
  const float* bk = (const float*)d_in[12];
  const float* wv = (const float*)d_in[13];
  const float* bv = (const float*)d_in[14];
  const float* wo = (const float*)d_in[15];
  const float* bo = (const float*)d_in[16];
  const float* pqw = (const float*)d_in[17];
  const float* pqb = (const float*)d_in[18];
  const float* pkw = (const float*)d_in[19];
  const float* pkb = (const float*)d_in[20];
  const float* pvw = (const float*)d_in[21];
  const float* pvb = (const float*)d_in[22];
  const float* ln2g = (const float*)d_in[23];
  const float* ln2b = (const float*)d_in[24];
  const float* w1 = (const float*)d_in[25];
  const float* b1 = (const float*)d_in[26];
  const float* w2 = (const float*)d_in[27];
  const float* b2 = (const float*)d_in[28];

  char* wsb = (char*)d_ws;
  auto Ybf = (__hip_bfloat16*)(wsb);                  // 8MB ; later Y2b
  auto Qf = (float*)(wsb + (8l << 20));               // 16MB; later YSELF
  auto Kf = (float*)(wsb + (24l << 20));              // 16MB; later X2
  auto Vf = (float*)(wsb + (40l << 20));              // 16MB; later XP
  auto PQb = (__hip_bfloat16*)(wsb + (56l << 20));    // 8MB (HMID overlay)
  auto PKb = (__hip_bfloat16*)(wsb + (64l << 20));    // 8MB (HMID overlay)
  auto PVb = (__hip_bfloat16*)(wsb + (72l << 20));    // 8MB (HMID overlay)
  auto PVT = (__hip_bfloat16*)(wsb + (80l << 20));    // 8MB (HMID overlay)
  auto ATTb = (__hip_bfloat16*)(wsb + (88l << 20));   // 8MB
  auto PATTf = (float*)(wsb + (96l << 20));           // 8MB
  auto PATTb = (__hip_bfloat16*)(wsb + (104l << 20)); // 4MB
  auto WQT = (__hip_bfloat16*)(wsb + (108l << 20));
  auto WKT = (__hip_bfloat16*)(wsb + (110l << 20));
  auto WVT = (__hip_bfloat16*)(wsb + (112l << 20));
  auto WOT = (__hip_bfloat16*)(wsb + (114l << 20));
  auto PQWT = (__hip_bfloat16*)(wsb + (116l << 20));
  auto PKWT = (__hip_bfloat16*)(wsb + (118l << 20));
  auto PVWT = (__hip_bfloat16*)(wsb + (120l << 20));
  auto W1T = (__hip_bfloat16*)(wsb + (122l << 20));   // 8MB
  auto W2T = (__hip_bfloat16*)(wsb + (130l << 20));   // 8MB
  auto PATH = (float*)(wsb + (138l << 20));           // 32KB
  auto HMID = (__hip_bfloat16*)(wsb + (56l << 20));   // 32MB overlay
  float* YSELF = Qf;
  float* X2 = Kf;
  float* XP = Vf;
  __hip_bfloat16* Y2b = Ybf;
  float* OUT = (float*)d_out;

  const float qscale = 0.125f;
  const float pscale = 0.03125f;
  const long S2 = 512l * 512, SH = 512l * 1024;

  // 0) weight transpose-convert to bf16 [N,K]
  tconv_f32_bf16<<<dim3(32, 32), 256, 0, stream>>>(wq, WQT, 1024, 1024);
  tconv_f32_bf16<<<dim3(32, 32), 256, 0, stream>>>(wk, WKT, 1024, 1024);
  tconv_f32_bf16<<<dim3(32, 32), 256, 0, stream>>>(wv, WVT, 1024, 1024);
  tconv_f32_bf16<<<dim3(32, 32), 256, 0, stream>>>(wo, WOT, 1024, 1024);
  tconv_f32_bf16<<<dim3(32, 32), 256, 0, stream>>>(pqw, PQWT, 1024, 1024);
  tconv_f32_bf16<<<dim3(32, 32), 256, 0, stream>>>(pkw, PKWT, 1024, 1024);
  tconv_f32_bf16<<<dim3(32, 32), 256, 0, stream>>>(pvw, PVWT, 1024, 1024);
  tconv_f32_bf16<<<dim3(128, 32), 256, 0, stream>>>(w1, W1T, 1024, 4096);
  tconv_f32_bf16<<<dim3(32, 128), 256, 0, stream>>>(w2, W2T, 4096, 1024);

  // 1) LN1 -> Ybf (bf16)
  ln_rows_bf16<<<4096, 256, 0, stream>>>(x, ln1g, ln1b, Ybf);

  // 2) projections (M=4096, N=1024, K=1024)
  gemm_bf16_nt<<<dim3(8, 32, 1), 256, 0, stream>>>(
      Ybf, WQT, bq, nullptr, nullptr, Qf, 1024, 1024, 1024, 1024, 0, 0, 0, 0,
      qscale, 0, 0);
  gemm_bf16_nt<<<dim3(8, 32, 1), 256, 0, stream>>>(
      Ybf, WKT, bk, nullptr, nullptr, Kf, 1024, 1024, 1024, 1024, 0, 0, 0, 0,
      1.f, 0, 0);
  gemm_bf16_nt<<<dim3(8, 32, 1), 256, 0, stream>>>(
      Ybf, WVT, bv, nullptr, nullptr, Vf, 1024, 1024, 1024, 1024, 0, 0, 0, 0,
      1.f, 0, 0);
  gemm_bf16_nt<<<dim3(8, 32, 1), 256, 0, stream>>>(
      Ybf, PQWT, pqb, nullptr, nullptr, PQb, 1024, 1024, 1024, 1024, 0, 0, 0,
      0, pscale, 0, 1);
  gemm_bf16_nt<<<dim3(8, 32, 1), 256, 0, stream>>>(
      Ybf, PKWT, pkb, nullptr, nullptr, PKb, 1024, 1024, 1024, 1024, 0, 0, 0,
      0, 1.f, 0, 1);
  gemm_bf16_nt<<<dim3(8, 32, 1), 256, 0, stream>>>(
      Ybf, PVWT, pvb, nullptr, nullptr, PVb, 1024, 1024, 1024, 1024, 0, 0, 0,
      0, 1.f, 0, 1);

  // 3) PV^T per batch: [512,1024] -> [1024,512] bf16
  tconv_bf16<<<dim3(32, 16, 8), 256, 0, stream>>>(PVb, PVT, 512, 1024);

  // 4) path scores: PATTf = PQ@PK^T + agraph + vgraph (batched)
  gemm_bf16_nt<<<dim3(4, 4, 8), 256, 0, stream>>>(
      PQb, PKb, nullptr, agraph, vgraph, PATTf, 1024, 1024, 1024, 512, SH, SH,
      S2, S2, 1.f, 0, 0);
  softmax_rows<<<4096, 256, 0, stream>>>(PATTf, PATTb);

  // 5) fused MHA (f32) -> ATTb bf16
  attn_fused<<<dim3(32, 16, 8), 256, 0, stream>>>(Qf, Kf, Vf, abias, amask,
                                                  ATTb);

  // 6) XP = PATT @ PV (NT vs PVT), f32 out (overlays Vf; runs after attn)
  gemm_bf16_nt<<<dim3(8, 4, 8), 256, 0, stream>>>(
      PATTb, PVT, nullptr, nullptr, nullptr, XP, 512, 512, 512, 1024, S2, SH,
      SH, 0, 1.f, 0, 0);

  // 7) path gather-mean
  path_mean<<<dim3(8, 4), 256, 0, stream>>>(XP, pp, PATH);

  // 8) y_self = ATT @ wo + bo (f32 out, overlays Qf)
  gemm_bf16_nt<<<dim3(8, 32, 1), 256, 0, stream>>>(
      ATTb, WOT, bo, nullptr, nullptr, YSELF, 1024, 1024, 1024, 1024, 0, 0, 0,
      0, 1.f, 0, 0);

  // 9) X2 = x + 0.5*(YSELF + PATH)
  combine<<<4096, 256, 0, stream>>>(x, YSELF, PATH, X2);

  // 10) LN2 -> Y2b (bf16)
  ln_rows_bf16<<<4096, 256, 0, stream>>>(X2, ln2g, ln2b, Y2b);

  // 11) FFN1: HMID = gelu(Y2@w1+b1), bf16 out (M=4096,N=4096,K=1024)
  gemm_bf16_nt<<<dim3(32, 32, 1), 256, 0, stream>>>(
      Y2b, W1T, b1, nullptr, nullptr, HMID, 1024, 1024, 1024, 4096, 0, 0, 0, 0,
      1.f, 1, 1);

  // 12) FFN2: OUT = HMID@w2 + b2 + X2 (M=4096,N=1024,K=4096)
  gemm_bf16_nt<<<dim3(8, 32, 1), 256, 0, stream>>>(
      HMID, W2T, b2, X2, nullptr, OUT, 4096, 4096, 4096, 1024, 0, 0, 0, 0, 1.f,
      0, 0);
}

// Round 4
// 756.307 us; speedup vs baseline: 6.7039x; 1.6729x over previous
//
#include <hip/hip_runtime.h>
#include <hip/hip_bf16.h>
#include <math.h>

// B=8, S=512, H=1024, NH=16, DK=64, FF=4096.
// Round 4: attention -> bf16 MFMA (per-block (b,h,32 q-rows), in-register
// softmax, P in LDS, V pre-transposed). Projections emit bf16 directly.

typedef __bf16 bf16x8 __attribute__((ext_vector_type(8)));
typedef float f32x4 __attribute__((ext_vector_type(4)));

__device__ __forceinline__ void async_copy16(void* lds, const void* g) {
  __builtin_amdgcn_global_load_lds(
      (__attribute__((address_space(1))) void*)(void*)g,
      (__attribute__((address_space(3))) void*)lds, 16, 0, 0);
}

// ---------------------------------------------------------------------------
// LayerNorm over last dim (1024) -> bf16. One block (256 thr) per row.
// ---------------------------------------------------------------------------
__global__ __launch_bounds__(256) void ln_rows_bf16(
    const float* __restrict__ X, const float* __restrict__ G,
    const float* __restrict__ Bt, __hip_bfloat16* __restrict__ O) {
  long row = blockIdx.x;
  int t = threadIdx.x;
  const float4 xv = ((const float4*)(X + row * 1024))[t];
  float s = xv.x + xv.y + xv.z + xv.w;
  float q = xv.x * xv.x + xv.y * xv.y + xv.z * xv.z + xv.w * xv.w;
#pragma unroll
  for (int o = 32; o; o >>= 1) {
    s += __shfl_xor(s, o);
    q += __shfl_xor(q, o);
  }
  __shared__ float rs[4], rq[4];
  int wid = t >> 6;
  if ((t & 63) == 0) { rs[wid] = s; rq[wid] = q; }
  __syncthreads();
  s = rs[0] + rs[1] + rs[2] + rs[3];
  q = rq[0] + rq[1] + rq[2] + rq[3];
  float mean = s * (1.f / 1024.f);
  float var = q * (1.f / 1024.f) - mean * mean;
  float rstd = rsqrtf(var + 1e-5f);
  const float4 gv = ((const float4*)G)[t];
  const float4 bv = ((const float4*)Bt)[t];
  __hip_bfloat16* o = O + row * 1024 + t * 4;
  o[0] = __float2bfloat16((xv.x - mean) * rstd * gv.x + bv.x);
  o[1] = __float2bfloat16((xv.y - mean) * rstd * gv.y + bv.y);
  o[2] = __float2bfloat16((xv.z - mean) * rstd * gv.z + bv.z);
  o[3] = __float2bfloat16((xv.w - mean) * rstd * gv.w + bv.w);
}

// ---------------------------------------------------------------------------
// Transpose-convert f32 [R,C] -> bf16 [C,R]. grid (C/32, R/32), 256 thr.
// ---------------------------------------------------------------------------
__global__ __launch_bounds__(256) void tconv_f32_bf16(
    const float* __restrict__ in, __hip_bfloat16* __restrict__ out, int R,
    int C) {
  __shared__ float t[32][33];
  int c0 = blockIdx.x * 32, r0 = blockIdx.y * 32;
  int tid = threadIdx.x;
  int lr = tid >> 3, lc = (tid & 7) * 4;
  const float4 v = *(const float4*)&in[(long)(r0 + lr) * C + c0 + lc];
  t[lr][lc] = v.x; t[lr][lc + 1] = v.y; t[lr][lc + 2] = v.z; t[lr][lc + 3] = v.w;
  __syncthreads();
  int oc = tid >> 3, orr = (tid & 7) * 4;
  __hip_bfloat16* o = &out[(long)(c0 + oc) * R + r0 + orr];
  o[0] = __float2bfloat16(t[orr][oc]);
  o[1] = __float2bfloat16(t[orr + 1][oc]);
  o[2] = __float2bfloat16(t[orr + 2][oc]);
  o[3] = __float2bfloat16(t[orr + 3][oc]);
}

// Batched bf16 [bz][R][C] -> bf16 [bz][C][R]. grid (C/32, R/32, bz).
__global__ __launch_bounds__(256) void tconv_bf16(
    const __hip_bfloat16* __restrict__ in, __hip_bfloat16* __restrict__ out,
    int R, int C) {
  __shared__ __hip_bfloat16 t[32][34];
  long base = (long)blockIdx.z * R * C;
  int c0 = blockIdx.x * 32, r0 = blockIdx.y * 32;
  int tid = threadIdx.x;
  int lr = tid >> 3, lc = (tid & 7) * 4;
  const __hip_bfloat16* ip = &in[base + (long)(r0 + lr) * C + c0 + lc];
  t[lr][lc] = ip[0]; t[lr][lc + 1] = ip[1]; t[lr][lc + 2] = ip[2]; t[lr][lc + 3] = ip[3];
  __syncthreads();
  int oc = tid >> 3, orr = (tid & 7) * 4;
  __hip_bfloat16* o = &out[base + (long)(c0 + oc) * R + r0 + orr];
  o[0] = t[orr][oc];
  o[1] = t[orr + 1][oc];
  o[2] = t[orr + 2][oc];
  o[3] = t[orr + 3][oc];
}

// o = a + b (float4 per thread)
__global__ __launch_bounds__(256) void add2(const float* __restrict__ a,
                                            const float* __restrict__ b,
                                            float* __restrict__ o) {
  int i = blockIdx.x * 256 + threadIdx.x;
  float4 av = ((const float4*)a)[i], bv = ((const float4*)b)[i];
  float4 ov;
  ov.x = av.x + bv.x; ov.y = av.y + bv.y;
  ov.z = av.z + bv.z; ov.w = av.w + bv.w;
  ((float4*)o)[i] = ov;
}

// ---------------------------------------------------------------------------
// bf16 MFMA GEMM (NT): C = alpha*(A@Bt^T + bias) + E1 + E2, opt. exact GELU.
// 128x128 tile, BK=32, 256 thr = 4 waves (2x2), each wave 64x64 = 4x4 frags.
// ---------------------------------------------------------------------------
__global__ __launch_bounds__(256) void gemm_bf16_nt(
    const __hip_bfloat16* __restrict__ A, const __hip_bfloat16* __restrict__ Bt,
    const float* __restrict__ bias, const float* __restrict__ E1,
    const float* __restrict__ E2, void* __restrict__ C, int K, int lda,
    int ldb, int ldc, long sA, long sB, long sC, long sE, float alpha, int act,
    int obf) {
  __shared__ unsigned short AsU[128 * 32];
  __shared__ unsigned short BsU[128 * 32];
  const int tid = threadIdx.x;
  const int lane = tid & 63, wave = tid >> 6;
  const int wr = wave >> 1, wc = wave & 1;
  const int m0 = blockIdx.y * 128, n0 = blockIdx.x * 128;
  const int bz = blockIdx.z;
  const char* Ab = (const char*)(A + (long)bz * sA);
  const char* Bb = (const char*)(Bt + (long)bz * sB);

  f32x4 acc[4][4];
#pragma unroll
  for (int m = 0; m < 4; ++m)
#pragma unroll
    for (int n = 0; n < 4; ++n) acc[m][n] = (f32x4){0.f, 0.f, 0.f, 0.f};

  const int srow = tid >> 2;
  const int scol = (tid & 3) * 16;
  const int wbase = (tid >> 6) * 1024;

  for (int k0 = 0; k0 < K; k0 += 32) {
#pragma unroll
    for (int i = 0; i < 2; ++i) {
      async_copy16((char*)AsU + i * 4096 + wbase,
                   Ab + ((long)(m0 + i * 64 + srow) * lda + k0) * 2 + scol);
      async_copy16((char*)BsU + i * 4096 + wbase,
                   Bb + ((long)(n0 + i * 64 + srow) * ldb + k0) * 2 + scol);
    }
    __syncthreads();

    const int koff = (lane >> 4) * 8;
    bf16x8 a[4], b[4];
#pragma unroll
    for (int m = 0; m < 4; ++m)
      a[m] = *(const bf16x8*)&AsU[(wr * 64 + m * 16 + (lane & 15)) * 32 + koff];
#pragma unroll
    for (int n = 0; n < 4; ++n)
      b[n] = *(const bf16x8*)&BsU[(wc * 64 + n * 16 + (lane & 15)) * 32 + koff];
#pragma unroll
    for (int m = 0; m < 4; ++m)
#pragma unroll
      for (int n = 0; n < 4; ++n)
        acc[m][n] = __builtin_amdgcn_mfma_f32_16x16x32_bf16(a[m], b[n],
                                                            acc[m][n], 0, 0, 0);
    __syncthreads();
  }

#pragma unroll
  for (int m = 0; m < 4; ++m) {
    int row = m0 + wr * 64 + m * 16 + (lane >> 4) * 4;
#pragma unroll
    for (int n = 0; n < 4; ++n) {
      int col = n0 + wc * 64 + n * 16 + (lane & 15);
      float bs = bias ? bias[col] : 0.f;
#pragma unroll
      for (int r = 0; r < 4; ++r) {
        float v = (acc[m][n][r] + bs) * alpha;
        long eidx = (long)bz * sE + (long)(row + r) * ldc + col;
        if (E1) v += E1[eidx];
        if (E2) v += E2[eidx];
        if (act) v = v * 0.5f * (1.f + erff(v * 0.70710678118f));
        long cidx = (long)bz * sC + (long)(row + r) * ldc + col;
        if (obf)
          ((__hip_bfloat16*)C)[cidx] = __float2bfloat16(v);
        else
          ((float*)C)[cidx] = v;
      }
    }
  }
}

// ---------------------------------------------------------------------------
// MFMA attention. Block = (i-tile of 32, h, b); 4 waves.
// Q,K bf16 [B*S,1024] (Q pre-scaled); VT bf16 [B,1024,512]; BM f32 [B,S,S].
// Wave w owns score cols [w*128, w*128+128). In-register softmax.
// ---------------------------------------------------------------------------
__global__ __launch_bounds__(256) void attn_mfma(
    const __hip_bfloat16* __restrict__ Q, const __hip_bfloat16* __restrict__ K,
    const __hip_bfloat16* __restrict__ VT, const float* __restrict__ BM,
    __hip_bfloat16* __restrict__ O) {
  __shared__ __hip_bfloat16 P[32][520];  // row stride 1040B = 65*16B
  __shared__ float red[2][32][4];
  const int it = blockIdx.x, h = blockIdx.y, b = blockIdx.z;
  const int i0 = it * 32;
  const int tid = threadIdx.x;
  const int lane = tid & 63, w = tid >> 6;
  const int lh = lane >> 4, ll = lane & 15;

  const long qkb = ((long)b * 512) * 1024 + h * 64;

  // A-frags: Q rows (shared by all waves), 2 m-frags x 2 k-steps
  bf16x8 a[2][2];
#pragma unroll
  for (int m = 0; m < 2; ++m)
#pragma unroll
    for (int ks = 0; ks < 2; ++ks)
      a[m][ks] = *(const bf16x8*)&Q[qkb + (long)(i0 + m * 16 + ll) * 1024 +
                                    ks * 32 + lh * 8];

  f32x4 acc[2][8];
#pragma unroll
  for (int m = 0; m < 2; ++m)
#pragma unroll
    for (int n = 0; n < 8; ++n) acc[m][n] = (f32x4){0.f, 0.f, 0.f, 0.f};

  // scores: wave's 128 cols, K-frags straight from global (L2-resident)
#pragma unroll
  for (int n = 0; n < 8; ++n) {
    const __hip_bfloat16* kp =
        &K[qkb + (long)(w * 128 + n * 16 + ll) * 1024 + lh * 8];
    bf16x8 b0 = *(const bf16x8*)&kp[0];
    bf16x8 b1 = *(const bf16x8*)&kp[32];
#pragma unroll
    for (int m = 0; m < 2; ++m) {
      acc[m][n] =
          __builtin_amdgcn_mfma_f32_16x16x32_bf16(a[m][0], b0, acc[m][n], 0, 0, 0);
      acc[m][n] =
          __builtin_amdgcn_mfma_f32_16x16x32_bf16(a[m][1], b1, acc[m][n], 0, 0, 0);
    }
  }

  // add merged bias+mask
  const float* bmb = BM + ((long)b * 512 + i0) * 512 + w * 128;
#pragma unroll
  for (int m = 0; m < 2; ++m)
#pragma unroll
    for (int r = 0; r < 4; ++r) {
      int row = m * 16 + lh * 4 + r;
#pragma unroll
      for (int n = 0; n < 8; ++n)
        acc[m][n][r] += bmb[(long)row * 512 + n * 16 + ll];
    }

  // softmax: per-lane rows are (m, r); cols spread over n-frags + ll group
  float rmax[2][4];
#pragma unroll
  for (int m = 0; m < 2; ++m)
#pragma unroll
    for (int r = 0; r < 4; ++r) {
      float v = acc[m][0][r];
#pragma unroll
      for (int n = 1; n < 8; ++n) v = fmaxf(v, acc[m][n][r]);
#pragma unroll
      for (int o = 1; o < 16; o <<= 1) v = fmaxf(v, __shfl_xor(v, o));
      rmax[m][r] = v;
    }
  if (ll == 0) {
#pragma unroll
    for (int m = 0; m < 2; ++m)
#pragma unroll
      for (int r = 0; r < 4; ++r) red[0][m * 16 + lh * 4 + r][w] = rmax[m][r];
  }
  __syncthreads();
#pragma unroll
  for (int m = 0; m < 2; ++m)
#pragma unroll
    for (int r = 0; r < 4; ++r) {
      const float* p = red[0][m * 16 + lh * 4 + r];
      rmax[m][r] = fmaxf(fmaxf(p[0], p[1]), fmaxf(p[2], p[3]));
    }
  float rsum[2][4];
#pragma unroll
  for (int m = 0; m < 2; ++m)
#pragma unroll
    for (int r = 0; r < 4; ++r) {
      float s = 0.f;
#pragma unroll
      for (int n = 0; n < 8; ++n) {
        float e = __expf(acc[m][n][r] - rmax[m][r]);
        acc[m][n][r] = e;
        s += e;
      }
#pragma unroll
      for (int o = 1; o < 16; o <<= 1) s += __shfl_xor(s, o);
      rsum[m][r] = s;
    }
  if (ll == 0) {
#pragma unroll
    for (int m = 0; m < 2; ++m)
#pragma unroll
      for (int r = 0; r < 4; ++r) red[1][m * 16 + lh * 4 + r][w] = rsum[m][r];
  }
  __syncthreads();
#pragma unroll
  for (int m = 0; m < 2; ++m)
#pragma unroll
    for (int r = 0; r < 4; ++r) {
      const float* p = red[1][m * 16 + lh * 4 + r];
      float inv = 1.f / (p[0] + p[1] + p[2] + p[3]);
      int row = m * 16 + lh * 4 + r;
#pragma unroll
      for (int n = 0; n < 8; ++n)
        P[row][w * 128 + n * 16 + ll] = __float2bfloat16(acc[m][n][r] * inv);
    }
  __syncthreads();

  // PV: out[i, d] = sum_j P[i,j] * VT[d, j]. Wave: m-frag w>>1, 2 n-frags.
  const long vtb = ((long)b * 1024 + h * 64) * 512;
  const int mw = (w >> 1) * 16, nw = (w & 1) * 32;
  f32x4 oacc[2];
  oacc[0] = (f32x4){0.f, 0.f, 0.f, 0.f};
  oacc[1] = (f32x4){0.f, 0.f, 0.f, 0.f};
#pragma unroll
  for (int ks = 0; ks < 16; ++ks) {
    int k0 = ks * 32;
    bf16x8 pa = *(const bf16x8*)&P[mw + ll][k0 + lh * 8];
#pragma unroll
    for (int nf = 0; nf < 2; ++nf) {
      bf16x8 vb = *(const bf16x8*)&VT[vtb + (long)(nw + nf * 16 + ll) * 512 +
                                      k0 + lh * 8];
      oacc[nf] =
          __builtin_amdgcn_mfma_f32_16x16x32_bf16(pa, vb, oacc[nf], 0, 0, 0);
    }
  }
#pragma unroll
  for (int nf = 0; nf < 2; ++nf)
#pragma unroll
    for (int r = 0; r < 4; ++r)
      O[qkb + (long)(i0 + mw + lh * 4 + r) * 1024 + nw + nf * 16 + ll] =
          __float2bfloat16(oacc[nf][r]);
}

// ---------------------------------------------------------------------------
// Row softmax (512) f32 in -> bf16 out. One block per row.
// ---------------------------------------------------------------------------
__global__ __launch_bounds__(256) void softmax_rows(
    const float* __restrict__ P, __hip_bfloat16* __restrict__ Ob) {
  const float* row = P + (long)blockIdx.x * 512;
  __hip_bfloat16* orow = Ob + (long)blockIdx.x * 512;
  int t = threadIdx.x;
  float v0 = row[t], v1 = row[t + 256];
  float m = fmaxf(v0, v1);
#pragma unroll
  for (int o = 32; o; o >>= 1) m = fmaxf(m, __shfl_xor(m, o));
  __shared__ float red[8];
  int wid = t >> 6, lane = t & 63;
  if (!lane) red[wid] = m;
  __syncthreads();
  m = fmaxf(fmaxf(red[0], red[1]), fmaxf(red[2], red[3]));
  float e0 = __expf(v0 - m), e1 = __expf(v1 - m);
  float s = e0 + e1;
#pragma unroll
  for (int o = 32; o; o >>= 1) s += __shfl_xor(s, o);
  if (!lane) red[4 + wid] = s;
  __syncthreads();
  s = red[4] + red[5] + red[6] + red[7];
  float inv = 1.f / s;
  orow[t] = __float2bfloat16(e0 * inv);
  orow[t + 256] = __float2bfloat16(e1 * inv);
}

// ---------------------------------------------------------------------------
__global__ __launch_bounds__(256) void path_mean(const float* __restrict__ xp,
                                                 const int* __restrict__ pp,
                                                 float* __restrict__ path) {
  int b = blockIdx.x;
  int h = blockIdx.y * 256 + threadIdx.x;
  const int* ppb = pp + b * 512;
  const float* xb = xp + (long)b * 512 * 1024;
  float wsum = 0.f;
  for (int i = 0; i < 512; ++i) wsum += (ppb[i] == 1) ? 1.f : 0.f;
  float acc = 0.f;
  for (int i = 0; i < 512; ++i) {
    if (ppb[i] != 1) continue;
    float cur = xb[(long)i * 1024 + h];
    float a;
    if (i == 0) {
      a = 0.5f * (cur + xb[1024 + h]);
    } else if (i == 1) {
      a = (xb[h] + cur + xb[2 * 1024 + h]) * (1.f / 3.f);
    } else {
      int inx = (i + 1 < 512) ? i + 1 : 511;
      float nx = xb[(long)inx * 1024 + h];
      if (ppb[i - 2] == 1) {
        a = 0.5f * (cur + nx);
      } else {
        a = (xb[(long)(i - 1) * 1024 + h] + cur + nx) * (1.f / 3.f);
      }
    }
    acc += a;
  }
  path[b * 1024 + h] = acc / wsum;
}

__global__ __launch_bounds__(256) void combine(const float* __restrict__ X,
                                               const float* __restrict__ YS,
                                               const float* __restrict__ PT,
                                               float* __restrict__ X2) {
  int i = blockIdx.x * 256 + threadIdx.x;
  const float4 xv = ((const float4*)X)[i];
  const float4 sv = ((const float4*)YS)[i];
  int e = i * 4;
  int b = e >> 19;
  int h = e & 1023;
  const float4 pv = *(const float4*)(PT + b * 1024 + h);
  float4 o;
  o.x = xv.x + 0.5f * (sv.x + pv.x);
  o.y = xv.y + 0.5f * (sv.y + pv.y);
  o.z = xv.z + 0.5f * (sv.z + pv.z);
  o.w = xv.w + 0.5f * (sv.w + pv.w);
  ((float4*)X2)[i] = o;
}

// ---------------------------------------------------------------------------
extern "C" void kernel_launch(void* const* d_in, const int* in_sizes, int n_in,
                              void* d_out, int out_size, void* d_ws,
                              size_t ws_size, hipStream_t stream) {
  const float* x = (const float*)d_in[0];
  const int* pp = (const int*)d_in[1];
  const float* abias = (const float*)d_in[3];
  const float* amask = (const float*)d_in[4];
  const float* agraph = (const float*)d_in[5];
  const float* vgraph = (const float*)d_in[6];
  const float* ln1g = (const float*)d_in[7];
  const float* ln1b = (const float*)d_in[8];
  const float* wq = (const float*)d_in[9];
  const float* bq = (const float*)d_in[10];
  const float* wk = (const float*)d_in[11];
  const float* bk = (const float*)d_in[12];
  const float* wv = (const float*)d_in[13];
  const float* bv = (const float*)d_in[14];
  const float* wo = (const float*)d_in[15];
  const float* bo = (const float*)d_in[16];
  const float* pqw = (const float*)d_in[17];
  const float* pqb = (const float*)d_in[18];
  const float* pkw = (const float*)d_in[19];
  const float* pkb = (const float*)d_in[20];
  const float* pvw = (const float*)d_in[21];
  const float* pvb = (const float*)d_in[22];
  const float* ln2g = (const float*)d_in[23];
  const float* ln2b = (const float*)d_in[24];
  const float* w1 = (const float*)d_in[25];
  const float* b1 = (const float*)d_in[26];
  const float* w2 = (const float*)d_in[27];
  const float* b2 = (const float*)d_in[28];

  char* wsb = (char*)d_ws;
  auto Ybf = (__hip_bfloat16*)(wsb);                  // 0-8   (later Y2b)
  auto Qb = (__hip_bfloat16*)(wsb + (8l << 20));      // 8-16  (later YSELF lo)
  auto Kb = (__hip_bfloat16*)(wsb + (16l << 20));     // 16-24 (later YSELF hi)
  auto Vb = (__hip_bfloat16*)(wsb + (24l << 20));     // 24-32 (later X2 lo)
  auto VTb = (__hip_bfloat16*)(wsb + (32l << 20));    // 32-40 (later X2 hi)
  auto BM = (float*)(wsb + (40l << 20));              // 40-48 (later HMID)
  auto PQb = (__hip_bfloat16*)(wsb + (48l << 20));    // 48-56 (later HMID)
  auto PKb = (__hip_bfloat16*)(wsb + (56l << 20));    // 56-64 (later HMID)
  auto PVb = (__hip_bfloat16*)(wsb + (64l << 20));    // 64-72 (later HMID)
  auto PVT = (__hip_bfloat16*)(wsb + (72l << 20));    // 72-80
  auto ATTb = (__hip_bfloat16*)(wsb + (80l << 20));   // 80-88 (later W2T)
  auto PATTb = (__hip_bfloat16*)(wsb + (88l << 20));  // 88-92
  auto PATTf = (float*)(wsb + (92l << 20));           // 92-100 (later XP lo)
  auto XP = (float*)(wsb + (92l << 20));              // 92-108
  auto WQT = (__hip_bfloat16*)(wsb + (108l << 20));
  auto WKT = (__hip_bfloat16*)(wsb + (110l << 20));
  auto WVT = (__hip_bfloat16*)(wsb + (112l << 20));
  auto WOT = (__hip_bfloat16*)(wsb + (114l << 20));
  auto PQWT = (__hip_bfloat16*)(wsb + (116l << 20));
  auto PKWT = (__hip_bfloat16*)(wsb + (118l << 20));
  auto PVWT = (__hip_bfloat16*)(wsb + (120l << 20));
  auto W1T = (__hip_bfloat16*)(wsb + (122l << 20));   // 122-130
  auto PATH = (float*)(wsb + (130l << 20));           // 130-130.03
  auto W2T = ATTb;                                    // 80-88 after wo-gemm
  auto YSELF = (float*)(wsb + (8l << 20));            // 8-24 after attn
  auto X2 = (float*)(wsb + (24l << 20));              // 24-40 after attn
  auto HMID = (__hip_bfloat16*)(wsb + (40l << 20));   // 40-72 after XP gemm
  __hip_bfloat16* Y2b = Ybf;
  float* OUT = (float*)d_out;

  const float qscale = 0.125f;
  const float pscale = 0.03125f;
  const long S2 = 512l * 512, SH = 512l * 1024;

  // 0) weight transpose-converts (W2 deferred until ATTb is dead)
  tconv_f32_bf16<<<dim3(32, 32), 256, 0, stream>>>(wq, WQT, 1024, 1024);
  tconv_f32_bf16<<<dim3(32, 32), 256, 0, stream>>>(wk, WKT, 1024, 1024);
  tconv_f32_bf16<<<dim3(32, 32), 256, 0, stream>>>(wv, WVT, 1024, 1024);
  tconv_f32_bf16<<<dim3(32, 32), 256, 0, stream>>>(wo, WOT, 1024, 1024);
  tconv_f32_bf16<<<dim3(32, 32), 256, 0, stream>>>(pqw, PQWT, 1024, 1024);
  tconv_f32_bf16<<<dim3(32, 32), 256, 0, stream>>>(pkw, PKWT, 1024, 1024);
  tconv_f32_bf16<<<dim3(32, 32), 256, 0, stream>>>(pvw, PVWT, 1024, 1024);
  tconv_f32_bf16<<<dim3(128, 32), 256, 0, stream>>>(w1, W1T, 1024, 4096);

  // 0b) merged attention bias
  add2<<<2048, 256, 0, stream>>>(abias, amask, BM);

  // 1) LN1 -> Ybf
  ln_rows_bf16<<<4096, 256, 0, stream>>>(x, ln1g, ln1b, Ybf);

  // 2) projections (bf16 out)
  gemm_bf16_nt<<<dim3(8, 32, 1), 256, 0, stream>>>(
      Ybf, WQT, bq, nullptr, nullptr, Qb, 1024, 1024, 1024, 1024, 0, 0, 0, 0,
      qscale, 0, 1);
  gemm_bf16_nt<<<dim3(8, 32, 1), 256, 0, stream>>>(
      Ybf, WKT, bk, nullptr, nullptr, Kb, 1024, 1024, 1024, 1024, 0, 0, 0, 0,
      1.f, 0, 1);
  gemm_bf16_nt<<<dim3(8, 32, 1), 256, 0, stream>>>(
      Ybf, WVT, bv, nullptr, nullptr, Vb, 1024, 1024, 1024, 1024, 0, 0, 0, 0,
      1.f, 0, 1);
  gemm_bf16_nt<<<dim3(8, 32, 1), 256, 0, stream>>>(
      Ybf, PQWT, pqb, nullptr, nullptr, PQb, 1024, 1024, 1024, 1024, 0, 0, 0,
      0, pscale, 0, 1);
  gemm_bf16_nt<<<dim3(8, 32, 1), 256, 0, stream>>>(
      Ybf, PKWT, pkb, nullptr, nullptr, PKb, 1024, 1024, 1024, 1024, 0, 0, 0,
      0, 1.f, 0, 1);
  gemm_bf16_nt<<<dim3(8, 32, 1), 256, 0, stream>>>(
      Ybf, PVWT, pvb, nullptr, nullptr, PVb, 1024, 1024, 1024, 1024, 0, 0, 0,
      0, 1.f, 0, 1);

  // 3) transposes: V -> VT, PV -> PVT (per batch [512,1024] -> [1024,512])
  tconv_bf16<<<dim3(32, 16, 8), 256, 0, stream>>>(Vb, VTb, 512, 1024);
  tconv_bf16<<<dim3(32, 16, 8), 256, 0, stream>>>(PVb, PVT, 512, 1024);

  // 4) path scores + softmax
  gemm_bf16_nt<<<dim3(4, 4, 8), 256, 0, stream>>>(
      PQb, PKb, nullptr, agraph, vgraph, PATTf, 1024, 1024, 1024, 512, SH, SH,
      S2, S2, 1.f, 0, 0);
  softmax_rows<<<4096, 256, 0, stream>>>(PATTf, PATTb);

  // 5) MFMA attention -> ATTb
  attn_mfma<<<dim3(16, 16, 8), 256, 0, stream>>>(Qb, Kb, VTb, BM, ATTb);

  // 6) XP = PATT @ PV (overwrites PATTf region; reads PATTb+PVT)
  gemm_bf16_nt<<<dim3(8, 4, 8), 256, 0, stream>>>(
      PATTb, PVT, nullptr, nullptr, nullptr, XP, 512, 512, 512, 1024, S2, SH,
      SH, 0, 1.f, 0, 0);

  // 7) path gather-mean
  path_mean<<<dim3(8, 4), 256, 0, stream>>>(XP, pp, PATH);

  // 8) y_self = ATT @ wo + bo (f32, overlays Qb/Kb)
  gemm_bf16_nt<<<dim3(8, 32, 1), 256, 0, stream>>>(
      ATTb, WOT, bo, nullptr, nullptr, YSELF, 1024, 1024, 1024, 1024, 0, 0, 0,
      0, 1.f, 0, 0);

  // 8b) W2 transpose into ATTb's slot (ATTb now dead)
  tconv_f32_bf16<<<dim3(32, 128), 256, 0, stream>>>(w2, W2T, 4096, 1024);

  // 9) X2 = x + 0.5*(YSELF + PATH) (overlays Vb/VTb)
  combine<<<4096, 256, 0, stream>>>(x, YSELF, PATH, X2);

  // 10) LN2 -> Y2b
  ln_rows_bf16<<<4096, 256, 0, stream>>>(X2, ln2g, ln2b, Y2b);

  // 11) FFN1: HMID = gelu(Y2@w1+b1) bf16 (overlays BM/PQb/PKb/PVb)
  gemm_bf16_nt<<<dim3(32, 32, 1), 256, 0, stream>>>(
      Y2b, W1T, b1, nullptr, nullptr, HMID, 1024, 1024, 1024, 4096, 0, 0, 0, 0,
      1.f, 1, 1);

  // 12) FFN2: OUT = HMID@w2 + b2 + X2
  gemm_bf16_nt<<<dim3(8, 32, 1), 256, 0, stream>>>(
      HMID, W2T, b2, X2, nullptr, OUT, 4096, 4096, 4096, 1024, 0, 0, 0, 0, 1.f,
      0, 0);
}

// Round 5
// 557.919 us; speedup vs baseline: 9.0877x; 1.3556x over previous
//
#include <hip/hip_runtime.h>
#include <hip/hip_bf16.h>
#include <math.h>

// B=8, S=512, H=1024, NH=16, DK=64, FF=4096.
// Round 5: (1) path_mean parallelized over i-chunks (was 121us @ 1.4% occ);
// (2) 6 projection GEMMs fused into one (N=6144, pre-scaled concat weights);
// (3) weight transposes batched into one launch.

typedef __bf16 bf16x8 __attribute__((ext_vector_type(8)));
typedef float f32x4 __attribute__((ext_vector_type(4)));

__device__ __forceinline__ void async_copy16(void* lds, const void* g) {
  __builtin_amdgcn_global_load_lds(
      (__attribute__((address_space(1))) void*)(void*)g,
      (__attribute__((address_space(3))) void*)lds, 16, 0, 0);
}

// ---------------------------------------------------------------------------
// LayerNorm over last dim (1024) -> bf16. One block (256 thr) per row.
// ---------------------------------------------------------------------------
__global__ __launch_bounds__(256) void ln_rows_bf16(
    const float* __restrict__ X, const float* __restrict__ G,
    const float* __restrict__ Bt, __hip_bfloat16* __restrict__ O) {
  long row = blockIdx.x;
  int t = threadIdx.x;
  const float4 xv = ((const float4*)(X + row * 1024))[t];
  float s = xv.x + xv.y + xv.z + xv.w;
  float q = xv.x * xv.x + xv.y * xv.y + xv.z * xv.z + xv.w * xv.w;
#pragma unroll
  for (int o = 32; o; o >>= 1) {
    s += __shfl_xor(s, o);
    q += __shfl_xor(q, o);
  }
  __shared__ float rs[4], rq[4];
  int wid = t >> 6;
  if ((t & 63) == 0) { rs[wid] = s; rq[wid] = q; }
  __syncthreads();
  s = rs[0] + rs[1] + rs[2] + rs[3];
  q = rq[0] + rq[1] + rq[2] + rq[3];
  float mean = s * (1.f / 1024.f);
  float var = q * (1.f / 1024.f) - mean * mean;
  float rstd = rsqrtf(var + 1e-5f);
  const float4 gv = ((const float4*)G)[t];
  const float4 bv = ((const float4*)Bt)[t];
  __hip_bfloat16* o = O + row * 1024 + t * 4;
  o[0] = __float2bfloat16((xv.x - mean) * rstd * gv.x + bv.x);
  o[1] = __float2bfloat16((xv.y - mean) * rstd * gv.y + bv.y);
  o[2] = __float2bfloat16((xv.z - mean) * rstd * gv.z + bv.z);
  o[3] = __float2bfloat16((xv.w - mean) * rstd * gv.w + bv.w);
}

// ---------------------------------------------------------------------------
// Batched weight transpose-convert: 7x f32 [1024,1024] -> bf16 [1024,1024]^T
// with per-matrix scale. grid (32, 32, 7).
// ---------------------------------------------------------------------------
struct TC7 {
  const float* in[7];
  __hip_bfloat16* out[7];
  float scale[7];
};
__global__ __launch_bounds__(256) void tconv7(TC7 p) {
  __shared__ float t[32][33];
  int j = blockIdx.z;
  const float* in = p.in[j];
  __hip_bfloat16* out = p.out[j];
  float sc = p.scale[j];
  int c0 = blockIdx.x * 32, r0 = blockIdx.y * 32;
  int tid = threadIdx.x;
  int lr = tid >> 3, lc = (tid & 7) * 4;
  const float4 v = *(const float4*)&in[(long)(r0 + lr) * 1024 + c0 + lc];
  t[lr][lc] = v.x; t[lr][lc + 1] = v.y; t[lr][lc + 2] = v.z; t[lr][lc + 3] = v.w;
  __syncthreads();
  int oc = tid >> 3, orr = (tid & 7) * 4;
  __hip_bfloat16* o = &out[(long)(c0 + oc) * 1024 + r0 + orr];
  o[0] = __float2bfloat16(t[orr][oc] * sc);
  o[1] = __float2bfloat16(t[orr + 1][oc] * sc);
  o[2] = __float2bfloat16(t[orr + 2][oc] * sc);
  o[3] = __float2bfloat16(t[orr + 3][oc] * sc);
}

// Generic transpose-convert f32 [R,C] -> bf16 [C,R]. grid (C/32, R/32).
__global__ __launch_bounds__(256) void tconv_f32_bf16(
    const float* __restrict__ in, __hip_bfloat16* __restrict__ out, int R,
    int C) {
  __shared__ float t[32][33];
  int c0 = blockIdx.x * 32, r0 = blockIdx.y * 32;
  int tid = threadIdx.x;
  int lr = tid >> 3, lc = (tid & 7) * 4;
  const float4 v = *(const float4*)&in[(long)(r0 + lr) * C + c0 + lc];
  t[lr][lc] = v.x; t[lr][lc + 1] = v.y; t[lr][lc + 2] = v.z; t[lr][lc + 3] = v.w;
  __syncthreads();
  int oc = tid >> 3, orr = (tid & 7) * 4;
  __hip_bfloat16* o = &out[(long)(c0 + oc) * R + r0 + orr];
  o[0] = __float2bfloat16(t[orr][oc]);
  o[1] = __float2bfloat16(t[orr + 1][oc]);
  o[2] = __float2bfloat16(t[orr + 2][oc]);
  o[3] = __float2bfloat16(t[orr + 3][oc]);
}

// Batched bf16 transpose with strided input: in [bz] rows R x cols C at
// row-stride ldin, batch-stride sIn -> out packed [bz][C][R].
__global__ __launch_bounds__(256) void tconv_bf16(
    const __hip_bfloat16* __restrict__ in, __hip_bfloat16* __restrict__ out,
    int R, int C, int ldin, long sIn) {
  __shared__ __hip_bfloat16 t[32][34];
  int bz = blockIdx.z;
  long ibase = (long)bz * sIn;
  long obase = (long)bz * R * C;
  int c0 = blockIdx.x * 32, r0 = blockIdx.y * 32;
  int tid = threadIdx.x;
  int lr = tid >> 3, lc = (tid & 7) * 4;
  const __hip_bfloat16* ip = &in[ibase + (long)(r0 + lr) * ldin + c0 + lc];
  t[lr][lc] = ip[0]; t[lr][lc + 1] = ip[1]; t[lr][lc + 2] = ip[2]; t[lr][lc + 3] = ip[3];
  __syncthreads();
  int oc = tid >> 3, orr = (tid & 7) * 4;
  __hip_bfloat16* o = &out[obase + (long)(c0 + oc) * R + r0 + orr];
  o[0] = t[orr][oc];
  o[1] = t[orr + 1][oc];
  o[2] = t[orr + 2][oc];
  o[3] = t[orr + 3][oc];
}

// o = a + b (float4 per thread)
__global__ __launch_bounds__(256) void add2(const float* __restrict__ a,
                                            const float* __restrict__ b,
                                            float* __restrict__ o) {
  int i = blockIdx.x * 256 + threadIdx.x;
  float4 av = ((const float4*)a)[i], bv = ((const float4*)b)[i];
  float4 ov;
  ov.x = av.x + bv.x; ov.y = av.y + bv.y;
  ov.z = av.z + bv.z; ov.w = av.w + bv.w;
  ((float4*)o)[i] = ov;
}

// concat 6 bias vectors (x1024) with per-segment scale -> bias6[6144]
struct BC6 {
  const float* b[6];
  float scale[6];
};
__global__ __launch_bounds__(256) void bias_concat(BC6 p, float* __restrict__ o) {
  int idx = blockIdx.x * 256 + threadIdx.x;  // 0..6143
  int j = idx >> 10, e = idx & 1023;
  o[idx] = p.b[j][e] * p.scale[j];
}

// ---------------------------------------------------------------------------
// bf16 MFMA GEMM (NT): C = alpha*(A@Bt^T + bias) + E1 + E2, opt. exact GELU.
// 128x128 tile, BK=32, 256 thr = 4 waves (2x2), each wave 64x64 = 4x4 frags.
// ---------------------------------------------------------------------------
__global__ __launch_bounds__(256) void gemm_bf16_nt(
    const __hip_bfloat16* __restrict__ A, const __hip_bfloat16* __restrict__ Bt,
    const float* __restrict__ bias, const float* __restrict__ E1,
    const float* __restrict__ E2, void* __restrict__ C, int K, int lda,
    int ldb, int ldc, long sA, long sB, long sC, long sE, float alpha, int act,
    int obf) {
  __shared__ unsigned short AsU[128 * 32];
  __shared__ unsigned short BsU[128 * 32];
  const int tid = threadIdx.x;
  const int lane = tid & 63, wave = tid >> 6;
  const int wr = wave >> 1, wc = wave & 1;
  const int m0 = blockIdx.y * 128, n0 = blockIdx.x * 128;
  const int bz = blockIdx.z;
  const char* Ab = (const char*)(A + (long)bz * sA);
  const char* Bb = (const char*)(Bt + (long)bz * sB);

  f32x4 acc[4][4];
#pragma unroll
  for (int m = 0; m < 4; ++m)
#pragma unroll
    for (int n = 0; n < 4; ++n) acc[m][n] = (f32x4){0.f, 0.f, 0.f, 0.f};

  const int srow = tid >> 2;
  const int scol = (tid & 3) * 16;
  const int wbase = (tid >> 6) * 1024;

  for (int k0 = 0; k0 < K; k0 += 32) {
#pragma unroll
    for (int i = 0; i < 2; ++i) {
      async_copy16((char*)AsU + i * 4096 + wbase,
                   Ab + ((long)(m0 + i * 64 + srow) * lda + k0) * 2 + scol);
      async_copy16((char*)BsU + i * 4096 + wbase,
                   Bb + ((long)(n0 + i * 64 + srow) * ldb + k0) * 2 + scol);
    }
    __syncthreads();

    const int koff = (lane >> 4) * 8;
    bf16x8 a[4], b[4];
#pragma unroll
    for (int m = 0; m < 4; ++m)
      a[m] = *(const bf16x8*)&AsU[(wr * 64 + m * 16 + (lane & 15)) * 32 + koff];
#pragma unroll
    for (int n = 0; n < 4; ++n)
      b[n] = *(const bf16x8*)&BsU[(wc * 64 + n * 16 + (lane & 15)) * 32 + koff];
#pragma unroll
    for (int m = 0; m < 4; ++m)
#pragma unroll
      for (int n = 0; n < 4; ++n)
        acc[m][n] = __builtin_amdgcn_mfma_f32_16x16x32_bf16(a[m], b[n],
                                                            acc[m][n], 0, 0, 0);
    __syncthreads();
  }

#pragma unroll
  for (int m = 0; m < 4; ++m) {
    int row = m0 + wr * 64 + m * 16 + (lane >> 4) * 4;
#pragma unroll
    for (int n = 0; n < 4; ++n) {
      int col = n0 + wc * 64 + n * 16 + (lane & 15);
      float bs = bias ? bias[col] : 0.f;
#pragma unroll
      for (int r = 0; r < 4; ++r) {
        float v = (acc[m][n][r] + bs) * alpha;
        long eidx = (long)bz * sE + (long)(row + r) * ldc + col;
        if (E1) v += E1[eidx];
        if (E2) v += E2[eidx];
        if (act) v = v * 0.5f * (1.f + erff(v * 0.70710678118f));
        long cidx = (long)bz * sC + (long)(row + r) * ldc + col;
        if (obf)
          ((__hip_bfloat16*)C)[cidx] = __float2bfloat16(v);
        else
          ((float*)C)[cidx] = v;
      }
    }
  }
}

// ---------------------------------------------------------------------------
// MFMA attention. Block = (i-tile of 32, h, b); 4 waves.
// Q,K bf16 strided (ldqk); VT bf16 [B,1024,512]; BM f32 [B,S,S]; O packed 1024.
// ---------------------------------------------------------------------------
__global__ __launch_bounds__(256) void attn_mfma(
    const __hip_bfloat16* __restrict__ Q, const __hip_bfloat16* __restrict__ K,
    const __hip_bfloat16* __restrict__ VT, const float* __restrict__ BM,
    __hip_bfloat16* __restrict__ O, int ldqk) {
  __shared__ __hip_bfloat16 P[32][520];  // row stride 1040B
  __shared__ float red[2][32][4];
  const int it = blockIdx.x, h = blockIdx.y, b = blockIdx.z;
  const int i0 = it * 32;
  const int tid = threadIdx.x;
  const int lane = tid & 63, w = tid >> 6;
  const int lh = lane >> 4, ll = lane & 15;

  const long qkb = (long)b * 512 * ldqk + h * 64;

  bf16x8 a[2][2];
#pragma unroll
  for (int m = 0; m < 2; ++m)
#pragma unroll
    for (int ks = 0; ks < 2; ++ks)
      a[m][ks] = *(const bf16x8*)&Q[qkb + (long)(i0 + m * 16 + ll) * ldqk +
                                    ks * 32 + lh * 8];

  f32x4 acc[2][8];
#pragma unroll
  for (int m = 0; m < 2; ++m)
#pragma unroll
    for (int n = 0; n < 8; ++n) acc[m][n] = (f32x4){0.f, 0.f, 0.f, 0.f};

#pragma unroll
  for (int n = 0; n < 8; ++n) {
    const __hip_bfloat16* kp =
        &K[qkb + (long)(w * 128 + n * 16 + ll) * ldqk + lh * 8];
    bf16x8 b0 = *(const bf16x8*)&kp[0];
    bf16x8 b1 = *(const bf16x8*)&kp[32];
#pragma unroll
    for (int m = 0; m < 2; ++m) {
      acc[m][n] =
          __builtin_amdgcn_mfma_f32_16x16x32_bf16(a[m][0], b0, acc[m][n], 0, 0, 0);
      acc[m][n] =
          __builtin_amdgcn_mfma_f32_16x16x32_bf16(a[m][1], b1, acc[m][n], 0, 0, 0);
    }
  }

  const float* bmb = BM + ((long)b * 512 + i0) * 512 + w * 128;
#pragma unroll
  for (int m = 0; m < 2; ++m)
#pragma unroll
    for (int r = 0; r < 4; ++r) {
      int row = m * 16 + lh * 4 + r;
#pragma unroll
      for (int n = 0; n < 8; ++n)
        acc[m][n][r] += bmb[(long)row * 512 + n * 16 + ll];
    }

  float rmax[2][4];
#pragma unroll
  for (int m = 0; m < 2; ++m)
#pragma unroll
    for (int r = 0; r < 4; ++r) {
      float v = acc[m][0][r];
#pragma unroll
      for (int n = 1; n < 8; ++n) v = fmaxf(v, acc[m][n][r]);
#pragma unroll
      for (int o = 1; o < 16; o <<= 1) v = fmaxf(v, __shfl_xor(v, o));
      rmax[m][r] = v;
    }
  if (ll == 0) {
#pragma unroll
    for (int m = 0; m < 2; ++m)
#pragma unroll
      for (int r = 0; r < 4; ++r) red[0][m * 16 + lh * 4 + r][w] = rmax[m][r];
  }
  __syncthreads();
#pragma unroll
  for (int m = 0; m < 2; ++m)
#pragma unroll
    for (int r = 0; r < 4; ++r) {
      const float* p = red[0][m * 16 + lh * 4 + r];
      rmax[m][r] = fmaxf(fmaxf(p[0], p[1]), fmaxf(p[2], p[3]));
    }
  float rsum[2][4];
#pragma unroll
  for (int m = 0; m < 2; ++m)
#pragma unroll
    for (int r = 0; r < 4; ++r) {
      float s = 0.f;
#pragma unroll
      for (int n = 0; n < 8; ++n) {
        float e = __expf(acc[m][n][r] - rmax[m][r]);
        acc[m][n][r] = e;
        s += e;
      }
#pragma unroll
      for (int o = 1; o < 16; o <<= 1) s += __shfl_xor(s, o);
      rsum[m][r] = s;
    }
  if (ll == 0) {
#pragma unroll
    for (int m = 0; m < 2; ++m)
#pragma unroll
      for (int r = 0; r < 4; ++r) red[1][m * 16 + lh * 4 + r][w] = rsum[m][r];
  }
  __syncthreads();
#pragma unroll
  for (int m = 0; m < 2; ++m)
#pragma unroll
    for (int r = 0; r < 4; ++r) {
      const float* p = red[1][m * 16 + lh * 4 + r];
      float inv = 1.f / (p[0] + p[1] + p[2] + p[3]);
      int row = m * 16 + lh * 4 + r;
#pragma unroll
      for (int n = 0; n < 8; ++n)
        P[row][w * 128 + n * 16 + ll] = __float2bfloat16(acc[m][n][r] * inv);
    }
  __syncthreads();

  const long vtb = ((long)b * 1024 + h * 64) * 512;
  const long ob = (long)b * 512 * 1024 + h * 64;
  const int mw = (w >> 1) * 16, nw = (w & 1) * 32;
  f32x4 oacc[2];
  oacc[0] = (f32x4){0.f, 0.f, 0.f, 0.f};
  oacc[1] = (f32x4){0.f, 0.f, 0.f, 0.f};
#pragma unroll
  for (int ks = 0; ks < 16; ++ks) {
    int k0 = ks * 32;
    bf16x8 pa = *(const bf16x8*)&P[mw + ll][k0 + lh * 8];
#pragma unroll
    for (int nf = 0; nf < 2; ++nf) {
      bf16x8 vb = *(const bf16x8*)&VT[vtb + (long)(nw + nf * 16 + ll) * 512 +
                                      k0 + lh * 8];
      oacc[nf] =
          __builtin_amdgcn_mfma_f32_16x16x32_bf16(pa, vb, oacc[nf], 0, 0, 0);
    }
  }
#pragma unroll
  for (int nf = 0; nf < 2; ++nf)
#pragma unroll
    for (int r = 0; r < 4; ++r)
      O[ob + (long)(i0 + mw + lh * 4 + r) * 1024 + nw + nf * 16 + ll] =
          __float2bfloat16(oacc[nf][r]);
}

// ---------------------------------------------------------------------------
// Row softmax (512) f32 in -> bf16 out. One block per row.
// ---------------------------------------------------------------------------
__global__ __launch_bounds__(256) void softmax_rows(
    const float* __restrict__ P, __hip_bfloat16* __restrict__ Ob) {
  const float* row = P + (long)blockIdx.x * 512;
  __hip_bfloat16* orow = Ob + (long)blockIdx.x * 512;
  int t = threadIdx.x;
  float v0 = row[t], v1 = row[t + 256];
  float m = fmaxf(v0, v1);
#pragma unroll
  for (int o = 32; o; o >>= 1) m = fmaxf(m, __shfl_xor(m, o));
  __shared__ float red[8];
  int wid = t >> 6, lane = t & 63;
  if (!lane) red[wid] = m;
  __syncthreads();
  m = fmaxf(fmaxf(red[0], red[1]), fmaxf(red[2], red[3]));
  float e0 = __expf(v0 - m), e1 = __expf(v1 - m);
  float s = e0 + e1;
#pragma unroll
  for (int o = 32; o; o >>= 1) s += __shfl_xor(s, o);
  if (!lane) red[4 + wid] = s;
  __syncthreads();
  s = red[4] + red[5] + red[6] + red[7];
  float inv = 1.f / s;
  orow[t] = __float2bfloat16(e0 * inv);
  orow[t + 256] = __float2bfloat16(e1 * inv);
}

// ---------------------------------------------------------------------------
// path gather-mean, parallel over i-chunks. grid (8 b, 4 hc, 8 ic), 256 thr.
// Partials: PP[b][ic][h]; counts: WS[b][ic] (written by hc==0 blocks).
// ---------------------------------------------------------------------------
__global__ __launch_bounds__(256) void path_partial(
    const float* __restrict__ xp, const int* __restrict__ pp,
    float* __restrict__ PP, float* __restrict__ WS) {
  int b = blockIdx.x, hc = blockIdx.y, ic = blockIdx.z;
  int h = hc * 256 + threadIdx.x;
  const int* ppb = pp + b * 512;
  const float* xb = xp + (long)b * 512 * 1024;
  int iA = ic * 64, iB = iA + 64;
  float acc = 0.f;
  for (int i = iA; i < iB; ++i) {
    if (ppb[i] != 1) continue;
    float cur = xb[(long)i * 1024 + h];
    float a;
    if (i == 0) {
      a = 0.5f * (cur + xb[1024 + h]);
    } else if (i == 1) {
      a = (xb[h] + cur + xb[2 * 1024 + h]) * (1.f / 3.f);
    } else {
      int inx = (i + 1 < 512) ? i + 1 : 511;
      float nx = xb[(long)inx * 1024 + h];
      if (ppb[i - 2] == 1) {
        a = 0.5f * (cur + nx);
      } else {
        a = (xb[(long)(i - 1) * 1024 + h] + cur + nx) * (1.f / 3.f);
      }
    }
    acc += a;
  }
  PP[((long)b * 8 + ic) * 1024 + h] = acc;
  if (hc == 0 && threadIdx.x == 0) {
    float c = 0.f;
    for (int i = iA; i < iB; ++i) c += (ppb[i] == 1) ? 1.f : 0.f;
    WS[b * 8 + ic] = c;
  }
}

// finalize: PATH[b][h] = sum_ic PP / sum_ic WS. grid (8, 4) x 256.
__global__ __launch_bounds__(256) void path_finalize(
    const float* __restrict__ PP, const float* __restrict__ WS,
    float* __restrict__ PATH) {
  int b = blockIdx.x;
  int h = blockIdx.y * 256 + threadIdx.x;
  float s = 0.f, w = 0.f;
#pragma unroll
  for (int ic = 0; ic < 8; ++ic) {
    s += PP[((long)b * 8 + ic) * 1024 + h];
    w += WS[b * 8 + ic];
  }
  PATH[b * 1024 + h] = s / w;
}

__global__ __launch_bounds__(256) void combine(const float* __restrict__ X,
                                               const float* __restrict__ YS,
                                               const float* __restrict__ PT,
                                               float* __restrict__ X2) {
  int i = blockIdx.x * 256 + threadIdx.x;
  const float4 xv = ((const float4*)X)[i];
  const float4 sv = ((const float4*)YS)[i];
  int e = i * 4;
  int b = e >> 19;
  int h = e & 1023;
  const float4 pv = *(const float4*)(PT + b * 1024 + h);
  float4 o;
  o.x = xv.x + 0.5f * (sv.x + pv.x);
  o.y = xv.y + 0.5f * (sv.y + pv.y);
  o.z = xv.z + 0.5f * (sv.z + pv.z);
  o.w = xv.w + 0.5f * (sv.w + pv.w);
  ((float4*)X2)[i] = o;
}

// ---------------------------------------------------------------------------
extern "C" void kernel_launch(void* const* d_in, const int* in_sizes, int n_in,
                              void* d_out, int out_size, void* d_ws,
                              size_t ws_size, hipStream_t stream) {
  const float* x = (const float*)d_in[0];
  const int* pp = (const int*)d_in[1];
  const float* abias = (const float*)d_in[3];
  const float* amask = (const float*)d_in[4];
  const float* agraph = (const float*)d_in[5];
  const float* vgraph = (const float*)d_in[6];
  const float* ln1g = (const float*)d_in[7];
  const float* ln1b = (const float*)d_in[8];
  const float* wq = (const float*)d_in[9];
  const float* bq = (const float*)d_in[10];
  const float* wk = (const float*)d_in[11];
  const float* bk = (const float*)d_in[12];
  const float* wv = (const float*)d_in[13];
  const float* bv = (const float*)d_in[14];
  const float* wo = (const float*)d_in[15];
  const float* bo = (const float*)d_in[16];
  const float* pqw = (const float*)d_in[17];
  const float* pqb = (const float*)d_in[18];
  const float* pkw = (const float*)d_in[19];
  const float* pkb = (const float*)d_in[20];
  const float* pvw = (const float*)d_in[21];
  const float* pvb = (const float*)d_in[22];
  const float* ln2g = (const float*)d_in[23];
  const float* ln2b = (const float*)d_in[24];
  const float* w1 = (const float*)d_in[25];
  const float* b1 = (const float*)d_in[26];
  const float* w2 = (const float*)d_in[27];
  const float* b2 = (const float*)d_in[28];

  char* wsb = (char*)d_ws;
  // layout (MB offsets):
  auto Ybf = (__hip_bfloat16*)(wsb);                  // 0-8 (later Y2b)
  auto QKV = (__hip_bfloat16*)(wsb + (8l << 20));     // 8-56: [4096][6144]
  auto VTb = (__hip_bfloat16*)(wsb + (56l << 20));    // 56-64
  auto PVT = (__hip_bfloat16*)(wsb + (64l << 20));    // 64-72
  auto ATTb = (__hip_bfloat16*)(wsb + (72l << 20));   // 72-80 (later W2T)
  auto BM = (float*)(wsb + (80l << 20));              // 80-88
  auto PATTb = (__hip_bfloat16*)(wsb + (88l << 20));  // 88-92
  auto PATTf = (float*)(wsb + (92l << 20));           // 92-100
  auto XP = (float*)(wsb + (92l << 20));              // 92-108
  auto WALL = (__hip_bfloat16*)(wsb + (108l << 20));  // 108-120: [6144][1024]
  auto WOT = (__hip_bfloat16*)(wsb + (120l << 20));   // 120-122
  auto W1T = (__hip_bfloat16*)(wsb + (122l << 20));   // 122-130
  auto bias6 = (float*)(wsb + (130l << 20));          // 24KB
  auto PPart = (float*)(wsb + (131l << 20));          // 256KB
  auto WSp = (float*)(wsb + (132l << 20));            // 256B
  auto PATH = (float*)(wsb + (133l << 20));           // 32KB
  // overlays (QKV dead after step 5; ATTb dead after step 8):
  auto YSELF = (float*)(wsb + (8l << 20));            // 8-24
  auto X2 = (float*)(wsb + (24l << 20));              // 24-40
  auto HMID = (__hip_bfloat16*)(wsb + (40l << 20));   // 40-72
  auto W2T = ATTb;
  __hip_bfloat16* Y2b = Ybf;
  float* OUT = (float*)d_out;

  const float qscale = 0.125f;
  const float pscale = 0.03125f;
  const long S2 = 512l * 512;
  const long SQ = 512l * 6144;  // per-batch row-block of QKV

  // QKV column bases
  __hip_bfloat16* Qp = QKV;
  __hip_bfloat16* Kp = QKV + 1024;
  __hip_bfloat16* Vp = QKV + 2048;
  __hip_bfloat16* PQp = QKV + 3072;
  __hip_bfloat16* PKp = QKV + 4096;
  __hip_bfloat16* PVp = QKV + 5120;

  // 0) batched weight transposes: {wq,wk,wv,pqw,pkw,pvw} -> WALL (pre-scaled),
  //    wo -> WOT. w1 / w2 separate shapes.
  TC7 tp;
  tp.in[0] = wq;  tp.out[0] = WALL;                 tp.scale[0] = qscale;
  tp.in[1] = wk;  tp.out[1] = WALL + 1024 * 1024;   tp.scale[1] = 1.f;
  tp.in[2] = wv;  tp.out[2] = WALL + 2048 * 1024;   tp.scale[2] = 1.f;
  tp.in[3] = pqw; tp.out[3] = WALL + 3072 * 1024;   tp.scale[3] = pscale;
  tp.in[4] = pkw; tp.out[4] = WALL + 4096 * 1024;   tp.scale[4] = 1.f;
  tp.in[5] = pvw; tp.out[5] = WALL + 5120 * 1024;   tp.scale[5] = 1.f;
  tp.in[6] = wo;  tp.out[6] = WOT;                  tp.scale[6] = 1.f;
  tconv7<<<dim3(32, 32, 7), 256, 0, stream>>>(tp);
  tconv_f32_bf16<<<dim3(128, 32), 256, 0, stream>>>(w1, W1T, 1024, 4096);

  BC6 bp;
  bp.b[0] = bq;  bp.scale[0] = qscale;
  bp.b[1] = bk;  bp.scale[1] = 1.f;
  bp.b[2] = bv;  bp.scale[2] = 1.f;
  bp.b[3] = pqb; bp.scale[3] = pscale;
  bp.b[4] = pkb; bp.scale[4] = 1.f;
  bp.b[5] = pvb; bp.scale[5] = 1.f;
  bias_concat<<<24, 256, 0, stream>>>(bp, bias6);

  // 0b) merged attention bias
  add2<<<2048, 256, 0, stream>>>(abias, amask, BM);

  // 1) LN1 -> Ybf
  ln_rows_bf16<<<4096, 256, 0, stream>>>(x, ln1g, ln1b, Ybf);

  // 2) fused projections: QKV = Ybf @ WALL^T + bias6 (M=4096,N=6144,K=1024)
  gemm_bf16_nt<<<dim3(48, 32, 1), 256, 0, stream>>>(
      Ybf, WALL, bias6, nullptr, nullptr, QKV, 1024, 1024, 1024, 6144, 0, 0, 0,
      0, 1.f, 0, 1);

  // 3) transposes: V -> VT, PV -> PVT ([512 x 1024]@ld6144 -> [1024][512])
  tconv_bf16<<<dim3(32, 16, 8), 256, 0, stream>>>(Vp, VTb, 512, 1024, 6144, SQ);
  tconv_bf16<<<dim3(32, 16, 8), 256, 0, stream>>>(PVp, PVT, 512, 1024, 6144, SQ);

  // 4) path scores + softmax
  gemm_bf16_nt<<<dim3(4, 4, 8), 256, 0, stream>>>(
      PQp, PKp, nullptr, agraph, vgraph, PATTf, 1024, 6144, 6144, 512, SQ, SQ,
      S2, S2, 1.f, 0, 0);
  softmax_rows<<<4096, 256, 0, stream>>>(PATTf, PATTb);

  // 5) MFMA attention -> ATTb
  attn_mfma<<<dim3(16, 16, 8), 256, 0, stream>>>(Qp, Kp, VTb, BM, ATTb, 6144);

  // 6) XP = PATT @ PVT^T
  gemm_bf16_nt<<<dim3(8, 4, 8), 256, 0, stream>>>(
      PATTb, PVT, nullptr, nullptr, nullptr, XP, 512, 512, 512, 1024, S2,
      512l * 1024, 512l * 1024, 0, 1.f, 0, 0);

  // 7) path gather-mean (parallel) + finalize
  path_partial<<<dim3(8, 4, 8), 256, 0, stream>>>(XP, pp, PPart, WSp);
  path_finalize<<<dim3(8, 4), 256, 0, stream>>>(PPart, WSp, PATH);

  // 8) y_self = ATT @ wo + bo (f32, overlays QKV region)
  gemm_bf16_nt<<<dim3(8, 32, 1), 256, 0, stream>>>(
      ATTb, WOT, bo, nullptr, nullptr, YSELF, 1024, 1024, 1024, 1024, 0, 0, 0,
      0, 1.f, 0, 0);

  // 8b) W2 transpose into ATTb's slot (ATTb now dead)
  tconv_f32_bf16<<<dim3(32, 128), 256, 0, stream>>>(w2, W2T, 4096, 1024);

  // 9) X2 = x + 0.5*(YSELF + PATH)
  combine<<<4096, 256, 0, stream>>>(x, YSELF, PATH, X2);

  // 10) LN2 -> Y2b
  ln_rows_bf16<<<4096, 256, 0, stream>>>(X2, ln2g, ln2b, Y2b);

  // 11) FFN1: HMID = gelu(Y2@w1+b1) bf16
  gemm_bf16_nt<<<dim3(32, 32, 1), 256, 0, stream>>>(
      Y2b, W1T, b1, nullptr, nullptr, HMID, 1024, 1024, 1024, 4096, 0, 0, 0, 0,
      1.f, 1, 1);

  // 12) FFN2: OUT = HMID@w2 + b2 + X2
  gemm_bf16_nt<<<dim3(8, 32, 1), 256, 0, stream>>>(
      HMID, W2T, b2, X2, nullptr, OUT, 4096, 4096, 4096, 1024, 0, 0, 0, 0, 1.f,
      0, 0);
}

// Round 6
// 531.087 us; speedup vs baseline: 9.5468x; 1.0505x over previous
//
#include <hip/hip_runtime.h>
#include <hip/hip_bf16.h>
#include <math.h>

// B=8, S=512, H=1024, NH=16, DK=64, FF=4096.
// Round 6: (1) gemm256 (256-row tile, BK=64, 8 waves, 1 barrier/tile,
// issue-early staging, setprio) for QKV + FFN1; (2) XCD-chunked swizzle in
// both GEMMs; (3) drop add2 (attn reads bias+mask), fuse combine+LN2.

typedef __bf16 bf16x8 __attribute__((ext_vector_type(8)));
typedef float f32x4 __attribute__((ext_vector_type(4)));

__device__ __forceinline__ void async_copy16(void* lds, const void* g) {
  __builtin_amdgcn_global_load_lds(
      (__attribute__((address_space(1))) void*)(void*)g,
      (__attribute__((address_space(3))) void*)lds, 16, 0, 0);
}

// ---------------------------------------------------------------------------
// LayerNorm over last dim (1024) -> bf16. One block (256 thr) per row.
// ---------------------------------------------------------------------------
__global__ __launch_bounds__(256) void ln_rows_bf16(
    const float* __restrict__ X, const float* __restrict__ G,
    const float* __restrict__ Bt, __hip_bfloat16* __restrict__ O) {
  long row = blockIdx.x;
  int t = threadIdx.x;
  const float4 xv = ((const float4*)(X + row * 1024))[t];
  float s = xv.x + xv.y + xv.z + xv.w;
  float q = xv.x * xv.x + xv.y * xv.y + xv.z * xv.z + xv.w * xv.w;
#pragma unroll
  for (int o = 32; o; o >>= 1) {
    s += __shfl_xor(s, o);
    q += __shfl_xor(q, o);
  }
  __shared__ float rs[4], rq[4];
  int wid = t >> 6;
  if ((t & 63) == 0) { rs[wid] = s; rq[wid] = q; }
  __syncthreads();
  s = rs[0] + rs[1] + rs[2] + rs[3];
  q = rq[0] + rq[1] + rq[2] + rq[3];
  float mean = s * (1.f / 1024.f);
  float var = q * (1.f / 1024.f) - mean * mean;
  float rstd = rsqrtf(var + 1e-5f);
  const float4 gv = ((const float4*)G)[t];
  const float4 bv = ((const float4*)Bt)[t];
  __hip_bfloat16* o = O + row * 1024 + t * 4;
  o[0] = __float2bfloat16((xv.x - mean) * rstd * gv.x + bv.x);
  o[1] = __float2bfloat16((xv.y - mean) * rstd * gv.y + bv.y);
  o[2] = __float2bfloat16((xv.z - mean) * rstd * gv.z + bv.z);
  o[3] = __float2bfloat16((xv.w - mean) * rstd * gv.w + bv.w);
}

// ---------------------------------------------------------------------------
// Batched weight transpose-convert: 7x f32 [1024,1024] -> bf16 ^T w/ scale.
// ---------------------------------------------------------------------------
struct TC7 {
  const float* in[7];
  __hip_bfloat16* out[7];
  float scale[7];
};
__global__ __launch_bounds__(256) void tconv7(TC7 p) {
  __shared__ float t[32][33];
  int j = blockIdx.z;
  const float* in = p.in[j];
  __hip_bfloat16* out = p.out[j];
  float sc = p.scale[j];
  int c0 = blockIdx.x * 32, r0 = blockIdx.y * 32;
  int tid = threadIdx.x;
  int lr = tid >> 3, lc = (tid & 7) * 4;
  const float4 v = *(const float4*)&in[(long)(r0 + lr) * 1024 + c0 + lc];
  t[lr][lc] = v.x; t[lr][lc + 1] = v.y; t[lr][lc + 2] = v.z; t[lr][lc + 3] = v.w;
  __syncthreads();
  int oc = tid >> 3, orr = (tid & 7) * 4;
  __hip_bfloat16* o = &out[(long)(c0 + oc) * 1024 + r0 + orr];
  o[0] = __float2bfloat16(t[orr][oc] * sc);
  o[1] = __float2bfloat16(t[orr + 1][oc] * sc);
  o[2] = __float2bfloat16(t[orr + 2][oc] * sc);
  o[3] = __float2bfloat16(t[orr + 3][oc] * sc);
}

// Generic transpose-convert f32 [R,C] -> bf16 [C,R]. grid (C/32, R/32).
__global__ __launch_bounds__(256) void tconv_f32_bf16(
    const float* __restrict__ in, __hip_bfloat16* __restrict__ out, int R,
    int C) {
  __shared__ float t[32][33];
  int c0 = blockIdx.x * 32, r0 = blockIdx.y * 32;
  int tid = threadIdx.x;
  int lr = tid >> 3, lc = (tid & 7) * 4;
  const float4 v = *(const float4*)&in[(long)(r0 + lr) * C + c0 + lc];
  t[lr][lc] = v.x; t[lr][lc + 1] = v.y; t[lr][lc + 2] = v.z; t[lr][lc + 3] = v.w;
  __syncthreads();
  int oc = tid >> 3, orr = (tid & 7) * 4;
  __hip_bfloat16* o = &out[(long)(c0 + oc) * R + r0 + orr];
  o[0] = __float2bfloat16(t[orr][oc]);
  o[1] = __float2bfloat16(t[orr + 1][oc]);
  o[2] = __float2bfloat16(t[orr + 2][oc]);
  o[3] = __float2bfloat16(t[orr + 3][oc]);
}

// Batched bf16 transpose, strided input -> packed [bz][C][R].
__global__ __launch_bounds__(256) void tconv_bf16(
    const __hip_bfloat16* __restrict__ in, __hip_bfloat16* __restrict__ out,
    int R, int C, int ldin, long sIn) {
  __shared__ __hip_bfloat16 t[32][34];
  int bz = blockIdx.z;
  long ibase = (long)bz * sIn;
  long obase = (long)bz * R * C;
  int c0 = blockIdx.x * 32, r0 = blockIdx.y * 32;
  int tid = threadIdx.x;
  int lr = tid >> 3, lc = (tid & 7) * 4;
  const __hip_bfloat16* ip = &in[ibase + (long)(r0 + lr) * ldin + c0 + lc];
  t[lr][lc] = ip[0]; t[lr][lc + 1] = ip[1]; t[lr][lc + 2] = ip[2]; t[lr][lc + 3] = ip[3];
  __syncthreads();
  int oc = tid >> 3, orr = (tid & 7) * 4;
  __hip_bfloat16* o = &out[obase + (long)(c0 + oc) * R + r0 + orr];
  o[0] = t[orr][oc];
  o[1] = t[orr + 1][oc];
  o[2] = t[orr + 2][oc];
  o[3] = t[orr + 3][oc];
}

// concat 6 bias vectors (x1024) with per-segment scale -> bias6[6144]
struct BC6 {
  const float* b[6];
  float scale[6];
};
__global__ __launch_bounds__(256) void bias_concat(BC6 p, float* __restrict__ o) {
  int idx = blockIdx.x * 256 + threadIdx.x;
  int j = idx >> 10, e = idx & 1023;
  o[idx] = p.b[j][e] * p.scale[j];
}

// ---------------------------------------------------------------------------
// gemm256<BN>: C = A@Bt^T + bias (opt GELU), bf16 or f32 out. BM=256, BK=64,
// 512 thr = 8 waves (2M x 4N). Double-buffered LDS, stage(t+1) issued at
// start of tile t, ONE vmcnt(0)+barrier per tile. XCD-chunked swizzle.
// ---------------------------------------------------------------------------
template <int BN>
__global__ __launch_bounds__(512, 2) void gemm256(
    const __hip_bfloat16* __restrict__ A, const __hip_bfloat16* __restrict__ Bt,
    const float* __restrict__ bias, void* __restrict__ C, int K, int lda,
    int ldb, int ldc, int act, int obf) {
  constexpr int NR = BN / 64;          // n-frags per wave
  constexpr int ABYTES = 256 * 128;    // 32KB per A buffer
  constexpr int BBYTES = BN * 128;     // per B buffer
  constexpr int BUF = ABYTES + BBYTES;
  __shared__ char lds[2 * BUF];

  // XCD-chunked bijective swizzle (nwg % 8 == 0 at all call sites)
  int nwg = gridDim.x * gridDim.y;
  int wg = blockIdx.y * gridDim.x + blockIdx.x;
  int cpx = nwg >> 3;
  int sw = (wg & 7) * cpx + (wg >> 3);
  int bx = sw % gridDim.x, by = sw / gridDim.x;
  const int m0 = by * 256, n0 = bx * BN;

  const int tid = threadIdx.x;
  const int lane = tid & 63, wid = tid >> 6;
  const int wm = wid >> 2, wn = wid & 3;
  const int ll = lane & 15, lh = lane >> 4;

  const char* Ag = (const char*)A;
  const char* Bg = (const char*)Bt;
  const int srow = tid >> 3;            // 0..63
  const int scb = (tid & 7) * 16;       // col byte 0..112

  auto stage = [&](int t, int bsel) {
    char* base = lds + bsel * BUF;
    long kb = (long)t * 128;  // 64 cols * 2B
#pragma unroll
    for (int l = 0; l < 4; ++l) {
      int row = l * 64 + srow;
      async_copy16(base + row * 128 + scb,
                   Ag + ((long)(m0 + row) * lda) * 2 + kb + scb);
    }
#pragma unroll
    for (int l = 0; l < BN / 64; ++l) {
      int row = l * 64 + srow;
      async_copy16(base + ABYTES + row * 128 + scb,
                   Bg + ((long)(n0 + row) * ldb) * 2 + kb + scb);
    }
  };

  f32x4 acc[8][NR];
#pragma unroll
  for (int m = 0; m < 8; ++m)
#pragma unroll
    for (int n = 0; n < NR; ++n) acc[m][n] = (f32x4){0.f, 0.f, 0.f, 0.f};

  const int nt = K >> 6;
  stage(0, 0);
  asm volatile("s_waitcnt vmcnt(0)" ::: "memory");
  __builtin_amdgcn_s_barrier();

  for (int t = 0; t < nt; ++t) {
    int bt = t & 1;
    if (t + 1 < nt) stage(t + 1, bt ^ 1);
    const char* Ab = lds + bt * BUF;
    const char* Bb = Ab + ABYTES;
#pragma unroll
    for (int ks = 0; ks < 2; ++ks) {
      bf16x8 af[8], bf[NR];
#pragma unroll
      for (int m = 0; m < 8; ++m)
        af[m] = *(const bf16x8*)(Ab + (wm * 128 + m * 16 + ll) * 128 +
                                 ks * 64 + lh * 16);
#pragma unroll
      for (int n = 0; n < NR; ++n)
        bf[n] = *(const bf16x8*)(Bb + (wn * (BN / 4) + n * 16 + ll) * 128 +
                                 ks * 64 + lh * 16);
      __builtin_amdgcn_s_setprio(1);
#pragma unroll
      for (int m = 0; m < 8; ++m)
#pragma unroll
        for (int n = 0; n < NR; ++n)
          acc[m][n] = __builtin_amdgcn_mfma_f32_16x16x32_bf16(af[m], bf[n],
                                                              acc[m][n], 0, 0, 0);
      __builtin_amdgcn_s_setprio(0);
    }
    asm volatile("s_waitcnt vmcnt(0)" ::: "memory");
    __builtin_amdgcn_s_barrier();
  }

#pragma unroll
  for (int m = 0; m < 8; ++m) {
    int row = m0 + wm * 128 + m * 16 + lh * 4;
#pragma unroll
    for (int n = 0; n < NR; ++n) {
      int col = n0 + wn * (BN / 4) + n * 16 + ll;
      float bs = bias ? bias[col] : 0.f;
#pragma unroll
      for (int r = 0; r < 4; ++r) {
        float v = acc[m][n][r] + bs;
        if (act) v = v * 0.5f * (1.f + erff(v * 0.70710678118f));
        long cidx = (long)(row + r) * ldc + col;
        if (obf)
          ((__hip_bfloat16*)C)[cidx] = __float2bfloat16(v);
        else
          ((float*)C)[cidx] = v;
      }
    }
  }
}

// ---------------------------------------------------------------------------
// bf16 MFMA GEMM (NT), 128x128 tile, BK=32, 4 waves. XCD swizzle added.
// ---------------------------------------------------------------------------
__global__ __launch_bounds__(256) void gemm_bf16_nt(
    const __hip_bfloat16* __restrict__ A, const __hip_bfloat16* __restrict__ Bt,
    const float* __restrict__ bias, const float* __restrict__ E1,
    const float* __restrict__ E2, void* __restrict__ C, int K, int lda,
    int ldb, int ldc, long sA, long sB, long sC, long sE, float alpha, int act,
    int obf) {
  __shared__ unsigned short AsU[128 * 32];
  __shared__ unsigned short BsU[128 * 32];
  const int tid = threadIdx.x;
  const int lane = tid & 63, wave = tid >> 6;
  const int wr = wave >> 1, wc = wave & 1;

  int nwg = gridDim.x * gridDim.y;
  int wg = blockIdx.y * gridDim.x + blockIdx.x;
  int bx = blockIdx.x, by = blockIdx.y;
  if ((nwg & 7) == 0) {
    int cpx = nwg >> 3;
    int sw = (wg & 7) * cpx + (wg >> 3);
    bx = sw % gridDim.x;
    by = sw / gridDim.x;
  }
  const int m0 = by * 128, n0 = bx * 128;
  const int bz = blockIdx.z;
  const char* Ab = (const char*)(A + (long)bz * sA);
  const char* Bb = (const char*)(Bt + (long)bz * sB);

  f32x4 acc[4][4];
#pragma unroll
  for (int m = 0; m < 4; ++m)
#pragma unroll
    for (int n = 0; n < 4; ++n) acc[m][n] = (f32x4){0.f, 0.f, 0.f, 0.f};

  const int srow = tid >> 2;
  const int scol = (tid & 3) * 16;
  const int wbase = (tid >> 6) * 1024;

  for (int k0 = 0; k0 < K; k0 += 32) {
#pragma unroll
    for (int i = 0; i < 2; ++i) {
      async_copy16((char*)AsU + i * 4096 + wbase,
                   Ab + ((long)(m0 + i * 64 + srow) * lda + k0) * 2 + scol);
      async_copy16((char*)BsU + i * 4096 + wbase,
                   Bb + ((long)(n0 + i * 64 + srow) * ldb + k0) * 2 + scol);
    }
    __syncthreads();

    const int koff = (lane >> 4) * 8;
    bf16x8 a[4], b[4];
#pragma unroll
    for (int m = 0; m < 4; ++m)
      a[m] = *(const bf16x8*)&AsU[(wr * 64 + m * 16 + (lane & 15)) * 32 + koff];
#pragma unroll
    for (int n = 0; n < 4; ++n)
      b[n] = *(const bf16x8*)&BsU[(wc * 64 + n * 16 + (lane & 15)) * 32 + koff];
#pragma unroll
    for (int m = 0; m < 4; ++m)
#pragma unroll
      for (int n = 0; n < 4; ++n)
        acc[m][n] = __builtin_amdgcn_mfma_f32_16x16x32_bf16(a[m], b[n],
                                                            acc[m][n], 0, 0, 0);
    __syncthreads();
  }

#pragma unroll
  for (int m = 0; m < 4; ++m) {
    int row = m0 + wr * 64 + m * 16 + (lane >> 4) * 4;
#pragma unroll
    for (int n = 0; n < 4; ++n) {
      int col = n0 + wc * 64 + n * 16 + (lane & 15);
      float bs = bias ? bias[col] : 0.f;
#pragma unroll
      for (int r = 0; r < 4; ++r) {
        float v = (acc[m][n][r] + bs) * alpha;
        long eidx = (long)bz * sE + (long)(row + r) * ldc + col;
        if (E1) v += E1[eidx];
        if (E2) v += E2[eidx];
        if (act) v = v * 0.5f * (1.f + erff(v * 0.70710678118f));
        long cidx = (long)bz * sC + (long)(row + r) * ldc + col;
        if (obf)
          ((__hip_bfloat16*)C)[cidx] = __float2bfloat16(v);
        else
          ((float*)C)[cidx] = v;
      }
    }
  }
}

// ---------------------------------------------------------------------------
// MFMA attention. Block = (i-tile of 32, h, b); 4 waves. Reads bias+mask raw.
// ---------------------------------------------------------------------------
__global__ __launch_bounds__(256) void attn_mfma(
    const __hip_bfloat16* __restrict__ Q, const __hip_bfloat16* __restrict__ K,
    const __hip_bfloat16* __restrict__ VT, const float* __restrict__ BiasP,
    const float* __restrict__ MaskP, __hip_bfloat16* __restrict__ O,
    int ldqk) {
  __shared__ __hip_bfloat16 P[32][520];
  __shared__ float red[2][32][4];
  const int it = blockIdx.x, h = blockIdx.y, b = blockIdx.z;
  const int i0 = it * 32;
  const int tid = threadIdx.x;
  const int lane = tid & 63, w = tid >> 6;
  const int lh = lane >> 4, ll = lane & 15;

  const long qkb = (long)b * 512 * ldqk + h * 64;

  bf16x8 a[2][2];
#pragma unroll
  for (int m = 0; m < 2; ++m)
#pragma unroll
    for (int ks = 0; ks < 2; ++ks)
      a[m][ks] = *(const bf16x8*)&Q[qkb + (long)(i0 + m * 16 + ll) * ldqk +
                                    ks * 32 + lh * 8];

  f32x4 acc[2][8];
#pragma unroll
  for (int m = 0; m < 2; ++m)
#pragma unroll
    for (int n = 0; n < 8; ++n) acc[m][n] = (f32x4){0.f, 0.f, 0.f, 0.f};

#pragma unroll
  for (int n = 0; n < 8; ++n) {
    const __hip_bfloat16* kp =
        &K[qkb + (long)(w * 128 + n * 16 + ll) * ldqk + lh * 8];
    bf16x8 b0 = *(const bf16x8*)&kp[0];
    bf16x8 b1 = *(const bf16x8*)&kp[32];
#pragma unroll
    for (int m = 0; m < 2; ++m) {
      acc[m][n] =
          __builtin_amdgcn_mfma_f32_16x16x32_bf16(a[m][0], b0, acc[m][n], 0, 0, 0);
      acc[m][n] =
          __builtin_amdgcn_mfma_f32_16x16x32_bf16(a[m][1], b1, acc[m][n], 0, 0, 0);
    }
  }

  const long bmo = ((long)b * 512 + i0) * 512 + w * 128;
#pragma unroll
  for (int m = 0; m < 2; ++m)
#pragma unroll
    for (int r = 0; r < 4; ++r) {
      int row = m * 16 + lh * 4 + r;
#pragma unroll
      for (int n = 0; n < 8; ++n) {
        long gi = bmo + (long)row * 512 + n * 16 + ll;
        acc[m][n][r] += BiasP[gi] + MaskP[gi];
      }
    }

  float rmax[2][4];
#pragma unroll
  for (int m = 0; m < 2; ++m)
#pragma unroll
    for (int r = 0; r < 4; ++r) {
      float v = acc[m][0][r];
#pragma unroll
      for (int n = 1; n < 8; ++n) v = fmaxf(v, acc[m][n][r]);
#pragma unroll
      for (int o = 1; o < 16; o <<= 1) v = fmaxf(v, __shfl_xor(v, o));
      rmax[m][r] = v;
    }
  if (ll == 0) {
#pragma unroll
    for (int m = 0; m < 2; ++m)
#pragma unroll
      for (int r = 0; r < 4; ++r) red[0][m * 16 + lh * 4 + r][w] = rmax[m][r];
  }
  __syncthreads();
#pragma unroll
  for (int m = 0; m < 2; ++m)
#pragma unroll
    for (int r = 0; r < 4; ++r) {
      const float* p = red[0][m * 16 + lh * 4 + r];
      rmax[m][r] = fmaxf(fmaxf(p[0], p[1]), fmaxf(p[2], p[3]));
    }
  float rsum[2][4];
#pragma unroll
  for (int m = 0; m < 2; ++m)
#pragma unroll
    for (int r = 0; r < 4; ++r) {
      float s = 0.f;
#pragma unroll
      for (int n = 0; n < 8; ++n) {
        float e = __expf(acc[m][n][r] - rmax[m][r]);
        acc[m][n][r] = e;
        s += e;
      }
#pragma unroll
      for (int o = 1; o < 16; o <<= 1) s += __shfl_xor(s, o);
      rsum[m][r] = s;
    }
  if (ll == 0) {
#pragma unroll
    for (int m = 0; m < 2; ++m)
#pragma unroll
      for (int r = 0; r < 4; ++r) red[1][m * 16 + lh * 4 + r][w] = rsum[m][r];
  }
  __syncthreads();
#pragma unroll
  for (int m = 0; m < 2; ++m)
#pragma unroll
    for (int r = 0; r < 4; ++r) {
      const float* p = red[1][m * 16 + lh * 4 + r];
      float inv = 1.f / (p[0] + p[1] + p[2] + p[3]);
      int row = m * 16 + lh * 4 + r;
#pragma unroll
      for (int n = 0; n < 8; ++n)
        P[row][w * 128 + n * 16 + ll] = __float2bfloat16(acc[m][n][r] * inv);
    }
  __syncthreads();

  const long vtb = ((long)b * 1024 + h * 64) * 512;
  const long ob = (long)b * 512 * 1024 + h * 64;
  const int mw = (w >> 1) * 16, nw = (w & 1) * 32;
  f32x4 oacc[2];
  oacc[0] = (f32x4){0.f, 0.f, 0.f, 0.f};
  oacc[1] = (f32x4){0.f, 0.f, 0.f, 0.f};
#pragma unroll
  for (int ks = 0; ks < 16; ++ks) {
    int k0 = ks * 32;
    bf16x8 pa = *(const bf16x8*)&P[mw + ll][k0 + lh * 8];
#pragma unroll
    for (int nf = 0; nf < 2; ++nf) {
      bf16x8 vb = *(const bf16x8*)&VT[vtb + (long)(nw + nf * 16 + ll) * 512 +
                                      k0 + lh * 8];
      oacc[nf] =
          __builtin_amdgcn_mfma_f32_16x16x32_bf16(pa, vb, oacc[nf], 0, 0, 0);
    }
  }
#pragma unroll
  for (int nf = 0; nf < 2; ++nf)
#pragma unroll
    for (int r = 0; r < 4; ++r)
      O[ob + (long)(i0 + mw + lh * 4 + r) * 1024 + nw + nf * 16 + ll] =
          __float2bfloat16(oacc[nf][r]);
}

// ---------------------------------------------------------------------------
// Row softmax (512) f32 in -> bf16 out. One block per row.
// ---------------------------------------------------------------------------
__global__ __launch_bounds__(256) void softmax_rows(
    const float* __restrict__ P, __hip_bfloat16* __restrict__ Ob) {
  const float* row = P + (long)blockIdx.x * 512;
  __hip_bfloat16* orow = Ob + (long)blockIdx.x * 512;
  int t = threadIdx.x;
  float v0 = row[t], v1 = row[t + 256];
  float m = fmaxf(v0, v1);
#pragma unroll
  for (int o = 32; o; o >>= 1) m = fmaxf(m, __shfl_xor(m, o));
  __shared__ float red[8];
  int wid = t >> 6, lane = t & 63;
  if (!lane) red[wid] = m;
  __syncthreads();
  m = fmaxf(fmaxf(red[0], red[1]), fmaxf(red[2], red[3]));
  float e0 = __expf(v0 - m), e1 = __expf(v1 - m);
  float s = e0 + e1;
#pragma unroll
  for (int o = 32; o; o >>= 1) s += __shfl_xor(s, o);
  if (!lane) red[4 + wid] = s;
  __syncthreads();
  s = red[4] + red[5] + red[6] + red[7];
  float inv = 1.f / s;
  orow[t] = __float2bfloat16(e0 * inv);
  orow[t + 256] = __float2bfloat16(e1 * inv);
}

// ---------------------------------------------------------------------------
// path gather-mean partials + finalize.
// ---------------------------------------------------------------------------
__global__ __launch_bounds__(256) void path_partial(
    const float* __restrict__ xp, const int* __restrict__ pp,
    float* __restrict__ PP, float* __restrict__ WS) {
  int b = blockIdx.x, hc = blockIdx.y, ic = blockIdx.z;
  int h = hc * 256 + threadIdx.x;
  const int* ppb = pp + b * 512;
  const float* xb = xp + (long)b * 512 * 1024;
  int iA = ic * 64, iB = iA + 64;
  float acc = 0.f;
  for (int i = iA; i < iB; ++i) {
    if (ppb[i] != 1) continue;
    float cur = xb[(long)i * 1024 + h];
    float a;
    if (i == 0) {
      a = 0.5f * (cur + xb[1024 + h]);
    } else if (i == 1) {
      a = (xb[h] + cur + xb[2 * 1024 + h]) * (1.f / 3.f);
    } else {
      int inx = (i + 1 < 512) ? i + 1 : 511;
      float nx = xb[(long)inx * 1024 + h];
      if (ppb[i - 2] == 1) {
        a = 0.5f * (cur + nx);
      } else {
        a = (xb[(long)(i - 1) * 1024 + h] + cur + nx) * (1.f / 3.f);
      }
    }
    acc += a;
  }
  PP[((long)b * 8 + ic) * 1024 + h] = acc;
  if (hc == 0 && threadIdx.x == 0) {
    float c = 0.f;
    for (int i = iA; i < iB; ++i) c += (ppb[i] == 1) ? 1.f : 0.f;
    WS[b * 8 + ic] = c;
  }
}

__global__ __launch_bounds__(256) void path_finalize(
    const float* __restrict__ PP, const float* __restrict__ WS,
    float* __restrict__ PATH) {
  int b = blockIdx.x;
  int h = blockIdx.y * 256 + threadIdx.x;
  float s = 0.f, w = 0.f;
#pragma unroll
  for (int ic = 0; ic < 8; ++ic) {
    s += PP[((long)b * 8 + ic) * 1024 + h];
    w += WS[b * 8 + ic];
  }
  PATH[b * 1024 + h] = s / w;
}

// ---------------------------------------------------------------------------
// Fused: X2 = x + 0.5*(YSELF + PATH); Y2b = LN(X2). One block per row.
// ---------------------------------------------------------------------------
__global__ __launch_bounds__(256) void combine_ln2(
    const float* __restrict__ X, const float* __restrict__ YS,
    const float* __restrict__ PT, const float* __restrict__ G,
    const float* __restrict__ Bt, float* __restrict__ X2,
    __hip_bfloat16* __restrict__ Y2b) {
  long row = blockIdx.x;
  int b = (int)(row >> 9);
  int t = threadIdx.x;
  const float4 xv = ((const float4*)(X + row * 1024))[t];
  const float4 sv = ((const float4*)(YS + row * 1024))[t];
  const float4 pv = *(const float4*)(PT + b * 1024 + t * 4);
  float4 v;
  v.x = xv.x + 0.5f * (sv.x + pv.x);
  v.y = xv.y + 0.5f * (sv.y + pv.y);
  v.z = xv.z + 0.5f * (sv.z + pv.z);
  v.w = xv.w + 0.5f * (sv.w + pv.w);
  ((float4*)(X2 + row * 1024))[t] = v;

  float s = v.x + v.y + v.z + v.w;
  float q = v.x * v.x + v.y * v.y + v.z * v.z + v.w * v.w;
#pragma unroll
  for (int o = 32; o; o >>= 1) {
    s += __shfl_xor(s, o);
    q += __shfl_xor(q, o);
  }
  __shared__ float rs[4], rq[4];
  int wid = t >> 6;
  if ((t & 63) == 0) { rs[wid] = s; rq[wid] = q; }
  __syncthreads();
  s = rs[0] + rs[1] + rs[2] + rs[3];
  q = rq[0] + rq[1] + rq[2] + rq[3];
  float mean = s * (1.f / 1024.f);
  float var = q * (1.f / 1024.f) - mean * mean;
  float rstd = rsqrtf(var + 1e-5f);
  const float4 gv = ((const float4*)G)[t];
  const float4 bv = ((const float4*)Bt)[t];
  __hip_bfloat16* o = Y2b + row * 1024 + t * 4;
  o[0] = __float2bfloat16((v.x - mean) * rstd * gv.x + bv.x);
  o[1] = __float2bfloat16((v.y - mean) * rstd * gv.y + bv.y);
  o[2] = __float2bfloat16((v.z - mean) * rstd * gv.z + bv.z);
  o[3] = __float2bfloat16((v.w - mean) * rstd * gv.w + bv.w);
}

// ---------------------------------------------------------------------------
extern "C" void kernel_launch(void* const* d_in, const int* in_sizes, int n_in,
                              void* d_out, int out_size, void* d_ws,
                              size_t ws_size, hipStream_t stream) {
  const float* x = (const float*)d_in[0];
  const int* pp = (const int*)d_in[1];
  const float* abias = (const float*)d_in[3];
  const float* amask = (const float*)d_in[4];
  const float* agraph = (const float*)d_in[5];
  const float* vgraph = (const float*)d_in[6];
  const float* ln1g = (const float*)d_in[7];
  const float* ln1b = (const float*)d_in[8];
  const float* wq = (const float*)d_in[9];
  const float* bq = (const float*)d_in[10];
  const float* wk = (const float*)d_in[11];
  const float* bk = (const float*)d_in[12];
  const float* wv = (const float*)d_in[13];
  const float* bv = (const float*)d_in[14];
  const float* wo = (const float*)d_in[15];
  const float* bo = (const float*)d_in[16];
  const float* pqw = (const float*)d_in[17];
  const float* pqb = (const float*)d_in[18];
  const float* pkw = (const float*)d_in[19];
  const float* pkb = (const float*)d_in[20];
  const float* pvw = (const float*)d_in[21];
  const float* pvb = (const float*)d_in[22];
  const float* ln2g = (const float*)d_in[23];
  const float* ln2b = (const float*)d_in[24];
  const float* w1 = (const float*)d_in[25];
  const float* b1 = (const float*)d_in[26];
  const float* w2 = (const float*)d_in[27];
  const float* b2 = (const float*)d_in[28];

  char* wsb = (char*)d_ws;
  auto Ybf = (__hip_bfloat16*)(wsb);                  // 0-8 (later Y2b)
  auto QKV = (__hip_bfloat16*)(wsb + (8l << 20));     // 8-56: [4096][6144]
  auto VTb = (__hip_bfloat16*)(wsb + (56l << 20));    // 56-64
  auto PVT = (__hip_bfloat16*)(wsb + (64l << 20));    // 64-72
  auto ATTb = (__hip_bfloat16*)(wsb + (72l << 20));   // 72-80 (later W2T)
  auto PATTb = (__hip_bfloat16*)(wsb + (88l << 20));  // 88-92
  auto PATTf = (float*)(wsb + (92l << 20));           // 92-100
  auto XP = (float*)(wsb + (92l << 20));              // 92-108
  auto WALL = (__hip_bfloat16*)(wsb + (108l << 20));  // 108-120: [6144][1024]
  auto WOT = (__hip_bfloat16*)(wsb + (120l << 20));   // 120-122
  auto W1T = (__hip_bfloat16*)(wsb + (122l << 20));   // 122-130
  auto bias6 = (float*)(wsb + (130l << 20));          // 24KB
  auto PPart = (float*)(wsb + (131l << 20));          // 256KB
  auto WSp = (float*)(wsb + (132l << 20));            // 256B
  auto PATH = (float*)(wsb + (133l << 20));           // 32KB
  auto YSELF = (float*)(wsb + (8l << 20));            // 8-24 (QKV dead)
  auto X2 = (float*)(wsb + (24l << 20));              // 24-40
  auto HMID = (__hip_bfloat16*)(wsb + (40l << 20));   // 40-72
  auto W2T = ATTb;
  __hip_bfloat16* Y2b = Ybf;
  float* OUT = (float*)d_out;

  const float qscale = 0.125f;
  const float pscale = 0.03125f;
  const long S2 = 512l * 512;
  const long SQ = 512l * 6144;

  __hip_bfloat16* Qp = QKV;
  __hip_bfloat16* Kp = QKV + 1024;
  __hip_bfloat16* Vp = QKV + 2048;
  __hip_bfloat16* PQp = QKV + 3072;
  __hip_bfloat16* PKp = QKV + 4096;
  __hip_bfloat16* PVp = QKV + 5120;

  // 0) weight transposes + bias concat
  TC7 tp;
  tp.in[0] = wq;  tp.out[0] = WALL;                 tp.scale[0] = qscale;
  tp.in[1] = wk;  tp.out[1] = WALL + 1024 * 1024;   tp.scale[1] = 1.f;
  tp.in[2] = wv;  tp.out[2] = WALL + 2048 * 1024;   tp.scale[2] = 1.f;
  tp.in[3] = pqw; tp.out[3] = WALL + 3072 * 1024;   tp.scale[3] = pscale;
  tp.in[4] = pkw; tp.out[4] = WALL + 4096 * 1024;   tp.scale[4] = 1.f;
  tp.in[5] = pvw; tp.out[5] = WALL + 5120 * 1024;   tp.scale[5] = 1.f;
  tp.in[6] = wo;  tp.out[6] = WOT;                  tp.scale[6] = 1.f;
  tconv7<<<dim3(32, 32, 7), 256, 0, stream>>>(tp);
  tconv_f32_bf16<<<dim3(128, 32), 256, 0, stream>>>(w1, W1T, 1024, 4096);

  BC6 bp;
  bp.b[0] = bq;  bp.scale[0] = qscale;
  bp.b[1] = bk;  bp.scale[1] = 1.f;
  bp.b[2] = bv;  bp.scale[2] = 1.f;
  bp.b[3] = pqb; bp.scale[3] = pscale;
  bp.b[4] = pkb; bp.scale[4] = 1.f;
  bp.b[5] = pvb; bp.scale[5] = 1.f;
  bias_concat<<<24, 256, 0, stream>>>(bp, bias6);

  // 1) LN1 -> Ybf
  ln_rows_bf16<<<4096, 256, 0, stream>>>(x, ln1g, ln1b, Ybf);

  // 2) fused projections via gemm256<128>: M=4096 (y=16), N=6144 (x=48)
  gemm256<128><<<dim3(48, 16), 512, 0, stream>>>(
      Ybf, WALL, bias6, QKV, 1024, 1024, 1024, 6144, 0, 1);

  // 3) transposes: V -> VT, PV -> PVT
  tconv_bf16<<<dim3(32, 16, 8), 256, 0, stream>>>(Vp, VTb, 512, 1024, 6144, SQ);
  tconv_bf16<<<dim3(32, 16, 8), 256, 0, stream>>>(PVp, PVT, 512, 1024, 6144, SQ);

  // 4) path scores + softmax
  gemm_bf16_nt<<<dim3(4, 4, 8), 256, 0, stream>>>(
      PQp, PKp, nullptr, agraph, vgraph, PATTf, 1024, 6144, 6144, 512, SQ, SQ,
      S2, S2, 1.f, 0, 0);
  softmax_rows<<<4096, 256, 0, stream>>>(PATTf, PATTb);

  // 5) MFMA attention -> ATTb (reads bias + mask directly)
  attn_mfma<<<dim3(16, 16, 8), 256, 0, stream>>>(Qp, Kp, VTb, abias, amask,
                                                 ATTb, 6144);

  // 6) XP = PATT @ PVT^T
  gemm_bf16_nt<<<dim3(8, 4, 8), 256, 0, stream>>>(
      PATTb, PVT, nullptr, nullptr, nullptr, XP, 512, 512, 512, 1024, S2,
      512l * 1024, 512l * 1024, 0, 1.f, 0, 0);

  // 7) path gather-mean
  path_partial<<<dim3(8, 4, 8), 256, 0, stream>>>(XP, pp, PPart, WSp);
  path_finalize<<<dim3(8, 4), 256, 0, stream>>>(PPart, WSp, PATH);

  // 8) y_self = ATT @ wo + bo (f32, overlays QKV lo)
  gemm_bf16_nt<<<dim3(8, 32, 1), 256, 0, stream>>>(
      ATTb, WOT, bo, nullptr, nullptr, YSELF, 1024, 1024, 1024, 1024, 0, 0, 0,
      0, 1.f, 0, 0);

  // 8b) W2 transpose into ATTb's slot
  tconv_f32_bf16<<<dim3(32, 128), 256, 0, stream>>>(w2, W2T, 4096, 1024);

  // 9+10) fused combine + LN2
  combine_ln2<<<4096, 256, 0, stream>>>(x, YSELF, PATH, ln2g, ln2b, X2, Y2b);

  // 11) FFN1 via gemm256<256>: M=4096 (y=16), N=4096 (x=16), GELU, bf16 out
  gemm256<256><<<dim3(16, 16), 512, 0, stream>>>(
      Y2b, W1T, b1, HMID, 1024, 1024, 1024, 4096, 1, 1);

  // 12) FFN2: OUT = HMID@w2 + b2 + X2 (128-tile, K=4096, swizzled)
  gemm_bf16_nt<<<dim3(8, 32, 1), 256, 0, stream>>>(
      HMID, W2T, b2, X2, nullptr, OUT, 4096, 4096, 4096, 1024, 0, 0, 0, 0, 1.f,
      0, 0);
}

// Round 7
// 530.089 us; speedup vs baseline: 9.5648x; 1.0019x over previous
//
#include <hip/hip_runtime.h>
#include <hip/hip_bf16.h>
#include <math.h>

// B=8, S=512, H=1024, NH=16, DK=64, FF=4096.
// Round 7: FFN2 (K=4096, N=1024 -> was 1 block/CU, latency-bound, MfmaUtil
// 11.7%) converted to split-K=4 via gemm256 z-dim + f32 partials + reduce.
// Everything else frozen from round 6.

typedef __bf16 bf16x8 __attribute__((ext_vector_type(8)));
typedef float f32x4 __attribute__((ext_vector_type(4)));

__device__ __forceinline__ void async_copy16(void* lds, const void* g) {
  __builtin_amdgcn_global_load_lds(
      (__attribute__((address_space(1))) void*)(void*)g,
      (__attribute__((address_space(3))) void*)lds, 16, 0, 0);
}

// ---------------------------------------------------------------------------
// LayerNorm over last dim (1024) -> bf16. One block (256 thr) per row.
// ---------------------------------------------------------------------------
__global__ __launch_bounds__(256) void ln_rows_bf16(
    const float* __restrict__ X, const float* __restrict__ G,
    const float* __restrict__ Bt, __hip_bfloat16* __restrict__ O) {
  long row = blockIdx.x;
  int t = threadIdx.x;
  const float4 xv = ((const float4*)(X + row * 1024))[t];
  float s = xv.x + xv.y + xv.z + xv.w;
  float q = xv.x * xv.x + xv.y * xv.y + xv.z * xv.z + xv.w * xv.w;
#pragma unroll
  for (int o = 32; o; o >>= 1) {
    s += __shfl_xor(s, o);
    q += __shfl_xor(q, o);
  }
  __shared__ float rs[4], rq[4];
  int wid = t >> 6;
  if ((t & 63) == 0) { rs[wid] = s; rq[wid] = q; }
  __syncthreads();
  s = rs[0] + rs[1] + rs[2] + rs[3];
  q = rq[0] + rq[1] + rq[2] + rq[3];
  float mean = s * (1.f / 1024.f);
  float var = q * (1.f / 1024.f) - mean * mean;
  float rstd = rsqrtf(var + 1e-5f);
  const float4 gv = ((const float4*)G)[t];
  const float4 bv = ((const float4*)Bt)[t];
  __hip_bfloat16* o = O + row * 1024 + t * 4;
  o[0] = __float2bfloat16((xv.x - mean) * rstd * gv.x + bv.x);
  o[1] = __float2bfloat16((xv.y - mean) * rstd * gv.y + bv.y);
  o[2] = __float2bfloat16((xv.z - mean) * rstd * gv.z + bv.z);
  o[3] = __float2bfloat16((xv.w - mean) * rstd * gv.w + bv.w);
}

// ---------------------------------------------------------------------------
// Batched weight transpose-convert: 7x f32 [1024,1024] -> bf16 ^T w/ scale.
// ---------------------------------------------------------------------------
struct TC7 {
  const float* in[7];
  __hip_bfloat16* out[7];
  float scale[7];
};
__global__ __launch_bounds__(256) void tconv7(TC7 p) {
  __shared__ float t[32][33];
  int j = blockIdx.z;
  const float* in = p.in[j];
  __hip_bfloat16* out = p.out[j];
  float sc = p.scale[j];
  int c0 = blockIdx.x * 32, r0 = blockIdx.y * 32;
  int tid = threadIdx.x;
  int lr = tid >> 3, lc = (tid & 7) * 4;
  const float4 v = *(const float4*)&in[(long)(r0 + lr) * 1024 + c0 + lc];
  t[lr][lc] = v.x; t[lr][lc + 1] = v.y; t[lr][lc + 2] = v.z; t[lr][lc + 3] = v.w;
  __syncthreads();
  int oc = tid >> 3, orr = (tid & 7) * 4;
  __hip_bfloat16* o = &out[(long)(c0 + oc) * 1024 + r0 + orr];
  o[0] = __float2bfloat16(t[orr][oc] * sc);
  o[1] = __float2bfloat16(t[orr + 1][oc] * sc);
  o[2] = __float2bfloat16(t[orr + 2][oc] * sc);
  o[3] = __float2bfloat16(t[orr + 3][oc] * sc);
}

// Generic transpose-convert f32 [R,C] -> bf16 [C,R]. grid (C/32, R/32).
__global__ __launch_bounds__(256) void tconv_f32_bf16(
    const float* __restrict__ in, __hip_bfloat16* __restrict__ out, int R,
    int C) {
  __shared__ float t[32][33];
  int c0 = blockIdx.x * 32, r0 = blockIdx.y * 32;
  int tid = threadIdx.x;
  int lr = tid >> 3, lc = (tid & 7) * 4;
  const float4 v = *(const float4*)&in[(long)(r0 + lr) * C + c0 + lc];
  t[lr][lc] = v.x; t[lr][lc + 1] = v.y; t[lr][lc + 2] = v.z; t[lr][lc + 3] = v.w;
  __syncthreads();
  int oc = tid >> 3, orr = (tid & 7) * 4;
  __hip_bfloat16* o = &out[(long)(c0 + oc) * R + r0 + orr];
  o[0] = __float2bfloat16(t[orr][oc]);
  o[1] = __float2bfloat16(t[orr + 1][oc]);
  o[2] = __float2bfloat16(t[orr + 2][oc]);
  o[3] = __float2bfloat16(t[orr + 3][oc]);
}

// Batched bf16 transpose, strided input -> packed [bz][C][R].
__global__ __launch_bounds__(256) void tconv_bf16(
    const __hip_bfloat16* __restrict__ in, __hip_bfloat16* __restrict__ out,
    int R, int C, int ldin, long sIn) {
  __shared__ __hip_bfloat16 t[32][34];
  int bz = blockIdx.z;
  long ibase = (long)bz * sIn;
  long obase = (long)bz * R * C;
  int c0 = blockIdx.x * 32, r0 = blockIdx.y * 32;
  int tid = threadIdx.x;
  int lr = tid >> 3, lc = (tid & 7) * 4;
  const __hip_bfloat16* ip = &in[ibase + (long)(r0 + lr) * ldin + c0 + lc];
  t[lr][lc] = ip[0]; t[lr][lc + 1] = ip[1]; t[lr][lc + 2] = ip[2]; t[lr][lc + 3] = ip[3];
  __syncthreads();
  int oc = tid >> 3, orr = (tid & 7) * 4;
  __hip_bfloat16* o = &out[obase + (long)(c0 + oc) * R + r0 + orr];
  o[0] = t[orr][oc];
  o[1] = t[orr + 1][oc];
  o[2] = t[orr + 2][oc];
  o[3] = t[orr + 3][oc];
}

// concat 6 bias vectors (x1024) with per-segment scale -> bias6[6144]
struct BC6 {
  const float* b[6];
  float scale[6];
};
__global__ __launch_bounds__(256) void bias_concat(BC6 p, float* __restrict__ o) {
  int idx = blockIdx.x * 256 + threadIdx.x;
  int j = idx >> 10, e = idx & 1023;
  o[idx] = p.b[j][e] * p.scale[j];
}

// ---------------------------------------------------------------------------
// gemm256<BN>: BM=256, BK=64, 512 thr = 8 waves (2M x 4N). Double-buffered
// LDS, stage(t+1) issued at start of tile t, ONE vmcnt(0)+barrier per tile.
// XCD-chunked swizzle. Split-K via blockIdx.z: K is per-split; z scales the
// global K offset and output writes to C + z*sC (f32 partials when obf=0).
// ---------------------------------------------------------------------------
template <int BN>
__global__ __launch_bounds__(512, 2) void gemm256(
    const __hip_bfloat16* __restrict__ A, const __hip_bfloat16* __restrict__ Bt,
    const float* __restrict__ bias, void* __restrict__ C, int K, int lda,
    int ldb, int ldc, int act, int obf, long sC) {
  constexpr int NR = BN / 64;
  constexpr int ABYTES = 256 * 128;
  constexpr int BBYTES = BN * 128;
  constexpr int BUF = ABYTES + BBYTES;
  __shared__ char lds[2 * BUF];

  int nwg = gridDim.x * gridDim.y;
  int wg = blockIdx.y * gridDim.x + blockIdx.x;
  int cpx = nwg >> 3;
  int sw = (wg & 7) * cpx + (wg >> 3);
  int bx = sw % gridDim.x, by = sw / gridDim.x;
  const int m0 = by * 256, n0 = bx * BN;
  const int z = blockIdx.z;
  const long kbase = (long)z * K * 2;  // byte offset of this split's K range

  const int tid = threadIdx.x;
  const int lane = tid & 63, wid = tid >> 6;
  const int wm = wid >> 2, wn = wid & 3;
  const int ll = lane & 15, lh = lane >> 4;

  const char* Ag = (const char*)A;
  const char* Bg = (const char*)Bt;
  const int srow = tid >> 3;
  const int scb = (tid & 7) * 16;

  auto stage = [&](int t, int bsel) {
    char* base = lds + bsel * BUF;
    long kb = kbase + (long)t * 128;
#pragma unroll
    for (int l = 0; l < 4; ++l) {
      int row = l * 64 + srow;
      async_copy16(base + row * 128 + scb,
                   Ag + ((long)(m0 + row) * lda) * 2 + kb + scb);
    }
#pragma unroll
    for (int l = 0; l < BN / 64; ++l) {
      int row = l * 64 + srow;
      async_copy16(base + ABYTES + row * 128 + scb,
                   Bg + ((long)(n0 + row) * ldb) * 2 + kb + scb);
    }
  };

  f32x4 acc[8][NR];
#pragma unroll
  for (int m = 0; m < 8; ++m)
#pragma unroll
    for (int n = 0; n < NR; ++n) acc[m][n] = (f32x4){0.f, 0.f, 0.f, 0.f};

  const int nt = K >> 6;
  stage(0, 0);
  asm volatile("s_waitcnt vmcnt(0)" ::: "memory");
  __builtin_amdgcn_s_barrier();

  for (int t = 0; t < nt; ++t) {
    int bt = t & 1;
    if (t + 1 < nt) stage(t + 1, bt ^ 1);
    const char* Ab = lds + bt * BUF;
    const char* Bb = Ab + ABYTES;
#pragma unroll
    for (int ks = 0; ks < 2; ++ks) {
      bf16x8 af[8], bf[NR];
#pragma unroll
      for (int m = 0; m < 8; ++m)
        af[m] = *(const bf16x8*)(Ab + (wm * 128 + m * 16 + ll) * 128 +
                                 ks * 64 + lh * 16);
#pragma unroll
      for (int n = 0; n < NR; ++n)
        bf[n] = *(const bf16x8*)(Bb + (wn * (BN / 4) + n * 16 + ll) * 128 +
                                 ks * 64 + lh * 16);
      __builtin_amdgcn_s_setprio(1);
#pragma unroll
      for (int m = 0; m < 8; ++m)
#pragma unroll
        for (int n = 0; n < NR; ++n)
          acc[m][n] = __builtin_amdgcn_mfma_f32_16x16x32_bf16(af[m], bf[n],
                                                              acc[m][n], 0, 0, 0);
      __builtin_amdgcn_s_setprio(0);
    }
    asm volatile("s_waitcnt vmcnt(0)" ::: "memory");
    __builtin_amdgcn_s_barrier();
  }

#pragma unroll
  for (int m = 0; m < 8; ++m) {
    int row = m0 + wm * 128 + m * 16 + lh * 4;
#pragma unroll
    for (int n = 0; n < NR; ++n) {
      int col = n0 + wn * (BN / 4) + n * 16 + ll;
      float bs = bias ? bias[col] : 0.f;
#pragma unroll
      for (int r = 0; r < 4; ++r) {
        float v = acc[m][n][r] + bs;
        if (act) v = v * 0.5f * (1.f + erff(v * 0.70710678118f));
        long cidx = (long)z * sC + (long)(row + r) * ldc + col;
        if (obf)
          ((__hip_bfloat16*)C)[cidx] = __float2bfloat16(v);
        else
          ((float*)C)[cidx] = v;
      }
    }
  }
}

// FFN2 finalize: OUT = sum_z PART[z] + b2 + X2. float4/thread, grid 4096.
__global__ __launch_bounds__(256) void ffn2_reduce(
    const float* __restrict__ P, const float* __restrict__ X2,
    const float* __restrict__ b2, float* __restrict__ OUT) {
  int i = blockIdx.x * 256 + threadIdx.x;
  const long SP = 4194304;  // 4096*1024
  float4 a = ((const float4*)P)[i];
  float4 b = ((const float4*)(P + SP))[i];
  float4 c = ((const float4*)(P + 2 * SP))[i];
  float4 d = ((const float4*)(P + 3 * SP))[i];
  float4 xr = ((const float4*)X2)[i];
  const float4 bb = *(const float4*)(b2 + ((i & 255) * 4));
  float4 o;
  o.x = a.x + b.x + c.x + d.x + xr.x + bb.x;
  o.y = a.y + b.y + c.y + d.y + xr.y + bb.y;
  o.z = a.z + b.z + c.z + d.z + xr.z + bb.z;
  o.w = a.w + b.w + c.w + d.w + xr.w + bb.w;
  ((float4*)OUT)[i] = o;
}

// ---------------------------------------------------------------------------
// bf16 MFMA GEMM (NT), 128x128 tile, BK=32, 4 waves. XCD swizzle.
// ---------------------------------------------------------------------------
__global__ __launch_bounds__(256) void gemm_bf16_nt(
    const __hip_bfloat16* __restrict__ A, const __hip_bfloat16* __restrict__ Bt,
    const float* __restrict__ bias, const float* __restrict__ E1,
    const float* __restrict__ E2, void* __restrict__ C, int K, int lda,
    int ldb, int ldc, long sA, long sB, long sC, long sE, float alpha, int act,
    int obf) {
  __shared__ unsigned short AsU[128 * 32];
  __shared__ unsigned short BsU[128 * 32];
  const int tid = threadIdx.x;
  const int lane = tid & 63, wave = tid >> 6;
  const int wr = wave >> 1, wc = wave & 1;

  int nwg = gridDim.x * gridDim.y;
  int wg = blockIdx.y * gridDim.x + blockIdx.x;
  int bx = blockIdx.x, by = blockIdx.y;
  if ((nwg & 7) == 0) {
    int cpx = nwg >> 3;
    int sw = (wg & 7) * cpx + (wg >> 3);
    bx = sw % gridDim.x;
    by = sw / gridDim.x;
  }
  const int m0 = by * 128, n0 = bx * 128;
  const int bz = blockIdx.z;
  const char* Ab = (const char*)(A + (long)bz * sA);
  const char* Bb = (const char*)(Bt + (long)bz * sB);

  f32x4 acc[4][4];
#pragma unroll
  for (int m = 0; m < 4; ++m)
#pragma unroll
    for (int n = 0; n < 4; ++n) acc[m][n] = (f32x4){0.f, 0.f, 0.f, 0.f};

  const int srow = tid >> 2;
  const int scol = (tid & 3) * 16;
  const int wbase = (tid >> 6) * 1024;

  for (int k0 = 0; k0 < K; k0 += 32) {
#pragma unroll
    for (int i = 0; i < 2; ++i) {
      async_copy16((char*)AsU + i * 4096 + wbase,
                   Ab + ((long)(m0 + i * 64 + srow) * lda + k0) * 2 + scol);
      async_copy16((char*)BsU + i * 4096 + wbase,
                   Bb + ((long)(n0 + i * 64 + srow) * ldb + k0) * 2 + scol);
    }
    __syncthreads();

    const int koff = (lane >> 4) * 8;
    bf16x8 a[4], b[4];
#pragma unroll
    for (int m = 0; m < 4; ++m)
      a[m] = *(const bf16x8*)&AsU[(wr * 64 + m * 16 + (lane & 15)) * 32 + koff];
#pragma unroll
    for (int n = 0; n < 4; ++n)
      b[n] = *(const bf16x8*)&BsU[(wc * 64 + n * 16 + (lane & 15)) * 32 + koff];
#pragma unroll
    for (int m = 0; m < 4; ++m)
#pragma unroll
      for (int n = 0; n < 4; ++n)
        acc[m][n] = __builtin_amdgcn_mfma_f32_16x16x32_bf16(a[m], b[n],
                                                            acc[m][n], 0, 0, 0);
    __syncthreads();
  }

#pragma unroll
  for (int m = 0; m < 4; ++m) {
    int row = m0 + wr * 64 + m * 16 + (lane >> 4) * 4;
#pragma unroll
    for (int n = 0; n < 4; ++n) {
      int col = n0 + wc * 64 + n * 16 + (lane & 15);
      float bs = bias ? bias[col] : 0.f;
#pragma unroll
      for (int r = 0; r < 4; ++r) {
        float v = (acc[m][n][r] + bs) * alpha;
        long eidx = (long)bz * sE + (long)(row + r) * ldc + col;
        if (E1) v += E1[eidx];
        if (E2) v += E2[eidx];
        if (act) v = v * 0.5f * (1.f + erff(v * 0.70710678118f));
        long cidx = (long)bz * sC + (long)(row + r) * ldc + col;
        if (obf)
          ((__hip_bfloat16*)C)[cidx] = __float2bfloat16(v);
        else
          ((float*)C)[cidx] = v;
      }
    }
  }
}

// ---------------------------------------------------------------------------
// MFMA attention. Block = (i-tile of 32, h, b); 4 waves. Reads bias+mask raw.
// ---------------------------------------------------------------------------
__global__ __launch_bounds__(256) void attn_mfma(
    const __hip_bfloat16* __restrict__ Q, const __hip_bfloat16* __restrict__ K,
    const __hip_bfloat16* __restrict__ VT, const float* __restrict__ BiasP,
    const float* __restrict__ MaskP, __hip_bfloat16* __restrict__ O,
    int ldqk) {
  __shared__ __hip_bfloat16 P[32][520];
  __shared__ float red[2][32][4];
  const int it = blockIdx.x, h = blockIdx.y, b = blockIdx.z;
  const int i0 = it * 32;
  const int tid = threadIdx.x;
  const int lane = tid & 63, w = tid >> 6;
  const int lh = lane >> 4, ll = lane & 15;

  const long qkb = (long)b * 512 * ldqk + h * 64;

  bf16x8 a[2][2];
#pragma unroll
  for (int m = 0; m < 2; ++m)
#pragma unroll
    for (int ks = 0; ks < 2; ++ks)
      a[m][ks] = *(const bf16x8*)&Q[qkb + (long)(i0 + m * 16 + ll) * ldqk +
                                    ks * 32 + lh * 8];

  f32x4 acc[2][8];
#pragma unroll
  for (int m = 0; m < 2; ++m)
#pragma unroll
    for (int n = 0; n < 8; ++n) acc[m][n] = (f32x4){0.f, 0.f, 0.f, 0.f};

#pragma unroll
  for (int n = 0; n < 8; ++n) {
    const __hip_bfloat16* kp =
        &K[qkb + (long)(w * 128 + n * 16 + ll) * ldqk + lh * 8];
    bf16x8 b0 = *(const bf16x8*)&kp[0];
    bf16x8 b1 = *(const bf16x8*)&kp[32];
#pragma unroll
    for (int m = 0; m < 2; ++m) {
      acc[m][n] =
          __builtin_amdgcn_mfma_f32_16x16x32_bf16(a[m][0], b0, acc[m][n], 0, 0, 0);
      acc[m][n] =
          __builtin_amdgcn_mfma_f32_16x16x32_bf16(a[m][1], b1, acc[m][n], 0, 0, 0);
    }
  }

  const long bmo = ((long)b * 512 + i0) * 512 + w * 128;
#pragma unroll
  for (int m = 0; m < 2; ++m)
#pragma unroll
    for (int r = 0; r < 4; ++r) {
      int row = m * 16 + lh * 4 + r;
#pragma unroll
      for (int n = 0; n < 8; ++n) {
        long gi = bmo + (long)row * 512 + n * 16 + ll;
        acc[m][n][r] += BiasP[gi] + MaskP[gi];
      }
    }

  float rmax[2][4];
#pragma unroll
  for (int m = 0; m < 2; ++m)
#pragma unroll
    for (int r = 0; r < 4; ++r) {
      float v = acc[m][0][r];
#pragma unroll
      for (int n = 1; n < 8; ++n) v = fmaxf(v, acc[m][n][r]);
#pragma unroll
      for (int o = 1; o < 16; o <<= 1) v = fmaxf(v, __shfl_xor(v, o));
      rmax[m][r] = v;
    }
  if (ll == 0) {
#pragma unroll
    for (int m = 0; m < 2; ++m)
#pragma unroll
      for (int r = 0; r < 4; ++r) red[0][m * 16 + lh * 4 + r][w] = rmax[m][r];
  }
  __syncthreads();
#pragma unroll
  for (int m = 0; m < 2; ++m)
#pragma unroll
    for (int r = 0; r < 4; ++r) {
      const float* p = red[0][m * 16 + lh * 4 + r];
      rmax[m][r] = fmaxf(fmaxf(p[0], p[1]), fmaxf(p[2], p[3]));
    }
  float rsum[2][4];
#pragma unroll
  for (int m = 0; m < 2; ++m)
#pragma unroll
    for (int r = 0; r < 4; ++r) {
      float s = 0.f;
#pragma unroll
      for (int n = 0; n < 8; ++n) {
        float e = __expf(acc[m][n][r] - rmax[m][r]);
        acc[m][n][r] = e;
        s += e;
      }
#pragma unroll
      for (int o = 1; o < 16; o <<= 1) s += __shfl_xor(s, o);
      rsum[m][r] = s;
    }
  if (ll == 0) {
#pragma unroll
    for (int m = 0; m < 2; ++m)
#pragma unroll
      for (int r = 0; r < 4; ++r) red[1][m * 16 + lh * 4 + r][w] = rsum[m][r];
  }
  __syncthreads();
#pragma unroll
  for (int m = 0; m < 2; ++m)
#pragma unroll
    for (int r = 0; r < 4; ++r) {
      const float* p = red[1][m * 16 + lh * 4 + r];
      float inv = 1.f / (p[0] + p[1] + p[2] + p[3]);
      int row = m * 16 + lh * 4 + r;
#pragma unroll
      for (int n = 0; n < 8; ++n)
        P[row][w * 128 + n * 16 + ll] = __float2bfloat16(acc[m][n][r] * inv);
    }
  __syncthreads();

  const long vtb = ((long)b * 1024 + h * 64) * 512;
  const long ob = (long)b * 512 * 1024 + h * 64;
  const int mw = (w >> 1) * 16, nw = (w & 1) * 32;
  f32x4 oacc[2];
  oacc[0] = (f32x4){0.f, 0.f, 0.f, 0.f};
  oacc[1] = (f32x4){0.f, 0.f, 0.f, 0.f};
#pragma unroll
  for (int ks = 0; ks < 16; ++ks) {
    int k0 = ks * 32;
    bf16x8 pa = *(const bf16x8*)&P[mw + ll][k0 + lh * 8];
#pragma unroll
    for (int nf = 0; nf < 2; ++nf) {
      bf16x8 vb = *(const bf16x8*)&VT[vtb + (long)(nw + nf * 16 + ll) * 512 +
                                      k0 + lh * 8];
      oacc[nf] =
          __builtin_amdgcn_mfma_f32_16x16x32_bf16(pa, vb, oacc[nf], 0, 0, 0);
    }
  }
#pragma unroll
  for (int nf = 0; nf < 2; ++nf)
#pragma unroll
    for (int r = 0; r < 4; ++r)
      O[ob + (long)(i0 + mw + lh * 4 + r) * 1024 + nw + nf * 16 + ll] =
          __float2bfloat16(oacc[nf][r]);
}

// ---------------------------------------------------------------------------
// Row softmax (512) f32 in -> bf16 out. One block per row.
// ---------------------------------------------------------------------------
__global__ __launch_bounds__(256) void softmax_rows(
    const float* __restrict__ P, __hip_bfloat16* __restrict__ Ob) {
  const float* row = P + (long)blockIdx.x * 512;
  __hip_bfloat16* orow = Ob + (long)blockIdx.x * 512;
  int t = threadIdx.x;
  float v0 = row[t], v1 = row[t + 256];
  float m = fmaxf(v0, v1);
#pragma unroll
  for (int o = 32; o; o >>= 1) m = fmaxf(m, __shfl_xor(m, o));
  __shared__ float red[8];
  int wid = t >> 6, lane = t & 63;
  if (!lane) red[wid] = m;
  __syncthreads();
  m = fmaxf(fmaxf(red[0], red[1]), fmaxf(red[2], red[3]));
  float e0 = __expf(v0 - m), e1 = __expf(v1 - m);
  float s = e0 + e1;
#pragma unroll
  for (int o = 32; o; o >>= 1) s += __shfl_xor(s, o);
  if (!lane) red[4 + wid] = s;
  __syncthreads();
  s = red[4] + red[5] + red[6] + red[7];
  float inv = 1.f / s;
  orow[t] = __float2bfloat16(e0 * inv);
  orow[t + 256] = __float2bfloat16(e1 * inv);
}

// ---------------------------------------------------------------------------
// path gather-mean partials + finalize.
// ---------------------------------------------------------------------------
__global__ __launch_bounds__(256) void path_partial(
    const float* __restrict__ xp, const int* __restrict__ pp,
    float* __restrict__ PP, float* __restrict__ WS) {
  int b = blockIdx.x, hc = blockIdx.y, ic = blockIdx.z;
  int h = hc * 256 + threadIdx.x;
  const int* ppb = pp + b * 512;
  const float* xb = xp + (long)b * 512 * 1024;
  int iA = ic * 64, iB = iA + 64;
  float acc = 0.f;
  for (int i = iA; i < iB; ++i) {
    if (ppb[i] != 1) continue;
    float cur = xb[(long)i * 1024 + h];
    float a;
    if (i == 0) {
      a = 0.5f * (cur + xb[1024 + h]);
    } else if (i == 1) {
      a = (xb[h] + cur + xb[2 * 1024 + h]) * (1.f / 3.f);
    } else {
      int inx = (i + 1 < 512) ? i + 1 : 511;
      float nx = xb[(long)inx * 1024 + h];
      if (ppb[i - 2] == 1) {
        a = 0.5f * (cur + nx);
      } else {
        a = (xb[(long)(i - 1) * 1024 + h] + cur + nx) * (1.f / 3.f);
      }
    }
    acc += a;
  }
  PP[((long)b * 8 + ic) * 1024 + h] = acc;
  if (hc == 0 && threadIdx.x == 0) {
    float c = 0.f;
    for (int i = iA; i < iB; ++i) c += (ppb[i] == 1) ? 1.f : 0.f;
    WS[b * 8 + ic] = c;
  }
}

__global__ __launch_bounds__(256) void path_finalize(
    const float* __restrict__ PP, const float* __restrict__ WS,
    float* __restrict__ PATH) {
  int b = blockIdx.x;
  int h = blockIdx.y * 256 + threadIdx.x;
  float s = 0.f, w = 0.f;
#pragma unroll
  for (int ic = 0; ic < 8; ++ic) {
    s += PP[((long)b * 8 + ic) * 1024 + h];
    w += WS[b * 8 + ic];
  }
  PATH[b * 1024 + h] = s / w;
}

// ---------------------------------------------------------------------------
// Fused: X2 = x + 0.5*(YSELF + PATH); Y2b = LN(X2). One block per row.
// ---------------------------------------------------------------------------
__global__ __launch_bounds__(256) void combine_ln2(
    const float* __restrict__ X, const float* __restrict__ YS,
    const float* __restrict__ PT, const float* __restrict__ G,
    const float* __restrict__ Bt, float* __restrict__ X2,
    __hip_bfloat16* __restrict__ Y2b) {
  long row = blockIdx.x;
  int b = (int)(row >> 9);
  int t = threadIdx.x;
  const float4 xv = ((const float4*)(X + row * 1024))[t];
  const float4 sv = ((const float4*)(YS + row * 1024))[t];
  const float4 pv = *(const float4*)(PT + b * 1024 + t * 4);
  float4 v;
  v.x = xv.x + 0.5f * (sv.x + pv.x);
  v.y = xv.y + 0.5f * (sv.y + pv.y);
  v.z = xv.z + 0.5f * (sv.z + pv.z);
  v.w = xv.w + 0.5f * (sv.w + pv.w);
  ((float4*)(X2 + row * 1024))[t] = v;

  float s = v.x + v.y + v.z + v.w;
  float q = v.x * v.x + v.y * v.y + v.z * v.z + v.w * v.w;
#pragma unroll
  for (int o = 32; o; o >>= 1) {
    s += __shfl_xor(s, o);
    q += __shfl_xor(q, o);
  }
  __shared__ float rs[4], rq[4];
  int wid = t >> 6;
  if ((t & 63) == 0) { rs[wid] = s; rq[wid] = q; }
  __syncthreads();
  s = rs[0] + rs[1] + rs[2] + rs[3];
  q = rq[0] + rq[1] + rq[2] + rq[3];
  float mean = s * (1.f / 1024.f);
  float var = q * (1.f / 1024.f) - mean * mean;
  float rstd = rsqrtf(var + 1e-5f);
  const float4 gv = ((const float4*)G)[t];
  const float4 bv = ((const float4*)Bt)[t];
  __hip_bfloat16* o = Y2b + row * 1024 + t * 4;
  o[0] = __float2bfloat16((v.x - mean) * rstd * gv.x + bv.x);
  o[1] = __float2bfloat16((v.y - mean) * rstd * gv.y + bv.y);
  o[2] = __float2bfloat16((v.z - mean) * rstd * gv.z + bv.z);
  o[3] = __float2bfloat16((v.w - mean) * rstd * gv.w + bv.w);
}

// ---------------------------------------------------------------------------
extern "C" void kernel_launch(void* const* d_in, const int* in_sizes, int n_in,
                              void* d_out, int out_size, void* d_ws,
                              size_t ws_size, hipStream_t stream) {
  const float* x = (const float*)d_in[0];
  const int* pp = (const int*)d_in[1];
  const float* abias = (const float*)d_in[3];
  const float* amask = (const float*)d_in[4];
  const float* agraph = (const float*)d_in[5];
  const float* vgraph = (const float*)d_in[6];
  const float* ln1g = (const float*)d_in[7];
  const float* ln1b = (const float*)d_in[8];
  const float* wq = (const float*)d_in[9];
  const float* bq = (const float*)d_in[10];
  const float* wk = (const float*)d_in[11];
  const float* bk = (const float*)d_in[12];
  const float* wv = (const float*)d_in[13];
  const float* bv = (const float*)d_in[14];
  const float* wo = (const float*)d_in[15];
  const float* bo = (const float*)d_in[16];
  const float* pqw = (const float*)d_in[17];
  const float* pqb = (const float*)d_in[18];
  const float* pkw = (const float*)d_in[19];
  const float* pkb = (const float*)d_in[20];
  const float* pvw = (const float*)d_in[21];
  const float* pvb = (const float*)d_in[22];
  const float* ln2g = (const float*)d_in[23];
  const float* ln2b = (const float*)d_in[24];
  const float* w1 = (const float*)d_in[25];
  const float* b1 = (const float*)d_in[26];
  const float* w2 = (const float*)d_in[27];
  const float* b2 = (const float*)d_in[28];

  char* wsb = (char*)d_ws;
  auto Ybf = (__hip_bfloat16*)(wsb);                  // 0-8 (later Y2b)
  auto QKV = (__hip_bfloat16*)(wsb + (8l << 20));     // 8-56: [4096][6144]
  auto VTb = (__hip_bfloat16*)(wsb + (56l << 20));    // 56-64
  auto PVT = (__hip_bfloat16*)(wsb + (64l << 20));    // 64-72
  auto ATTb = (__hip_bfloat16*)(wsb + (72l << 20));   // 72-80 (later W2T)
  auto PATTb = (__hip_bfloat16*)(wsb + (88l << 20));  // 88-92
  auto PATTf = (float*)(wsb + (92l << 20));           // 92-100
  auto XP = (float*)(wsb + (92l << 20));              // 92-108
  auto WALL = (__hip_bfloat16*)(wsb + (108l << 20));  // 108-120: [6144][1024]
  auto WOT = (__hip_bfloat16*)(wsb + (120l << 20));   // 120-122
  auto W1T = (__hip_bfloat16*)(wsb + (122l << 20));   // 122-130
  auto bias6 = (float*)(wsb + (130l << 20));          // 24KB
  auto PPart = (float*)(wsb + (131l << 20));          // 256KB
  auto WSp = (float*)(wsb + (132l << 20));            // 256B
  auto PATH = (float*)(wsb + (133l << 20));           // 32KB
  auto YSELF = (float*)(wsb + (8l << 20));            // 8-24 (QKV dead)
  auto X2 = (float*)(wsb + (24l << 20));              // 24-40
  auto HMID = (__hip_bfloat16*)(wsb + (40l << 20));   // 40-72
  auto W2T = ATTb;
  // FFN2 split-K partials: 4 x 16MB f32 at 92-156MB (XP/WALL/WOT/W1T/bias6/
  // PPart/PATH regions -- all dead by FFN2 time; ws >= 168MB per round-1).
  auto PART = (float*)(wsb + (92l << 20));
  __hip_bfloat16* Y2b = Ybf;
  float* OUT = (float*)d_out;

  const float qscale = 0.125f;
  const float pscale = 0.03125f;
  const long S2 = 512l * 512;
  const long SQ = 512l * 6144;

  __hip_bfloat16* Qp = QKV;
  __hip_bfloat16* Kp = QKV + 1024;
  __hip_bfloat16* Vp = QKV + 2048;
  __hip_bfloat16* PQp = QKV + 3072;
  __hip_bfloat16* PKp = QKV + 4096;
  __hip_bfloat16* PVp = QKV + 5120;

  // 0) weight transposes + bias concat
  TC7 tp;
  tp.in[0] = wq;  tp.out[0] = WALL;                 tp.scale[0] = qscale;
  tp.in[1] = wk;  tp.out[1] = WALL + 1024 * 1024;   tp.scale[1] = 1.f;
  tp.in[2] = wv;  tp.out[2] = WALL + 2048 * 1024;   tp.scale[2] = 1.f;
  tp.in[3] = pqw; tp.out[3] = WALL + 3072 * 1024;   tp.scale[3] = pscale;
  tp.in[4] = pkw; tp.out[4] = WALL + 4096 * 1024;   tp.scale[4] = 1.f;
  tp.in[5] = pvw; tp.out[5] = WALL + 5120 * 1024;   tp.scale[5] = 1.f;
  tp.in[6] = wo;  tp.out[6] = WOT;                  tp.scale[6] = 1.f;
  tconv7<<<dim3(32, 32, 7), 256, 0, stream>>>(tp);
  tconv_f32_bf16<<<dim3(128, 32), 256, 0, stream>>>(w1, W1T, 1024, 4096);

  BC6 bp;
  bp.b[0] = bq;  bp.scale[0] = qscale;
  bp.b[1] = bk;  bp.scale[1] = 1.f;
  bp.b[2] = bv;  bp.scale[2] = 1.f;
  bp.b[3] = pqb; bp.scale[3] = pscale;
  bp.b[4] = pkb; bp.scale[4] = 1.f;
  bp.b[5] = pvb; bp.scale[5] = 1.f;
  bias_concat<<<24, 256, 0, stream>>>(bp, bias6);

  // 1) LN1 -> Ybf
  ln_rows_bf16<<<4096, 256, 0, stream>>>(x, ln1g, ln1b, Ybf);

  // 2) fused projections via gemm256<128>: M=4096 (y=16), N=6144 (x=48)
  gemm256<128><<<dim3(48, 16, 1), 512, 0, stream>>>(
      Ybf, WALL, bias6, QKV, 1024, 1024, 1024, 6144, 0, 1, 0);

  // 3) transposes: V -> VT, PV -> PVT
  tconv_bf16<<<dim3(32, 16, 8), 256, 0, stream>>>(Vp, VTb, 512, 1024, 6144, SQ);
  tconv_bf16<<<dim3(32, 16, 8), 256, 0, stream>>>(PVp, PVT, 512, 1024, 6144, SQ);

  // 4) path scores + softmax
  gemm_bf16_nt<<<dim3(4, 4, 8), 256, 0, stream>>>(
      PQp, PKp, nullptr, agraph, vgraph, PATTf, 1024, 6144, 6144, 512, SQ, SQ,
      S2, S2, 1.f, 0, 0);
  softmax_rows<<<4096, 256, 0, stream>>>(PATTf, PATTb);

  // 5) MFMA attention -> ATTb (reads bias + mask directly)
  attn_mfma<<<dim3(16, 16, 8), 256, 0, stream>>>(Qp, Kp, VTb, abias, amask,
                                                 ATTb, 6144);

  // 6) XP = PATT @ PVT^T
  gemm_bf16_nt<<<dim3(8, 4, 8), 256, 0, stream>>>(
      PATTb, PVT, nullptr, nullptr, nullptr, XP, 512, 512, 512, 1024, S2,
      512l * 1024, 512l * 1024, 0, 1.f, 0, 0);

  // 7) path gather-mean
  path_partial<<<dim3(8, 4, 8), 256, 0, stream>>>(XP, pp, PPart, WSp);
  path_finalize<<<dim3(8, 4), 256, 0, stream>>>(PPart, WSp, PATH);

  // 8) y_self = ATT @ wo + bo (f32, overlays QKV lo)
  gemm_bf16_nt<<<dim3(8, 32, 1), 256, 0, stream>>>(
      ATTb, WOT, bo, nullptr, nullptr, YSELF, 1024, 1024, 1024, 1024, 0, 0, 0,
      0, 1.f, 0, 0);

  // 8b) W2 transpose into ATTb's slot
  tconv_f32_bf16<<<dim3(32, 128), 256, 0, stream>>>(w2, W2T, 4096, 1024);

  // 9+10) fused combine + LN2
  combine_ln2<<<4096, 256, 0, stream>>>(x, YSELF, PATH, ln2g, ln2b, X2, Y2b);

  // 11) FFN1 via gemm256<256>: M=4096, N=4096, GELU, bf16 out
  gemm256<256><<<dim3(16, 16, 1), 512, 0, stream>>>(
      Y2b, W1T, b1, HMID, 1024, 1024, 1024, 4096, 1, 1, 0);

  // 12) FFN2 split-K=4: partials[z] = HMID[:, z*1024:(z+1)*1024] @ W2T^T
  gemm256<128><<<dim3(8, 16, 4), 512, 0, stream>>>(
      HMID, W2T, nullptr, PART, 1024, 4096, 4096, 1024, 0, 0, 4194304);

  // 12b) OUT = sum_z PART[z] + b2 + X2
  ffn2_reduce<<<4096, 256, 0, stream>>>(PART, X2, b2, OUT);
}

// Round 8
// 481.688 us; speedup vs baseline: 10.5259x; 1.1005x over previous
//
#include <hip/hip_runtime.h>
#include <hip/hip_bf16.h>
#include <math.h>

// B=8, S=512, H=1024, NH=16, DK=64, FF=4096.
// Round 8: gemm256 rebuilt: (1) counted vmcnt pipeline (was vmcnt(0) draining
// the just-issued prefetch); (2) LDS XOR chunk-swizzle via pre-swizzled global
// source + swizzled ds_read (16-way conflict fix); (3) 2D XCD chunking
// (per-XCD L2 footprint ~L2-fit; was 107MB fetch vs 20MB unique on QKV).

typedef __bf16 bf16x8 __attribute__((ext_vector_type(8)));
typedef float f32x4 __attribute__((ext_vector_type(4)));

__device__ __forceinline__ void async_copy16(void* lds, const void* g) {
  __builtin_amdgcn_global_load_lds(
      (__attribute__((address_space(1))) void*)(void*)g,
      (__attribute__((address_space(3))) void*)lds, 16, 0, 0);
}

// ---------------------------------------------------------------------------
// LayerNorm over last dim (1024) -> bf16. One block (256 thr) per row.
// ---------------------------------------------------------------------------
__global__ __launch_bounds__(256) void ln_rows_bf16(
    const float* __restrict__ X, const float* __restrict__ G,
    const float* __restrict__ Bt, __hip_bfloat16* __restrict__ O) {
  long row = blockIdx.x;
  int t = threadIdx.x;
  const float4 xv = ((const float4*)(X + row * 1024))[t];
  float s = xv.x + xv.y + xv.z + xv.w;
  float q = xv.x * xv.x + xv.y * xv.y + xv.z * xv.z + xv.w * xv.w;
#pragma unroll
  for (int o = 32; o; o >>= 1) {
    s += __shfl_xor(s, o);
    q += __shfl_xor(q, o);
  }
  __shared__ float rs[4], rq[4];
  int wid = t >> 6;
  if ((t & 63) == 0) { rs[wid] = s; rq[wid] = q; }
  __syncthreads();
  s = rs[0] + rs[1] + rs[2] + rs[3];
  q = rq[0] + rq[1] + rq[2] + rq[3];
  float mean = s * (1.f / 1024.f);
  float var = q * (1.f / 1024.f) - mean * mean;
  float rstd = rsqrtf(var + 1e-5f);
  const float4 gv = ((const float4*)G)[t];
  const float4 bv = ((const float4*)Bt)[t];
  __hip_bfloat16* o = O + row * 1024 + t * 4;
  o[0] = __float2bfloat16((xv.x - mean) * rstd * gv.x + bv.x);
  o[1] = __float2bfloat16((xv.y - mean) * rstd * gv.y + bv.y);
  o[2] = __float2bfloat16((xv.z - mean) * rstd * gv.z + bv.z);
  o[3] = __float2bfloat16((xv.w - mean) * rstd * gv.w + bv.w);
}

// ---------------------------------------------------------------------------
// Batched weight transpose-convert: 7x f32 [1024,1024] -> bf16 ^T w/ scale.
// ---------------------------------------------------------------------------
struct TC7 {
  const float* in[7];
  __hip_bfloat16* out[7];
  float scale[7];
};
__global__ __launch_bounds__(256) void tconv7(TC7 p) {
  __shared__ float t[32][33];
  int j = blockIdx.z;
  const float* in = p.in[j];
  __hip_bfloat16* out = p.out[j];
  float sc = p.scale[j];
  int c0 = blockIdx.x * 32, r0 = blockIdx.y * 32;
  int tid = threadIdx.x;
  int lr = tid >> 3, lc = (tid & 7) * 4;
  const float4 v = *(const float4*)&in[(long)(r0 + lr) * 1024 + c0 + lc];
  t[lr][lc] = v.x; t[lr][lc + 1] = v.y; t[lr][lc + 2] = v.z; t[lr][lc + 3] = v.w;
  __syncthreads();
  int oc = tid >> 3, orr = (tid & 7) * 4;
  __hip_bfloat16* o = &out[(long)(c0 + oc) * 1024 + r0 + orr];
  o[0] = __float2bfloat16(t[orr][oc] * sc);
  o[1] = __float2bfloat16(t[orr + 1][oc] * sc);
  o[2] = __float2bfloat16(t[orr + 2][oc] * sc);
  o[3] = __float2bfloat16(t[orr + 3][oc] * sc);
}

// Generic transpose-convert f32 [R,C] -> bf16 [C,R]. grid (C/32, R/32).
__global__ __launch_bounds__(256) void tconv_f32_bf16(
    const float* __restrict__ in, __hip_bfloat16* __restrict__ out, int R,
    int C) {
  __shared__ float t[32][33];
  int c0 = blockIdx.x * 32, r0 = blockIdx.y * 32;
  int tid = threadIdx.x;
  int lr = tid >> 3, lc = (tid & 7) * 4;
  const float4 v = *(const float4*)&in[(long)(r0 + lr) * C + c0 + lc];
  t[lr][lc] = v.x; t[lr][lc + 1] = v.y; t[lr][lc + 2] = v.z; t[lr][lc + 3] = v.w;
  __syncthreads();
  int oc = tid >> 3, orr = (tid & 7) * 4;
  __hip_bfloat16* o = &out[(long)(c0 + oc) * R + r0 + orr];
  o[0] = __float2bfloat16(t[orr][oc]);
  o[1] = __float2bfloat16(t[orr + 1][oc]);
  o[2] = __float2bfloat16(t[orr + 2][oc]);
  o[3] = __float2bfloat16(t[orr + 3][oc]);
}

// Batched bf16 transpose, strided input -> packed [bz][C][R].
__global__ __launch_bounds__(256) void tconv_bf16(
    const __hip_bfloat16* __restrict__ in, __hip_bfloat16* __restrict__ out,
    int R, int C, int ldin, long sIn) {
  __shared__ __hip_bfloat16 t[32][34];
  int bz = blockIdx.z;
  long ibase = (long)bz * sIn;
  long obase = (long)bz * R * C;
  int c0 = blockIdx.x * 32, r0 = blockIdx.y * 32;
  int tid = threadIdx.x;
  int lr = tid >> 3, lc = (tid & 7) * 4;
  const __hip_bfloat16* ip = &in[ibase + (long)(r0 + lr) * ldin + c0 + lc];
  t[lr][lc] = ip[0]; t[lr][lc + 1] = ip[1]; t[lr][lc + 2] = ip[2]; t[lr][lc + 3] = ip[3];
  __syncthreads();
  int oc = tid >> 3, orr = (tid & 7) * 4;
  __hip_bfloat16* o = &out[obase + (long)(c0 + oc) * R + r0 + orr];
  o[0] = t[orr][oc];
  o[1] = t[orr + 1][oc];
  o[2] = t[orr + 2][oc];
  o[3] = t[orr + 3][oc];
}

// concat 6 bias vectors (x1024) with per-segment scale -> bias6[6144]
struct BC6 {
  const float* b[6];
  float scale[6];
};
__global__ __launch_bounds__(256) void bias_concat(BC6 p, float* __restrict__ o) {
  int idx = blockIdx.x * 256 + threadIdx.x;
  int j = idx >> 10, e = idx & 1023;
  o[idx] = p.b[j][e] * p.scale[j];
}

// ---------------------------------------------------------------------------
// gemm256<BN>: BM=256, BK=64, 512 thr = 8 waves (2M x 4N).
// Pipeline: stage(t+1) issued, counted vmcnt(NLOADS) retires stage(t) only,
// raw s_barrier (no vmcnt(0) drain), MFMA, barrier. LDS linear store with
// pre-swizzled global source chunk ((tid&7)^(srow&7)); ds_read XORs the same
// involution -> bank-conflict-free-ish. 2D XCD chunking (4x2).
// Split-K via blockIdx.z: K per-split; writes C + z*sC (f32 when obf=0).
// ---------------------------------------------------------------------------
template <int BN>
__global__ __launch_bounds__(512, 2) void gemm256(
    const __hip_bfloat16* __restrict__ A, const __hip_bfloat16* __restrict__ Bt,
    const float* __restrict__ bias, void* __restrict__ C, int K, int lda,
    int ldb, int ldc, int act, int obf, long sC) {
  constexpr int NR = BN / 64;
  constexpr int ABYTES = 256 * 128;
  constexpr int BBYTES = BN * 128;
  constexpr int BUF = ABYTES + BBYTES;
  __shared__ char lds[2 * BUF];

  // 2D XCD chunking: xcd = wg&7 (HW round-robin); 4x2 XCD tile-grid.
  int bx, by;
  {
    int wg = blockIdx.y * gridDim.x + blockIdx.x;
    int gx = gridDim.x, gy = gridDim.y;
    if ((gx & 3) == 0 && (gy & 1) == 0) {
      int cw = gx >> 2, ch = gy >> 1;
      int xcd = wg & 7, idx = wg >> 3;
      bx = (xcd & 3) * cw + idx % cw;
      by = (xcd >> 2) * ch + idx / cw;
    } else {
      bx = blockIdx.x;
      by = blockIdx.y;
    }
  }
  const int m0 = by * 256, n0 = bx * BN;
  const int z = blockIdx.z;
  const long kbase = (long)z * K * 2;

  const int tid = threadIdx.x;
  const int lane = tid & 63, wid = tid >> 6;
  const int wm = wid >> 2, wn = wid & 3;
  const int ll = lane & 15, lh = lane >> 4;

  const char* Ag = (const char*)A;
  const char* Bg = (const char*)Bt;
  const int srow = tid >> 3;                              // 0..63
  const int scb = (((tid & 7) ^ (srow & 7)) << 4);        // swizzled src chunk
  const int sld = (tid & 7) << 4;                         // linear LDS chunk

  auto stage = [&](int t, int bsel) {
    char* base = lds + bsel * BUF;
    long kb = kbase + (long)t * 128;
#pragma unroll
    for (int l = 0; l < 4; ++l) {
      int row = l * 64 + srow;
      async_copy16(base + row * 128 + sld,
                   Ag + ((long)(m0 + row) * lda) * 2 + kb + scb);
    }
#pragma unroll
    for (int l = 0; l < BN / 64; ++l) {
      int row = l * 64 + srow;
      async_copy16(base + ABYTES + row * 128 + sld,
                   Bg + ((long)(n0 + row) * ldb) * 2 + kb + scb);
    }
  };

  // swizzled read chunk offsets (per-lane constant): row&7 == ll&7
  const int rx = ll & 7;
  const int ck[2] = {((0 + lh) ^ rx) << 4, ((4 + lh) ^ rx) << 4};

  f32x4 acc[8][NR];
#pragma unroll
  for (int m = 0; m < 8; ++m)
#pragma unroll
    for (int n = 0; n < NR; ++n) acc[m][n] = (f32x4){0.f, 0.f, 0.f, 0.f};

  const int nt = K >> 6;
  stage(0, 0);

  for (int t = 0; t < nt; ++t) {
    int bt = t & 1;
    if (t + 1 < nt) {
      stage(t + 1, bt ^ 1);
      if constexpr (BN == 128)
        asm volatile("s_waitcnt vmcnt(6)" ::: "memory");
      else
        asm volatile("s_waitcnt vmcnt(8)" ::: "memory");
    } else {
      asm volatile("s_waitcnt vmcnt(0)" ::: "memory");
    }
    __builtin_amdgcn_s_barrier();
    __builtin_amdgcn_sched_barrier(0);

    const char* Ab = lds + bt * BUF;
    const char* Bb = Ab + ABYTES;
#pragma unroll
    for (int ks = 0; ks < 2; ++ks) {
      bf16x8 af[8], bf[NR];
#pragma unroll
      for (int m = 0; m < 8; ++m)
        af[m] = *(const bf16x8*)(Ab + (wm * 128 + m * 16 + ll) * 128 + ck[ks]);
#pragma unroll
      for (int n = 0; n < NR; ++n)
        bf[n] = *(const bf16x8*)(Bb + (wn * (BN / 4) + n * 16 + ll) * 128 +
                                 ck[ks]);
      __builtin_amdgcn_s_setprio(1);
#pragma unroll
      for (int m = 0; m < 8; ++m)
#pragma unroll
        for (int n = 0; n < NR; ++n)
          acc[m][n] = __builtin_amdgcn_mfma_f32_16x16x32_bf16(af[m], bf[n],
                                                              acc[m][n], 0, 0, 0);
      __builtin_amdgcn_s_setprio(0);
    }
    __builtin_amdgcn_sched_barrier(0);
    __builtin_amdgcn_s_barrier();
  }

#pragma unroll
  for (int m = 0; m < 8; ++m) {
    int row = m0 + wm * 128 + m * 16 + lh * 4;
#pragma unroll
    for (int n = 0; n < NR; ++n) {
      int col = n0 + wn * (BN / 4) + n * 16 + ll;
      float bs = bias ? bias[col] : 0.f;
#pragma unroll
      for (int r = 0; r < 4; ++r) {
        float v = acc[m][n][r] + bs;
        if (act) v = v * 0.5f * (1.f + erff(v * 0.70710678118f));
        long cidx = (long)z * sC + (long)(row + r) * ldc + col;
        if (obf)
          ((__hip_bfloat16*)C)[cidx] = __float2bfloat16(v);
        else
          ((float*)C)[cidx] = v;
      }
    }
  }
}

// FFN2 finalize: OUT = sum_z PART[z] + b2 + X2. float4/thread, grid 4096.
__global__ __launch_bounds__(256) void ffn2_reduce(
    const float* __restrict__ P, const float* __restrict__ X2,
    const float* __restrict__ b2, float* __restrict__ OUT) {
  int i = blockIdx.x * 256 + threadIdx.x;
  const long SP = 4194304;
  float4 a = ((const float4*)P)[i];
  float4 b = ((const float4*)(P + SP))[i];
  float4 c = ((const float4*)(P + 2 * SP))[i];
  float4 d = ((const float4*)(P + 3 * SP))[i];
  float4 xr = ((const float4*)X2)[i];
  const float4 bb = *(const float4*)(b2 + ((i & 255) * 4));
  float4 o;
  o.x = a.x + b.x + c.x + d.x + xr.x + bb.x;
  o.y = a.y + b.y + c.y + d.y + xr.y + bb.y;
  o.z = a.z + b.z + c.z + d.z + xr.z + bb.z;
  o.w = a.w + b.w + c.w + d.w + xr.w + bb.w;
  ((float4*)OUT)[i] = o;
}

// ---------------------------------------------------------------------------
// bf16 MFMA GEMM (NT), 128x128 tile, BK=32, 4 waves. XCD swizzle.
// ---------------------------------------------------------------------------
__global__ __launch_bounds__(256) void gemm_bf16_nt(
    const __hip_bfloat16* __restrict__ A, const __hip_bfloat16* __restrict__ Bt,
    const float* __restrict__ bias, const float* __restrict__ E1,
    const float* __restrict__ E2, void* __restrict__ C, int K, int lda,
    int ldb, int ldc, long sA, long sB, long sC, long sE, float alpha, int act,
    int obf) {
  __shared__ unsigned short AsU[128 * 32];
  __shared__ unsigned short BsU[128 * 32];
  const int tid = threadIdx.x;
  const int lane = tid & 63, wave = tid >> 6;
  const int wr = wave >> 1, wc = wave & 1;

  int nwg = gridDim.x * gridDim.y;
  int wg = blockIdx.y * gridDim.x + blockIdx.x;
  int bx = blockIdx.x, by = blockIdx.y;
  if ((nwg & 7) == 0) {
    int cpx = nwg >> 3;
    int sw = (wg & 7) * cpx + (wg >> 3);
    bx = sw % gridDim.x;
    by = sw / gridDim.x;
  }
  const int m0 = by * 128, n0 = bx * 128;
  const int bz = blockIdx.z;
  const char* Ab = (const char*)(A + (long)bz * sA);
  const char* Bb = (const char*)(Bt + (long)bz * sB);

  f32x4 acc[4][4];
#pragma unroll
  for (int m = 0; m < 4; ++m)
#pragma unroll
    for (int n = 0; n < 4; ++n) acc[m][n] = (f32x4){0.f, 0.f, 0.f, 0.f};

  const int srow = tid >> 2;
  const int scol = (tid & 3) * 16;
  const int wbase = (tid >> 6) * 1024;

  for (int k0 = 0; k0 < K; k0 += 32) {
#pragma unroll
    for (int i = 0; i < 2; ++i) {
      async_copy16((char*)AsU + i * 4096 + wbase,
                   Ab + ((long)(m0 + i * 64 + srow) * lda + k0) * 2 + scol);
      async_copy16((char*)BsU + i * 4096 + wbase,
                   Bb + ((long)(n0 + i * 64 + srow) * ldb + k0) * 2 + scol);
    }
    __syncthreads();

    const int koff = (lane >> 4) * 8;
    bf16x8 a[4], b[4];
#pragma unroll
    for (int m = 0; m < 4; ++m)
      a[m] = *(const bf16x8*)&AsU[(wr * 64 + m * 16 + (lane & 15)) * 32 + koff];
#pragma unroll
    for (int n = 0; n < 4; ++n)
      b[n] = *(const bf16x8*)&BsU[(wc * 64 + n * 16 + (lane & 15)) * 32 + koff];
#pragma unroll
    for (int m = 0; m < 4; ++m)
#pragma unroll
      for (int n = 0; n < 4; ++n)
        acc[m][n] = __builtin_amdgcn_mfma_f32_16x16x32_bf16(a[m], b[n],
                                                            acc[m][n], 0, 0, 0);
    __syncthreads();
  }

#pragma unroll
  for (int m = 0; m < 4; ++m) {
    int row = m0 + wr * 64 + m * 16 + (lane >> 4) * 4;
#pragma unroll
    for (int n = 0; n < 4; ++n) {
      int col = n0 + wc * 64 + n * 16 + (lane & 15);
      float bs = bias ? bias[col] : 0.f;
#pragma unroll
      for (int r = 0; r < 4; ++r) {
        float v = (acc[m][n][r] + bs) * alpha;
        long eidx = (long)bz * sE + (long)(row + r) * ldc + col;
        if (E1) v += E1[eidx];
        if (E2) v += E2[eidx];
        if (act) v = v * 0.5f * (1.f + erff(v * 0.70710678118f));
        long cidx = (long)bz * sC + (long)(row + r) * ldc + col;
        if (obf)
          ((__hip_bfloat16*)C)[cidx] = __float2bfloat16(v);
        else
          ((float*)C)[cidx] = v;
      }
    }
  }
}

// ---------------------------------------------------------------------------
// MFMA attention. Block = (i-tile of 32, h, b); 4 waves. Reads bias+mask raw.
// ---------------------------------------------------------------------------
__global__ __launch_bounds__(256) void attn_mfma(
    const __hip_bfloat16* __restrict__ Q, const __hip_bfloat16* __restrict__ K,
    const __hip_bfloat16* __restrict__ VT, const float* __restrict__ BiasP,
    const float* __restrict__ MaskP, __hip_bfloat16* __restrict__ O,
    int ldqk) {
  __shared__ __hip_bfloat16 P[32][520];
  __shared__ float red[2][32][4];
  const int it = blockIdx.x, h = blockIdx.y, b = blockIdx.z;
  const int i0 = it * 32;
  const int tid = threadIdx.x;
  const int lane = tid & 63, w = tid >> 6;
  const int lh = lane >> 4, ll = lane & 15;

  const long qkb = (long)b * 512 * ldqk + h * 64;

  bf16x8 a[2][2];
#pragma unroll
  for (int m = 0; m < 2; ++m)
#pragma unroll
    for (int ks = 0; ks < 2; ++ks)
      a[m][ks] = *(const bf16x8*)&Q[qkb + (long)(i0 + m * 16 + ll) * ldqk +
                                    ks * 32 + lh * 8];

  f32x4 acc[2][8];
#pragma unroll
  for (int m = 0; m < 2; ++m)
#pragma unroll
    for (int n = 0; n < 8; ++n) acc[m][n] = (f32x4){0.f, 0.f, 0.f, 0.f};

#pragma unroll
  for (int n = 0; n < 8; ++n) {
    const __hip_bfloat16* kp =
        &K[qkb + (long)(w * 128 + n * 16 + ll) * ldqk + lh * 8];
    bf16x8 b0 = *(const bf16x8*)&kp[0];
    bf16x8 b1 = *(const bf16x8*)&kp[32];
#pragma unroll
    for (int m = 0; m < 2; ++m) {
      acc[m][n] =
          __builtin_amdgcn_mfma_f32_16x16x32_bf16(a[m][0], b0, acc[m][n], 0, 0, 0);
      acc[m][n] =
          __builtin_amdgcn_mfma_f32_16x16x32_bf16(a[m][1], b1, acc[m][n], 0, 0, 0);
    }
  }

  const long bmo = ((long)b * 512 + i0) * 512 + w * 128;
#pragma unroll
  for (int m = 0; m < 2; ++m)
#pragma unroll
    for (int r = 0; r < 4; ++r) {
      int row = m * 16 + lh * 4 + r;
#pragma unroll
      for (int n = 0; n < 8; ++n) {
        long gi = bmo + (long)row * 512 + n * 16 + ll;
        acc[m][n][r] += BiasP[gi] + MaskP[gi];
      }
    }

  float rmax[2][4];
#pragma unroll
  for (int m = 0; m < 2; ++m)
#pragma unroll
    for (int r = 0; r < 4; ++r) {
      float v = acc[m][0][r];
#pragma unroll
      for (int n = 1; n < 8; ++n) v = fmaxf(v, acc[m][n][r]);
#pragma unroll
      for (int o = 1; o < 16; o <<= 1) v = fmaxf(v, __shfl_xor(v, o));
      rmax[m][r] = v;
    }
  if (ll == 0) {
#pragma unroll
    for (int m = 0; m < 2; ++m)
#pragma unroll
      for (int r = 0; r < 4; ++r) red[0][m * 16 + lh * 4 + r][w] = rmax[m][r];
  }
  __syncthreads();
#pragma unroll
  for (int m = 0; m < 2; ++m)
#pragma unroll
    for (int r = 0; r < 4; ++r) {
      const float* p = red[0][m * 16 + lh * 4 + r];
      rmax[m][r] = fmaxf(fmaxf(p[0], p[1]), fmaxf(p[2], p[3]));
    }
  float rsum[2][4];
#pragma unroll
  for (int m = 0; m < 2; ++m)
#pragma unroll
    for (int r = 0; r < 4; ++r) {
      float s = 0.f;
#pragma unroll
      for (int n = 0; n < 8; ++n) {
        float e = __expf(acc[m][n][r] - rmax[m][r]);
        acc[m][n][r] = e;
        s += e;
      }
#pragma unroll
      for (int o = 1; o < 16; o <<= 1) s += __shfl_xor(s, o);
      rsum[m][r] = s;
    }
  if (ll == 0) {
#pragma unroll
    for (int m = 0; m < 2; ++m)
#pragma unroll
      for (int r = 0; r < 4; ++r) red[1][m * 16 + lh * 4 + r][w] = rsum[m][r];
  }
  __syncthreads();
#pragma unroll
  for (int m = 0; m < 2; ++m)
#pragma unroll
    for (int r = 0; r < 4; ++r) {
      const float* p = red[1][m * 16 + lh * 4 + r];
      float inv = 1.f / (p[0] + p[1] + p[2] + p[3]);
      int row = m * 16 + lh * 4 + r;
#pragma unroll
      for (int n = 0; n < 8; ++n)
        P[row][w * 128 + n * 16 + ll] = __float2bfloat16(acc[m][n][r] * inv);
    }
  __syncthreads();

  const long vtb = ((long)b * 1024 + h * 64) * 512;
  const long ob = (long)b * 512 * 1024 + h * 64;
  const int mw = (w >> 1) * 16, nw = (w & 1) * 32;
  f32x4 oacc[2];
  oacc[0] = (f32x4){0.f, 0.f, 0.f, 0.f};
  oacc[1] = (f32x4){0.f, 0.f, 0.f, 0.f};
#pragma unroll
  for (int ks = 0; ks < 16; ++ks) {
    int k0 = ks * 32;
    bf16x8 pa = *(const bf16x8*)&P[mw + ll][k0 + lh * 8];
#pragma unroll
    for (int nf = 0; nf < 2; ++nf) {
      bf16x8 vb = *(const bf16x8*)&VT[vtb + (long)(nw + nf * 16 + ll) * 512 +
                                      k0 + lh * 8];
      oacc[nf] =
          __builtin_amdgcn_mfma_f32_16x16x32_bf16(pa, vb, oacc[nf], 0, 0, 0);
    }
  }
#pragma unroll
  for (int nf = 0; nf < 2; ++nf)
#pragma unroll
    for (int r = 0; r < 4; ++r)
      O[ob + (long)(i0 + mw + lh * 4 + r) * 1024 + nw + nf * 16 + ll] =
          __float2bfloat16(oacc[nf][r]);
}

// ---------------------------------------------------------------------------
// Row softmax (512) f32 in -> bf16 out. One block per row.
// ---------------------------------------------------------------------------
__global__ __launch_bounds__(256) void softmax_rows(
    const float* __restrict__ P, __hip_bfloat16* __restrict__ Ob) {
  const float* row = P + (long)blockIdx.x * 512;
  __hip_bfloat16* orow = Ob + (long)blockIdx.x * 512;
  int t = threadIdx.x;
  float v0 = row[t], v1 = row[t + 256];
  float m = fmaxf(v0, v1);
#pragma unroll
  for (int o = 32; o; o >>= 1) m = fmaxf(m, __shfl_xor(m, o));
  __shared__ float red[8];
  int wid = t >> 6, lane = t & 63;
  if (!lane) red[wid] = m;
  __syncthreads();
  m = fmaxf(fmaxf(red[0], red[1]), fmaxf(red[2], red[3]));
  float e0 = __expf(v0 - m), e1 = __expf(v1 - m);
  float s = e0 + e1;
#pragma unroll
  for (int o = 32; o; o >>= 1) s += __shfl_xor(s, o);
  if (!lane) red[4 + wid] = s;
  __syncthreads();
  s = red[4] + red[5] + red[6] + red[7];
  float inv = 1.f / s;
  orow[t] = __float2bfloat16(e0 * inv);
  orow[t + 256] = __float2bfloat16(e1 * inv);
}

// ---------------------------------------------------------------------------
// path gather-mean partials + finalize.
// ---------------------------------------------------------------------------
__global__ __launch_bounds__(256) void path_partial(
    const float* __restrict__ xp, const int* __restrict__ pp,
    float* __restrict__ PP, float* __restrict__ WS) {
  int b = blockIdx.x, hc = blockIdx.y, ic = blockIdx.z;
  int h = hc * 256 + threadIdx.x;
  const int* ppb = pp + b * 512;
  const float* xb = xp + (long)b * 512 * 1024;
  int iA = ic * 64, iB = iA + 64;
  float acc = 0.f;
  for (int i = iA; i < iB; ++i) {
    if (ppb[i] != 1) continue;
    float cur = xb[(long)i * 1024 + h];
    float a;
    if (i == 0) {
      a = 0.5f * (cur + xb[1024 + h]);
    } else if (i == 1) {
      a = (xb[h] + cur + xb[2 * 1024 + h]) * (1.f / 3.f);
    } else {
      int inx = (i + 1 < 512) ? i + 1 : 511;
      float nx = xb[(long)inx * 1024 + h];
      if (ppb[i - 2] == 1) {
        a = 0.5f * (cur + nx);
      } else {
        a = (xb[(long)(i - 1) * 1024 + h] + cur + nx) * (1.f / 3.f);
      }
    }
    acc += a;
  }
  PP[((long)b * 8 + ic) * 1024 + h] = acc;
  if (hc == 0 && threadIdx.x == 0) {
    float c = 0.f;
    for (int i = iA; i < iB; ++i) c += (ppb[i] == 1) ? 1.f : 0.f;
    WS[b * 8 + ic] = c;
  }
}

__global__ __launch_bounds__(256) void path_finalize(
    const float* __restrict__ PP, const float* __restrict__ WS,
    float* __restrict__ PATH) {
  int b = blockIdx.x;
  int h = blockIdx.y * 256 + threadIdx.x;
  float s = 0.f, w = 0.f;
#pragma unroll
  for (int ic = 0; ic < 8; ++ic) {
    s += PP[((long)b * 8 + ic) * 1024 + h];
    w += WS[b * 8 + ic];
  }
  PATH[b * 1024 + h] = s / w;
}

// ---------------------------------------------------------------------------
// Fused: X2 = x + 0.5*(YSELF + PATH); Y2b = LN(X2). One block per row.
// ---------------------------------------------------------------------------
__global__ __launch_bounds__(256) void combine_ln2(
    const float* __restrict__ X, const float* __restrict__ YS,
    const float* __restrict__ PT, const float* __restrict__ G,
    const float* __restrict__ Bt, float* __restrict__ X2,
    __hip_bfloat16* __restrict__ Y2b) {
  long row = blockIdx.x;
  int b = (int)(row >> 9);
  int t = threadIdx.x;
  const float4 xv = ((const float4*)(X + row * 1024))[t];
  const float4 sv = ((const float4*)(YS + row * 1024))[t];
  const float4 pv = *(const float4*)(PT + b * 1024 + t * 4);
  float4 v;
  v.x = xv.x + 0.5f * (sv.x + pv.x);
  v.y = xv.y + 0.5f * (sv.y + pv.y);
  v.z = xv.z + 0.5f * (sv.z + pv.z);
  v.w = xv.w + 0.5f * (sv.w + pv.w);
  ((float4*)(X2 + row * 1024))[t] = v;

  float s = v.x + v.y + v.z + v.w;
  float q = v.x * v.x + v.y * v.y + v.z * v.z + v.w * v.w;
#pragma unroll
  for (int o = 32; o; o >>= 1) {
    s += __shfl_xor(s, o);
    q += __shfl_xor(q, o);
  }
  __shared__ float rs[4], rq[4];
  int wid = t >> 6;
  if ((t & 63) == 0) { rs[wid] = s; rq[wid] = q; }
  __syncthreads();
  s = rs[0] + rs[1] + rs[2] + rs[3];
  q = rq[0] + rq[1] + rq[2] + rq[3];
  float mean = s * (1.f / 1024.f);
  float var = q * (1.f / 1024.f) - mean * mean;
  float rstd = rsqrtf(var + 1e-5f);
  const float4 gv = ((const float4*)G)[t];
  const float4 bv = ((const float4*)Bt)[t];
  __hip_bfloat16* o = Y2b + row * 1024 + t * 4;
  o[0] = __float2bfloat16((v.x - mean) * rstd * gv.x + bv.x);
  o[1] = __float2bfloat16((v.y - mean) * rstd * gv.y + bv.y);
  o[2] = __float2bfloat16((v.z - mean) * rstd * gv.z + bv.z);
  o[3] = __float2bfloat16((v.w - mean) * rstd * gv.w + bv.w);
}

// ---------------------------------------------------------------------------
extern "C" void kernel_launch(void* const* d_in, const int* in_sizes, int n_in,
                              void* d_out, int out_size, void* d_ws,
                              size_t ws_size, hipStream_t stream) {
  const float* x = (const float*)d_in[0];
  const int* pp = (const int*)d_in[1];
  const float* abias = (const float*)d_in[3];
  const float* amask = (const float*)d_in[4];
  const float* agraph = (const float*)d_in[5];
  const float* vgraph = (const float*)d_in[6];
  const float* ln1g = (const float*)d_in[7];
  const float* ln1b = (const float*)d_in[8];
  const float* wq = (const float*)d_in[9];
  const float* bq = (const float*)d_in[10];
  const float* wk = (const float*)d_in[11];
  const float* bk = (const float*)d_in[12];
  const float* wv = (const float*)d_in[13];
  const float* bv = (const float*)d_in[14];
  const float* wo = (const float*)d_in[15];
  const float* bo = (const float*)d_in[16];
  const float* pqw = (const float*)d_in[17];
  const float* pqb = (const float*)d_in[18];
  const float* pkw = (const float*)d_in[19];
  const float* pkb = (const float*)d_in[20];
  const float* pvw = (const float*)d_in[21];
  const float* pvb = (const float*)d_in[22];
  const float* ln2g = (const float*)d_in[23];
  const float* ln2b = (const float*)d_in[24];
  const float* w1 = (const float*)d_in[25];
  const float* b1 = (const float*)d_in[26];
  const float* w2 = (const float*)d_in[27];
  const float* b2 = (const float*)d_in[28];

  char* wsb = (char*)d_ws;
  auto Ybf = (__hip_bfloat16*)(wsb);                  // 0-8 (later Y2b)
  auto QKV = (__hip_bfloat16*)(wsb + (8l << 20));     // 8-56: [4096][6144]
  auto VTb = (__hip_bfloat16*)(wsb + (56l << 20));    // 56-64
  auto PVT = (__hip_bfloat16*)(wsb + (64l << 20));    // 64-72
  auto ATTb = (__hip_bfloat16*)(wsb + (72l << 20));   // 72-80 (later W2T)
  auto PATTb = (__hip_bfloat16*)(wsb + (88l << 20));  // 88-92
  auto PATTf = (float*)(wsb + (92l << 20));           // 92-100
  auto XP = (float*)(wsb + (92l << 20));              // 92-108
  auto WALL = (__hip_bfloat16*)(wsb + (108l << 20));  // 108-120: [6144][1024]
  auto WOT = (__hip_bfloat16*)(wsb + (120l << 20));   // 120-122
  auto W1T = (__hip_bfloat16*)(wsb + (122l << 20));   // 122-130
  auto bias6 = (float*)(wsb + (130l << 20));          // 24KB
  auto PPart = (float*)(wsb + (131l << 20));          // 256KB
  auto WSp = (float*)(wsb + (132l << 20));            // 256B
  auto PATH = (float*)(wsb + (133l << 20));           // 32KB
  auto YSELF = (float*)(wsb + (8l << 20));            // 8-24 (QKV dead)
  auto X2 = (float*)(wsb + (24l << 20));              // 24-40
  auto HMID = (__hip_bfloat16*)(wsb + (40l << 20));   // 40-72
  auto W2T = ATTb;
  auto PART = (float*)(wsb + (92l << 20));            // 92-156 (4x16MB f32)
  __hip_bfloat16* Y2b = Ybf;
  float* OUT = (float*)d_out;

  const float qscale = 0.125f;
  const float pscale = 0.03125f;
  const long S2 = 512l * 512;
  const long SQ = 512l * 6144;

  __hip_bfloat16* Qp = QKV;
  __hip_bfloat16* Kp = QKV + 1024;
  __hip_bfloat16* Vp = QKV + 2048;
  __hip_bfloat16* PQp = QKV + 3072;
  __hip_bfloat16* PKp = QKV + 4096;
  __hip_bfloat16* PVp = QKV + 5120;

  // 0) weight transposes + bias concat
  TC7 tp;
  tp.in[0] = wq;  tp.out[0] = WALL;                 tp.scale[0] = qscale;
  tp.in[1] = wk;  tp.out[1] = WALL + 1024 * 1024;   tp.scale[1] = 1.f;
  tp.in[2] = wv;  tp.out[2] = WALL + 2048 * 1024;   tp.scale[2] = 1.f;
  tp.in[3] = pqw; tp.out[3] = WALL + 3072 * 1024;   tp.scale[3] = pscale;
  tp.in[4] = pkw; tp.out[4] = WALL + 4096 * 1024;   tp.scale[4] = 1.f;
  tp.in[5] = pvw; tp.out[5] = WALL + 5120 * 1024;   tp.scale[5] = 1.f;
  tp.in[6] = wo;  tp.out[6] = WOT;                  tp.scale[6] = 1.f;
  tconv7<<<dim3(32, 32, 7), 256, 0, stream>>>(tp);
  tconv_f32_bf16<<<dim3(128, 32), 256, 0, stream>>>(w1, W1T, 1024, 4096);

  BC6 bp;
  bp.b[0] = bq;  bp.scale[0] = qscale;
  bp.b[1] = bk;  bp.scale[1] = 1.f;
  bp.b[2] = bv;  bp.scale[2] = 1.f;
  bp.b[3] = pqb; bp.scale[3] = pscale;
  bp.b[4] = pkb; bp.scale[4] = 1.f;
  bp.b[5] = pvb; bp.scale[5] = 1.f;
  bias_concat<<<24, 256, 0, stream>>>(bp, bias6);

  // 1) LN1 -> Ybf
  ln_rows_bf16<<<4096, 256, 0, stream>>>(x, ln1g, ln1b, Ybf);

  // 2) fused projections via gemm256<128>: M=4096 (y=16), N=6144 (x=48)
  gemm256<128><<<dim3(48, 16, 1), 512, 0, stream>>>(
      Ybf, WALL, bias6, QKV, 1024, 1024, 1024, 6144, 0, 1, 0);

  // 3) transposes: V -> VT, PV -> PVT
  tconv_bf16<<<dim3(32, 16, 8), 256, 0, stream>>>(Vp, VTb, 512, 1024, 6144, SQ);
  tconv_bf16<<<dim3(32, 16, 8), 256, 0, stream>>>(PVp, PVT, 512, 1024, 6144, SQ);

  // 4) path scores + softmax
  gemm_bf16_nt<<<dim3(4, 4, 8), 256, 0, stream>>>(
      PQp, PKp, nullptr, agraph, vgraph, PATTf, 1024, 6144, 6144, 512, SQ, SQ,
      S2, S2, 1.f, 0, 0);
  softmax_rows<<<4096, 256, 0, stream>>>(PATTf, PATTb);

  // 5) MFMA attention -> ATTb (reads bias + mask directly)
  attn_mfma<<<dim3(16, 16, 8), 256, 0, stream>>>(Qp, Kp, VTb, abias, amask,
                                                 ATTb, 6144);

  // 6) XP = PATT @ PVT^T
  gemm_bf16_nt<<<dim3(8, 4, 8), 256, 0, stream>>>(
      PATTb, PVT, nullptr, nullptr, nullptr, XP, 512, 512, 512, 1024, S2,
      512l * 1024, 512l * 1024, 0, 1.f, 0, 0);

  // 7) path gather-mean
  path_partial<<<dim3(8, 4, 8), 256, 0, stream>>>(XP, pp, PPart, WSp);
  path_finalize<<<dim3(8, 4), 256, 0, stream>>>(PPart, WSp, PATH);

  // 8) y_self = ATT @ wo + bo (f32, overlays QKV lo)
  gemm_bf16_nt<<<dim3(8, 32, 1), 256, 0, stream>>>(
      ATTb, WOT, bo, nullptr, nullptr, YSELF, 1024, 1024, 1024, 1024, 0, 0, 0,
      0, 1.f, 0, 0);

  // 8b) W2 transpose into ATTb's slot
  tconv_f32_bf16<<<dim3(32, 128), 256, 0, stream>>>(w2, W2T, 4096, 1024);

  // 9+10) fused combine + LN2
  combine_ln2<<<4096, 256, 0, stream>>>(x, YSELF, PATH, ln2g, ln2b, X2, Y2b);

  // 11) FFN1 via gemm256<256>: M=4096, N=4096, GELU, bf16 out
  gemm256<256><<<dim3(16, 16, 1), 512, 0, stream>>>(
      Y2b, W1T, b1, HMID, 1024, 1024, 1024, 4096, 1, 1, 0);

  // 12) FFN2 split-K=4: partials[z] = HMID[:, z*1024:(z+1)*1024] @ W2T^T
  gemm256<128><<<dim3(8, 16, 4), 512, 0, stream>>>(
      HMID, W2T, nullptr, PART, 1024, 4096, 4096, 1024, 0, 0, 4194304);

  // 12b) OUT = sum_z PART[z] + b2 + X2
  ffn2_reduce<<<4096, 256, 0, stream>>>(PART, X2, b2, OUT);
}

// Round 9
// 474.532 us; speedup vs baseline: 10.6846x; 1.0151x over previous
//
#include <hip/hip_runtime.h>
#include <hip/hip_bf16.h>
#include <math.h>

// B=8, S=512, H=1024, NH=16, DK=64, FF=4096.
// Round 9: (1) QKV + FFN2 -> 256x256 tile (gemm256<256>): LDS-read B/FLOP is
// the binding constraint at BN=128 (208KB per 4.2MFLOP vs 1.24k cyc MFMA);
// 256^2 cuts it ~40%. (2) combine fused into wo-gemm epilogue (pbc flag).

typedef __bf16 bf16x8 __attribute__((ext_vector_type(8)));
typedef float f32x4 __attribute__((ext_vector_type(4)));

__device__ __forceinline__ void async_copy16(void* lds, const void* g) {
  __builtin_amdgcn_global_load_lds(
      (__attribute__((address_space(1))) void*)(void*)g,
      (__attribute__((address_space(3))) void*)lds, 16, 0, 0);
}

// ---------------------------------------------------------------------------
// LayerNorm over last dim (1024) -> bf16. One block (256 thr) per row.
// ---------------------------------------------------------------------------
__global__ __launch_bounds__(256) void ln_rows_bf16(
    const float* __restrict__ X, const float* __restrict__ G,
    const float* __restrict__ Bt, __hip_bfloat16* __restrict__ O) {
  long row = blockIdx.x;
  int t = threadIdx.x;
  const float4 xv = ((const float4*)(X + row * 1024))[t];
  float s = xv.x + xv.y + xv.z + xv.w;
  float q = xv.x * xv.x + xv.y * xv.y + xv.z * xv.z + xv.w * xv.w;
#pragma unroll
  for (int o = 32; o; o >>= 1) {
    s += __shfl_xor(s, o);
    q += __shfl_xor(q, o);
  }
  __shared__ float rs[4], rq[4];
  int wid = t >> 6;
  if ((t & 63) == 0) { rs[wid] = s; rq[wid] = q; }
  __syncthreads();
  s = rs[0] + rs[1] + rs[2] + rs[3];
  q = rq[0] + rq[1] + rq[2] + rq[3];
  float mean = s * (1.f / 1024.f);
  float var = q * (1.f / 1024.f) - mean * mean;
  float rstd = rsqrtf(var + 1e-5f);
  const float4 gv = ((const float4*)G)[t];
  const float4 bv = ((const float4*)Bt)[t];
  __hip_bfloat16* o = O + row * 1024 + t * 4;
  o[0] = __float2bfloat16((xv.x - mean) * rstd * gv.x + bv.x);
  o[1] = __float2bfloat16((xv.y - mean) * rstd * gv.y + bv.y);
  o[2] = __float2bfloat16((xv.z - mean) * rstd * gv.z + bv.z);
  o[3] = __float2bfloat16((xv.w - mean) * rstd * gv.w + bv.w);
}

// ---------------------------------------------------------------------------
// Batched weight transpose-convert: 7x f32 [1024,1024] -> bf16 ^T w/ scale.
// ---------------------------------------------------------------------------
struct TC7 {
  const float* in[7];
  __hip_bfloat16* out[7];
  float scale[7];
};
__global__ __launch_bounds__(256) void tconv7(TC7 p) {
  __shared__ float t[32][33];
  int j = blockIdx.z;
  const float* in = p.in[j];
  __hip_bfloat16* out = p.out[j];
  float sc = p.scale[j];
  int c0 = blockIdx.x * 32, r0 = blockIdx.y * 32;
  int tid = threadIdx.x;
  int lr = tid >> 3, lc = (tid & 7) * 4;
  const float4 v = *(const float4*)&in[(long)(r0 + lr) * 1024 + c0 + lc];
  t[lr][lc] = v.x; t[lr][lc + 1] = v.y; t[lr][lc + 2] = v.z; t[lr][lc + 3] = v.w;
  __syncthreads();
  int oc = tid >> 3, orr = (tid & 7) * 4;
  __hip_bfloat16* o = &out[(long)(c0 + oc) * 1024 + r0 + orr];
  o[0] = __float2bfloat16(t[orr][oc] * sc);
  o[1] = __float2bfloat16(t[orr + 1][oc] * sc);
  o[2] = __float2bfloat16(t[orr + 2][oc] * sc);
  o[3] = __float2bfloat16(t[orr + 3][oc] * sc);
}

// Generic transpose-convert f32 [R,C] -> bf16 [C,R]. grid (C/32, R/32).
__global__ __launch_bounds__(256) void tconv_f32_bf16(
    const float* __restrict__ in, __hip_bfloat16* __restrict__ out, int R,
    int C) {
  __shared__ float t[32][33];
  int c0 = blockIdx.x * 32, r0 = blockIdx.y * 32;
  int tid = threadIdx.x;
  int lr = tid >> 3, lc = (tid & 7) * 4;
  const float4 v = *(const float4*)&in[(long)(r0 + lr) * C + c0 + lc];
  t[lr][lc] = v.x; t[lr][lc + 1] = v.y; t[lr][lc + 2] = v.z; t[lr][lc + 3] = v.w;
  __syncthreads();
  int oc = tid >> 3, orr = (tid & 7) * 4;
  __hip_bfloat16* o = &out[(long)(c0 + oc) * R + r0 + orr];
  o[0] = __float2bfloat16(t[orr][oc]);
  o[1] = __float2bfloat16(t[orr + 1][oc]);
  o[2] = __float2bfloat16(t[orr + 2][oc]);
  o[3] = __float2bfloat16(t[orr + 3][oc]);
}

// Batched bf16 transpose, strided input -> packed [bz][C][R].
__global__ __launch_bounds__(256) void tconv_bf16(
    const __hip_bfloat16* __restrict__ in, __hip_bfloat16* __restrict__ out,
    int R, int C, int ldin, long sIn) {
  __shared__ __hip_bfloat16 t[32][34];
  int bz = blockIdx.z;
  long ibase = (long)bz * sIn;
  long obase = (long)bz * R * C;
  int c0 = blockIdx.x * 32, r0 = blockIdx.y * 32;
  int tid = threadIdx.x;
  int lr = tid >> 3, lc = (tid & 7) * 4;
  const __hip_bfloat16* ip = &in[ibase + (long)(r0 + lr) * ldin + c0 + lc];
  t[lr][lc] = ip[0]; t[lr][lc + 1] = ip[1]; t[lr][lc + 2] = ip[2]; t[lr][lc + 3] = ip[3];
  __syncthreads();
  int oc = tid >> 3, orr = (tid & 7) * 4;
  __hip_bfloat16* o = &out[obase + (long)(c0 + oc) * R + r0 + orr];
  o[0] = t[orr][oc];
  o[1] = t[orr + 1][oc];
  o[2] = t[orr + 2][oc];
  o[3] = t[orr + 3][oc];
}

// concat 6 bias vectors (x1024) with per-segment scale -> bias6[6144]
struct BC6 {
  const float* b[6];
  float scale[6];
};
__global__ __launch_bounds__(256) void bias_concat(BC6 p, float* __restrict__ o) {
  int idx = blockIdx.x * 256 + threadIdx.x;
  int j = idx >> 10, e = idx & 1023;
  o[idx] = p.b[j][e] * p.scale[j];
}

// ---------------------------------------------------------------------------
// gemm256<BN>: BM=256, BK=64, 512 thr = 8 waves (2M x 4N).
// Counted-vmcnt double-buffer pipeline; LDS XOR chunk-swizzle (linear store,
// pre-swizzled global source, swizzled read); 2D XCD chunking (4x2).
// Split-K via blockIdx.z: K per-split; writes C + z*sC (f32 when obf=0).
// ---------------------------------------------------------------------------
template <int BN>
__global__ __launch_bounds__(512, 2) void gemm256(
    const __hip_bfloat16* __restrict__ A, const __hip_bfloat16* __restrict__ Bt,
    const float* __restrict__ bias, void* __restrict__ C, int K, int lda,
    int ldb, int ldc, int act, int obf, long sC) {
  constexpr int NR = BN / 64;
  constexpr int ABYTES = 256 * 128;
  constexpr int BBYTES = BN * 128;
  constexpr int BUF = ABYTES + BBYTES;
  __shared__ char lds[2 * BUF];

  int bx, by;
  {
    int wg = blockIdx.y * gridDim.x + blockIdx.x;
    int gx = gridDim.x, gy = gridDim.y;
    if ((gx & 3) == 0 && (gy & 1) == 0) {
      int cw = gx >> 2, ch = gy >> 1;
      int xcd = wg & 7, idx = wg >> 3;
      bx = (xcd & 3) * cw + idx % cw;
      by = (xcd >> 2) * ch + idx / cw;
    } else {
      bx = blockIdx.x;
      by = blockIdx.y;
    }
  }
  const int m0 = by * 256, n0 = bx * BN;
  const int z = blockIdx.z;
  const long kbase = (long)z * K * 2;

  const int tid = threadIdx.x;
  const int lane = tid & 63, wid = tid >> 6;
  const int wm = wid >> 2, wn = wid & 3;
  const int ll = lane & 15, lh = lane >> 4;

  const char* Ag = (const char*)A;
  const char* Bg = (const char*)Bt;
  const int srow = tid >> 3;
  const int scb = (((tid & 7) ^ (srow & 7)) << 4);  // swizzled src chunk
  const int sld = (tid & 7) << 4;                   // linear LDS chunk

  auto stage = [&](int t, int bsel) {
    char* base = lds + bsel * BUF;
    long kb = kbase + (long)t * 128;
#pragma unroll
    for (int l = 0; l < 4; ++l) {
      int row = l * 64 + srow;
      async_copy16(base + row * 128 + sld,
                   Ag + ((long)(m0 + row) * lda) * 2 + kb + scb);
    }
#pragma unroll
    for (int l = 0; l < BN / 64; ++l) {
      int row = l * 64 + srow;
      async_copy16(base + ABYTES + row * 128 + sld,
                   Bg + ((long)(n0 + row) * ldb) * 2 + kb + scb);
    }
  };

  const int rx = ll & 7;
  const int ck[2] = {((0 + lh) ^ rx) << 4, ((4 + lh) ^ rx) << 4};

  f32x4 acc[8][NR];
#pragma unroll
  for (int m = 0; m < 8; ++m)
#pragma unroll
    for (int n = 0; n < NR; ++n) acc[m][n] = (f32x4){0.f, 0.f, 0.f, 0.f};

  const int nt = K >> 6;
  stage(0, 0);

  for (int t = 0; t < nt; ++t) {
    int bt = t & 1;
    if (t + 1 < nt) {
      stage(t + 1, bt ^ 1);
      if constexpr (BN == 128)
        asm volatile("s_waitcnt vmcnt(6)" ::: "memory");
      else
        asm volatile("s_waitcnt vmcnt(8)" ::: "memory");
    } else {
      asm volatile("s_waitcnt vmcnt(0)" ::: "memory");
    }
    __builtin_amdgcn_s_barrier();
    __builtin_amdgcn_sched_barrier(0);

    const char* Ab = lds + bt * BUF;
    const char* Bb = Ab + ABYTES;
#pragma unroll
    for (int ks = 0; ks < 2; ++ks) {
      bf16x8 af[8], bf[NR];
#pragma unroll
      for (int m = 0; m < 8; ++m)
        af[m] = *(const bf16x8*)(Ab + (wm * 128 + m * 16 + ll) * 128 + ck[ks]);
#pragma unroll
      for (int n = 0; n < NR; ++n)
        bf[n] = *(const bf16x8*)(Bb + (wn * (BN / 4) + n * 16 + ll) * 128 +
                                 ck[ks]);
      __builtin_amdgcn_s_setprio(1);
#pragma unroll
      for (int m = 0; m < 8; ++m)
#pragma unroll
        for (int n = 0; n < NR; ++n)
          acc[m][n] = __builtin_amdgcn_mfma_f32_16x16x32_bf16(af[m], bf[n],
                                                              acc[m][n], 0, 0, 0);
      __builtin_amdgcn_s_setprio(0);
    }
    __builtin_amdgcn_sched_barrier(0);
    __builtin_amdgcn_s_barrier();
  }

#pragma unroll
  for (int m = 0; m < 8; ++m) {
    int row = m0 + wm * 128 + m * 16 + lh * 4;
#pragma unroll
    for (int n = 0; n < NR; ++n) {
      int col = n0 + wn * (BN / 4) + n * 16 + ll;
      float bs = bias ? bias[col] : 0.f;
#pragma unroll
      for (int r = 0; r < 4; ++r) {
        float v = acc[m][n][r] + bs;
        if (act) v = v * 0.5f * (1.f + erff(v * 0.70710678118f));
        long cidx = (long)z * sC + (long)(row + r) * ldc + col;
        if (obf)
          ((__hip_bfloat16*)C)[cidx] = __float2bfloat16(v);
        else
          ((float*)C)[cidx] = v;
      }
    }
  }
}

// FFN2 finalize: OUT = sum_z PART[z] + b2 + X2. float4/thread, grid 4096.
__global__ __launch_bounds__(256) void ffn2_reduce(
    const float* __restrict__ P, const float* __restrict__ X2,
    const float* __restrict__ b2, float* __restrict__ OUT) {
  int i = blockIdx.x * 256 + threadIdx.x;
  const long SP = 4194304;
  float4 a = ((const float4*)P)[i];
  float4 b = ((const float4*)(P + SP))[i];
  float4 c = ((const float4*)(P + 2 * SP))[i];
  float4 d = ((const float4*)(P + 3 * SP))[i];
  float4 xr = ((const float4*)X2)[i];
  const float4 bb = *(const float4*)(b2 + ((i & 255) * 4));
  float4 o;
  o.x = a.x + b.x + c.x + d.x + xr.x + bb.x;
  o.y = a.y + b.y + c.y + d.y + xr.y + bb.y;
  o.z = a.z + b.z + c.z + d.z + xr.z + bb.z;
  o.w = a.w + b.w + c.w + d.w + xr.w + bb.w;
  ((float4*)OUT)[i] = o;
}

// ---------------------------------------------------------------------------
// bf16 MFMA GEMM (NT), 128x128 tile, BK=32, 4 waves. XCD swizzle.
// pbc=1: C = E1 + 0.5*((A@Bt^T + bias) + E2[row>>9, col])  (combine fusion).
// ---------------------------------------------------------------------------
__global__ __launch_bounds__(256) void gemm_bf16_nt(
    const __hip_bfloat16* __restrict__ A, const __hip_bfloat16* __restrict__ Bt,
    const float* __restrict__ bias, const float* __restrict__ E1,
    const float* __restrict__ E2, void* __restrict__ C, int K, int lda,
    int ldb, int ldc, long sA, long sB, long sC, long sE, float alpha, int act,
    int obf, int pbc) {
  __shared__ unsigned short AsU[128 * 32];
  __shared__ unsigned short BsU[128 * 32];
  const int tid = threadIdx.x;
  const int lane = tid & 63, wave = tid >> 6;
  const int wr = wave >> 1, wc = wave & 1;

  int nwg = gridDim.x * gridDim.y;
  int wg = blockIdx.y * gridDim.x + blockIdx.x;
  int bx = blockIdx.x, by = blockIdx.y;
  if ((nwg & 7) == 0) {
    int cpx = nwg >> 3;
    int sw = (wg & 7) * cpx + (wg >> 3);
    bx = sw % gridDim.x;
    by = sw / gridDim.x;
  }
  const int m0 = by * 128, n0 = bx * 128;
  const int bz = blockIdx.z;
  const char* Ab = (const char*)(A + (long)bz * sA);
  const char* Bb = (const char*)(Bt + (long)bz * sB);

  f32x4 acc[4][4];
#pragma unroll
  for (int m = 0; m < 4; ++m)
#pragma unroll
    for (int n = 0; n < 4; ++n) acc[m][n] = (f32x4){0.f, 0.f, 0.f, 0.f};

  const int srow = tid >> 2;
  const int scol = (tid & 3) * 16;
  const int wbase = (tid >> 6) * 1024;

  for (int k0 = 0; k0 < K; k0 += 32) {
#pragma unroll
    for (int i = 0; i < 2; ++i) {
      async_copy16((char*)AsU + i * 4096 + wbase,
                   Ab + ((long)(m0 + i * 64 + srow) * lda + k0) * 2 + scol);
      async_copy16((char*)BsU + i * 4096 + wbase,
                   Bb + ((long)(n0 + i * 64 + srow) * ldb + k0) * 2 + scol);
    }
    __syncthreads();

    const int koff = (lane >> 4) * 8;
    bf16x8 a[4], b[4];
#pragma unroll
    for (int m = 0; m < 4; ++m)
      a[m] = *(const bf16x8*)&AsU[(wr * 64 + m * 16 + (lane & 15)) * 32 + koff];
#pragma unroll
    for (int n = 0; n < 4; ++n)
      b[n] = *(const bf16x8*)&BsU[(wc * 64 + n * 16 + (lane & 15)) * 32 + koff];
#pragma unroll
    for (int m = 0; m < 4; ++m)
#pragma unroll
      for (int n = 0; n < 4; ++n)
        acc[m][n] = __builtin_amdgcn_mfma_f32_16x16x32_bf16(a[m], b[n],
                                                            acc[m][n], 0, 0, 0);
    __syncthreads();
  }

#pragma unroll
  for (int m = 0; m < 4; ++m) {
    int row = m0 + wr * 64 + m * 16 + (lane >> 4) * 4;
#pragma unroll
    for (int n = 0; n < 4; ++n) {
      int col = n0 + wc * 64 + n * 16 + (lane & 15);
      float bs = bias ? bias[col] : 0.f;
#pragma unroll
      for (int r = 0; r < 4; ++r) {
        float v = (acc[m][n][r] + bs) * alpha;
        if (pbc) {
          v = E1[(long)(row + r) * ldc + col] +
              0.5f * (v + E2[(long)((row + r) >> 9) * 1024 + col]);
        } else {
          long eidx = (long)bz * sE + (long)(row + r) * ldc + col;
          if (E1) v += E1[eidx];
          if (E2) v += E2[eidx];
        }
        if (act) v = v * 0.5f * (1.f + erff(v * 0.70710678118f));
        long cidx = (long)bz * sC + (long)(row + r) * ldc + col;
        if (obf)
          ((__hip_bfloat16*)C)[cidx] = __float2bfloat16(v);
        else
          ((float*)C)[cidx] = v;
      }
    }
  }
}

// ---------------------------------------------------------------------------
// MFMA attention. Block = (i-tile of 32, h, b); 4 waves. Reads bias+mask raw.
// ---------------------------------------------------------------------------
__global__ __launch_bounds__(256) void attn_mfma(
    const __hip_bfloat16* __restrict__ Q, const __hip_bfloat16* __restrict__ K,
    const __hip_bfloat16* __restrict__ VT, const float* __restrict__ BiasP,
    const float* __restrict__ MaskP, __hip_bfloat16* __restrict__ O,
    int ldqk) {
  __shared__ __hip_bfloat16 P[32][520];
  __shared__ float red[2][32][4];
  const int it = blockIdx.x, h = blockIdx.y, b = blockIdx.z;
  const int i0 = it * 32;
  const int tid = threadIdx.x;
  const int lane = tid & 63, w = tid >> 6;
  const int lh = lane >> 4, ll = lane & 15;

  const long qkb = (long)b * 512 * ldqk + h * 64;

  bf16x8 a[2][2];
#pragma unroll
  for (int m = 0; m < 2; ++m)
#pragma unroll
    for (int ks = 0; ks < 2; ++ks)
      a[m][ks] = *(const bf16x8*)&Q[qkb + (long)(i0 + m * 16 + ll) * ldqk +
                                    ks * 32 + lh * 8];

  f32x4 acc[2][8];
#pragma unroll
  for (int m = 0; m < 2; ++m)
#pragma unroll
    for (int n = 0; n < 8; ++n) acc[m][n] = (f32x4){0.f, 0.f, 0.f, 0.f};

#pragma unroll
  for (int n = 0; n < 8; ++n) {
    const __hip_bfloat16* kp =
        &K[qkb + (long)(w * 128 + n * 16 + ll) * ldqk + lh * 8];
    bf16x8 b0 = *(const bf16x8*)&kp[0];
    bf16x8 b1 = *(const bf16x8*)&kp[32];
#pragma unroll
    for (int m = 0; m < 2; ++m) {
      acc[m][n] =
          __builtin_amdgcn_mfma_f32_16x16x32_bf16(a[m][0], b0, acc[m][n], 0, 0, 0);
      acc[m][n] =
          __builtin_amdgcn_mfma_f32_16x16x32_bf16(a[m][1], b1, acc[m][n], 0, 0, 0);
    }
  }

  const long bmo = ((long)b * 512 + i0) * 512 + w * 128;
#pragma unroll
  for (int m = 0; m < 2; ++m)
#pragma unroll
    for (int r = 0; r < 4; ++r) {
      int row = m * 16 + lh * 4 + r;
#pragma unroll
      for (int n = 0; n < 8; ++n) {
        long gi = bmo + (long)row * 512 + n * 16 + ll;
        acc[m][n][r] += BiasP[gi] + MaskP[gi];
      }
    }

  float rmax[2][4];
#pragma unroll
  for (int m = 0; m < 2; ++m)
#pragma unroll
    for (int r = 0; r < 4; ++r) {
      float v = acc[m][0][r];
#pragma unroll
      for (int n = 1; n < 8; ++n) v = fmaxf(v, acc[m][n][r]);
#pragma unroll
      for (int o = 1; o < 16; o <<= 1) v = fmaxf(v, __shfl_xor(v, o));
      rmax[m][r] = v;
    }
  if (ll == 0) {
#pragma unroll
    for (int m = 0; m < 2; ++m)
#pragma unroll
      for (int r = 0; r < 4; ++r) red[0][m * 16 + lh * 4 + r][w] = rmax[m][r];
  }
  __syncthreads();
#pragma unroll
  for (int m = 0; m < 2; ++m)
#pragma unroll
    for (int r = 0; r < 4; ++r) {
      const float* p = red[0][m * 16 + lh * 4 + r];
      rmax[m][r] = fmaxf(fmaxf(p[0], p[1]), fmaxf(p[2], p[3]));
    }
  float rsum[2][4];
#pragma unroll
  for (int m = 0; m < 2; ++m)
#pragma unroll
    for (int r = 0; r < 4; ++r) {
      float s = 0.f;
#pragma unroll
      for (int n = 0; n < 8; ++n) {
        float e = __expf(acc[m][n][r] - rmax[m][r]);
        acc[m][n][r] = e;
        s += e;
      }
#pragma unroll
      for (int o = 1; o < 16; o <<= 1) s += __shfl_xor(s, o);
      rsum[m][r] = s;
    }
  if (ll == 0) {
#pragma unroll
    for (int m = 0; m < 2; ++m)
#pragma unroll
      for (int r = 0; r < 4; ++r) red[1][m * 16 + lh * 4 + r][w] = rsum[m][r];
  }
  __syncthreads();
#pragma unroll
  for (int m = 0; m < 2; ++m)
#pragma unroll
    for (int r = 0; r < 4; ++r) {
      const float* p = red[1][m * 16 + lh * 4 + r];
      float inv = 1.f / (p[0] + p[1] + p[2] + p[3]);
      int row = m * 16 + lh * 4 + r;
#pragma unroll
      for (int n = 0; n < 8; ++n)
        P[row][w * 128 + n * 16 + ll] = __float2bfloat16(acc[m][n][r] * inv);
    }
  __syncthreads();

  const long vtb = ((long)b * 1024 + h * 64) * 512;
  const long ob = (long)b * 512 * 1024 + h * 64;
  const int mw = (w >> 1) * 16, nw = (w & 1) * 32;
  f32x4 oacc[2];
  oacc[0] = (f32x4){0.f, 0.f, 0.f, 0.f};
  oacc[1] = (f32x4){0.f, 0.f, 0.f, 0.f};
#pragma unroll
  for (int ks = 0; ks < 16; ++ks) {
    int k0 = ks * 32;
    bf16x8 pa = *(const bf16x8*)&P[mw + ll][k0 + lh * 8];
#pragma unroll
    for (int nf = 0; nf < 2; ++nf) {
      bf16x8 vb = *(const bf16x8*)&VT[vtb + (long)(nw + nf * 16 + ll) * 512 +
                                      k0 + lh * 8];
      oacc[nf] =
          __builtin_amdgcn_mfma_f32_16x16x32_bf16(pa, vb, oacc[nf], 0, 0, 0);
    }
  }
#pragma unroll
  for (int nf = 0; nf < 2; ++nf)
#pragma unroll
    for (int r = 0; r < 4; ++r)
      O[ob + (long)(i0 + mw + lh * 4 + r) * 1024 + nw + nf * 16 + ll] =
          __float2bfloat16(oacc[nf][r]);
}

// ---------------------------------------------------------------------------
// Row softmax (512) f32 in -> bf16 out. One block per row.
// ---------------------------------------------------------------------------
__global__ __launch_bounds__(256) void softmax_rows(
    const float* __restrict__ P, __hip_bfloat16* __restrict__ Ob) {
  const float* row = P + (long)blockIdx.x * 512;
  __hip_bfloat16* orow = Ob + (long)blockIdx.x * 512;
  int t = threadIdx.x;
  float v0 = row[t], v1 = row[t + 256];
  float m = fmaxf(v0, v1);
#pragma unroll
  for (int o = 32; o; o >>= 1) m = fmaxf(m, __shfl_xor(m, o));
  __shared__ float red[8];
  int wid = t >> 6, lane = t & 63;
  if (!lane) red[wid] = m;
  __syncthreads();
  m = fmaxf(fmaxf(red[0], red[1]), fmaxf(red[2], red[3]));
  float e0 = __expf(v0 - m), e1 = __expf(v1 - m);
  float s = e0 + e1;
#pragma unroll
  for (int o = 32; o; o >>= 1) s += __shfl_xor(s, o);
  if (!lane) red[4 + wid] = s;
  __syncthreads();
  s = red[4] + red[5] + red[6] + red[7];
  float inv = 1.f / s;
  orow[t] = __float2bfloat16(e0 * inv);
  orow[t + 256] = __float2bfloat16(e1 * inv);
}

// ---------------------------------------------------------------------------
// path gather-mean partials + finalize.
// ---------------------------------------------------------------------------
__global__ __launch_bounds__(256) void path_partial(
    const float* __restrict__ xp, const int* __restrict__ pp,
    float* __restrict__ PP, float* __restrict__ WS) {
  int b = blockIdx.x, hc = blockIdx.y, ic = blockIdx.z;
  int h = hc * 256 + threadIdx.x;
  const int* ppb = pp + b * 512;
  const float* xb = xp + (long)b * 512 * 1024;
  int iA = ic * 64, iB = iA + 64;
  float acc = 0.f;
  for (int i = iA; i < iB; ++i) {
    if (ppb[i] != 1) continue;
    float cur = xb[(long)i * 1024 + h];
    float a;
    if (i == 0) {
      a = 0.5f * (cur + xb[1024 + h]);
    } else if (i == 1) {
      a = (xb[h] + cur + xb[2 * 1024 + h]) * (1.f / 3.f);
    } else {
      int inx = (i + 1 < 512) ? i + 1 : 511;
      float nx = xb[(long)inx * 1024 + h];
      if (ppb[i - 2] == 1) {
        a = 0.5f * (cur + nx);
      } else {
        a = (xb[(long)(i - 1) * 1024 + h] + cur + nx) * (1.f / 3.f);
      }
    }
    acc += a;
  }
  PP[((long)b * 8 + ic) * 1024 + h] = acc;
  if (hc == 0 && threadIdx.x == 0) {
    float c = 0.f;
    for (int i = iA; i < iB; ++i) c += (ppb[i] == 1) ? 1.f : 0.f;
    WS[b * 8 + ic] = c;
  }
}

__global__ __launch_bounds__(256) void path_finalize(
    const float* __restrict__ PP, const float* __restrict__ WS,
    float* __restrict__ PATH) {
  int b = blockIdx.x;
  int h = blockIdx.y * 256 + threadIdx.x;
  float s = 0.f, w = 0.f;
#pragma unroll
  for (int ic = 0; ic < 8; ++ic) {
    s += PP[((long)b * 8 + ic) * 1024 + h];
    w += WS[b * 8 + ic];
  }
  PATH[b * 1024 + h] = s / w;
}

// ---------------------------------------------------------------------------
extern "C" void kernel_launch(void* const* d_in, const int* in_sizes, int n_in,
                              void* d_out, int out_size, void* d_ws,
                              size_t ws_size, hipStream_t stream) {
  const float* x = (const float*)d_in[0];
  const int* pp = (const int*)d_in[1];
  const float* abias = (const float*)d_in[3];
  const float* amask = (const float*)d_in[4];
  const float* agraph = (const float*)d_in[5];
  const float* vgraph = (const float*)d_in[6];
  const float* ln1g = (const float*)d_in[7];
  const float* ln1b = (const float*)d_in[8];
  const float* wq = (const float*)d_in[9];
  const float* bq = (const float*)d_in[10];
  const float* wk = (const float*)d_in[11];
  const float* bk = (const float*)d_in[12];
  const float* wv = (const float*)d_in[13];
  const float* bv = (const float*)d_in[14];
  const float* wo = (const float*)d_in[15];
  const float* bo = (const float*)d_in[16];
  const float* pqw = (const float*)d_in[17];
  const float* pqb = (const float*)d_in[18];
  const float* pkw = (const float*)d_in[19];
  const float* pkb = (const float*)d_in[20];
  const float* pvw = (const float*)d_in[21];
  const float* pvb = (const float*)d_in[22];
  const float* ln2g = (const float*)d_in[23];
  const float* ln2b = (const float*)d_in[24];
  const float* w1 = (const float*)d_in[25];
  const float* b1 = (const float*)d_in[26];
  const float* w2 = (const float*)d_in[27];
  const float* b2 = (const float*)d_in[28];

  char* wsb = (char*)d_ws;
  auto Ybf = (__hip_bfloat16*)(wsb);                  // 0-8 (later Y2b)
  auto QKV = (__hip_bfloat16*)(wsb + (8l << 20));     // 8-56: [4096][6144]
  auto VTb = (__hip_bfloat16*)(wsb + (56l << 20));    // 56-64
  auto PVT = (__hip_bfloat16*)(wsb + (64l << 20));    // 64-72
  auto ATTb = (__hip_bfloat16*)(wsb + (72l << 20));   // 72-80 (later W2T)
  auto PATTb = (__hip_bfloat16*)(wsb + (88l << 20));  // 88-92
  auto PATTf = (float*)(wsb + (92l << 20));           // 92-100
  auto XP = (float*)(wsb + (92l << 20));              // 92-108
  auto WALL = (__hip_bfloat16*)(wsb + (108l << 20));  // 108-120: [6144][1024]
  auto WOT = (__hip_bfloat16*)(wsb + (120l << 20));   // 120-122
  auto W1T = (__hip_bfloat16*)(wsb + (122l << 20));   // 122-130
  auto bias6 = (float*)(wsb + (130l << 20));          // 24KB
  auto PPart = (float*)(wsb + (131l << 20));          // 256KB
  auto WSp = (float*)(wsb + (132l << 20));            // 256B
  auto PATH = (float*)(wsb + (133l << 20));           // 32KB
  auto X2 = (float*)(wsb + (24l << 20));              // 24-40 (QKV dead)
  auto HMID = (__hip_bfloat16*)(wsb + (40l << 20));   // 40-72
  auto W2T = ATTb;
  auto PART = (float*)(wsb + (92l << 20));            // 92-156 (4x16MB f32)
  __hip_bfloat16* Y2b = Ybf;
  float* OUT = (float*)d_out;

  const float qscale = 0.125f;
  const float pscale = 0.03125f;
  const long S2 = 512l * 512;
  const long SQ = 512l * 6144;

  __hip_bfloat16* Qp = QKV;
  __hip_bfloat16* Kp = QKV + 1024;
  __hip_bfloat16* Vp = QKV + 2048;
  __hip_bfloat16* PQp = QKV + 3072;
  __hip_bfloat16* PKp = QKV + 4096;
  __hip_bfloat16* PVp = QKV + 5120;

  // 0) weight transposes + bias concat
  TC7 tp;
  tp.in[0] = wq;  tp.out[0] = WALL;                 tp.scale[0] = qscale;
  tp.in[1] = wk;  tp.out[1] = WALL + 1024 * 1024;   tp.scale[1] = 1.f;
  tp.in[2] = wv;  tp.out[2] = WALL + 2048 * 1024;   tp.scale[2] = 1.f;
  tp.in[3] = pqw; tp.out[3] = WALL + 3072 * 1024;   tp.scale[3] = pscale;
  tp.in[4] = pkw; tp.out[4] = WALL + 4096 * 1024;   tp.scale[4] = 1.f;
  tp.in[5] = pvw; tp.out[5] = WALL + 5120 * 1024;   tp.scale[5] = 1.f;
  tp.in[6] = wo;  tp.out[6] = WOT;                  tp.scale[6] = 1.f;
  tconv7<<<dim3(32, 32, 7), 256, 0, stream>>>(tp);
  tconv_f32_bf16<<<dim3(128, 32), 256, 0, stream>>>(w1, W1T, 1024, 4096);

  BC6 bp;
  bp.b[0] = bq;  bp.scale[0] = qscale;
  bp.b[1] = bk;  bp.scale[1] = 1.f;
  bp.b[2] = bv;  bp.scale[2] = 1.f;
  bp.b[3] = pqb; bp.scale[3] = pscale;
  bp.b[4] = pkb; bp.scale[4] = 1.f;
  bp.b[5] = pvb; bp.scale[5] = 1.f;
  bias_concat<<<24, 256, 0, stream>>>(bp, bias6);

  // 1) LN1 -> Ybf
  ln_rows_bf16<<<4096, 256, 0, stream>>>(x, ln1g, ln1b, Ybf);

  // 2) fused projections via gemm256<256>: M=4096 (y=16), N=6144 (x=24)
  gemm256<256><<<dim3(24, 16, 1), 512, 0, stream>>>(
      Ybf, WALL, bias6, QKV, 1024, 1024, 1024, 6144, 0, 1, 0);

  // 3) transposes: V -> VT, PV -> PVT
  tconv_bf16<<<dim3(32, 16, 8), 256, 0, stream>>>(Vp, VTb, 512, 1024, 6144, SQ);
  tconv_bf16<<<dim3(32, 16, 8), 256, 0, stream>>>(PVp, PVT, 512, 1024, 6144, SQ);

  // 4) path scores + softmax
  gemm_bf16_nt<<<dim3(4, 4, 8), 256, 0, stream>>>(
      PQp, PKp, nullptr, agraph, vgraph, PATTf, 1024, 6144, 6144, 512, SQ, SQ,
      S2, S2, 1.f, 0, 0, 0);
  softmax_rows<<<4096, 256, 0, stream>>>(PATTf, PATTb);

  // 5) MFMA attention -> ATTb (reads bias + mask directly)
  attn_mfma<<<dim3(16, 16, 8), 256, 0, stream>>>(Qp, Kp, VTb, abias, amask,
                                                 ATTb, 6144);

  // 6) XP = PATT @ PVT^T
  gemm_bf16_nt<<<dim3(8, 4, 8), 256, 0, stream>>>(
      PATTb, PVT, nullptr, nullptr, nullptr, XP, 512, 512, 512, 1024, S2,
      512l * 1024, 512l * 1024, 0, 1.f, 0, 0, 0);

  // 7) path gather-mean
  path_partial<<<dim3(8, 4, 8), 256, 0, stream>>>(XP, pp, PPart, WSp);
  path_finalize<<<dim3(8, 4), 256, 0, stream>>>(PPart, WSp, PATH);

  // 8) fused: X2 = x + 0.5*((ATT@wo + bo) + PATH)  (pbc epilogue, f32 out)
  gemm_bf16_nt<<<dim3(8, 32, 1), 256, 0, stream>>>(
      ATTb, WOT, bo, x, PATH, X2, 1024, 1024, 1024, 1024, 0, 0, 0, 0, 1.f, 0,
      0, 1);

  // 8b) W2 transpose into ATTb's slot (ATTb now dead)
  tconv_f32_bf16<<<dim3(32, 128), 256, 0, stream>>>(w2, W2T, 4096, 1024);

  // 10) LN2 -> Y2b
  ln_rows_bf16<<<4096, 256, 0, stream>>>(X2, ln2g, ln2b, Y2b);

  // 11) FFN1 via gemm256<256>: M=4096, N=4096, GELU, bf16 out
  gemm256<256><<<dim3(16, 16, 1), 512, 0, stream>>>(
      Y2b, W1T, b1, HMID, 1024, 1024, 1024, 4096, 1, 1, 0);

  // 12) FFN2 split-K=4 via gemm256<256>: grid (4,16,4) = 256 blocks
  gemm256<256><<<dim3(4, 16, 4), 512, 0, stream>>>(
      HMID, W2T, nullptr, PART, 1024, 4096, 4096, 1024, 0, 0, 4194304);

  // 12b) OUT = sum_z PART[z] + b2 + X2
  ffn2_reduce<<<4096, 256, 0, stream>>>(PART, X2, b2, OUT);
}

// Round 10
// 474.509 us; speedup vs baseline: 10.6851x; 1.0000x over previous
//
#include <hip/hip_runtime.h>
#include <hip/hip_bf16.h>
#include <math.h>

// B=8, S=512, H=1024, NH=16, DK=64, FF=4096.
// Round 10: gemm256 K-loop -> 4-phase schedule (T3): each phase
// {ds_read subtile + stage-issue -> s_barrier -> 16 MFMA -> s_barrier}.
// Creates wave role-split so LDS reads overlap MFMA (was serialized bursts,
// MfmaUtil capped ~21-25%). T2 swizzle + counted-stage retained.

typedef __bf16 bf16x8 __attribute__((ext_vector_type(8)));
typedef float f32x4 __attribute__((ext_vector_type(4)));

__device__ __forceinline__ void async_copy16(void* lds, const void* g) {
  __builtin_amdgcn_global_load_lds(
      (__attribute__((address_space(1))) void*)(void*)g,
      (__attribute__((address_space(3))) void*)lds, 16, 0, 0);
}

#define SB0 __builtin_amdgcn_sched_barrier(0)
#define BARRIER __builtin_amdgcn_s_barrier()

// ---------------------------------------------------------------------------
// LayerNorm over last dim (1024) -> bf16. One block (256 thr) per row.
// ---------------------------------------------------------------------------
__global__ __launch_bounds__(256) void ln_rows_bf16(
    const float* __restrict__ X, const float* __restrict__ G,
    const float* __restrict__ Bt, __hip_bfloat16* __restrict__ O) {
  long row = blockIdx.x;
  int t = threadIdx.x;
  const float4 xv = ((const float4*)(X + row * 1024))[t];
  float s = xv.x + xv.y + xv.z + xv.w;
  float q = xv.x * xv.x + xv.y * xv.y + xv.z * xv.z + xv.w * xv.w;
#pragma unroll
  for (int o = 32; o; o >>= 1) {
    s += __shfl_xor(s, o);
    q += __shfl_xor(q, o);
  }
  __shared__ float rs[4], rq[4];
  int wid = t >> 6;
  if ((t & 63) == 0) { rs[wid] = s; rq[wid] = q; }
  __syncthreads();
  s = rs[0] + rs[1] + rs[2] + rs[3];
  q = rq[0] + rq[1] + rq[2] + rq[3];
  float mean = s * (1.f / 1024.f);
  float var = q * (1.f / 1024.f) - mean * mean;
  float rstd = rsqrtf(var + 1e-5f);
  const float4 gv = ((const float4*)G)[t];
  const float4 bv = ((const float4*)Bt)[t];
  __hip_bfloat16* o = O + row * 1024 + t * 4;
  o[0] = __float2bfloat16((xv.x - mean) * rstd * gv.x + bv.x);
  o[1] = __float2bfloat16((xv.y - mean) * rstd * gv.y + bv.y);
  o[2] = __float2bfloat16((xv.z - mean) * rstd * gv.z + bv.z);
  o[3] = __float2bfloat16((xv.w - mean) * rstd * gv.w + bv.w);
}

// ---------------------------------------------------------------------------
// Batched weight transpose-convert: 7x f32 [1024,1024] -> bf16 ^T w/ scale.
// ---------------------------------------------------------------------------
struct TC7 {
  const float* in[7];
  __hip_bfloat16* out[7];
  float scale[7];
};
__global__ __launch_bounds__(256) void tconv7(TC7 p) {
  __shared__ float t[32][33];
  int j = blockIdx.z;
  const float* in = p.in[j];
  __hip_bfloat16* out = p.out[j];
  float sc = p.scale[j];
  int c0 = blockIdx.x * 32, r0 = blockIdx.y * 32;
  int tid = threadIdx.x;
  int lr = tid >> 3, lc = (tid & 7) * 4;
  const float4 v = *(const float4*)&in[(long)(r0 + lr) * 1024 + c0 + lc];
  t[lr][lc] = v.x; t[lr][lc + 1] = v.y; t[lr][lc + 2] = v.z; t[lr][lc + 3] = v.w;
  __syncthreads();
  int oc = tid >> 3, orr = (tid & 7) * 4;
  __hip_bfloat16* o = &out[(long)(c0 + oc) * 1024 + r0 + orr];
  o[0] = __float2bfloat16(t[orr][oc] * sc);
  o[1] = __float2bfloat16(t[orr + 1][oc] * sc);
  o[2] = __float2bfloat16(t[orr + 2][oc] * sc);
  o[3] = __float2bfloat16(t[orr + 3][oc] * sc);
}

// Generic transpose-convert f32 [R,C] -> bf16 [C,R]. grid (C/32, R/32).
__global__ __launch_bounds__(256) void tconv_f32_bf16(
    const float* __restrict__ in, __hip_bfloat16* __restrict__ out, int R,
    int C) {
  __shared__ float t[32][33];
  int c0 = blockIdx.x * 32, r0 = blockIdx.y * 32;
  int tid = threadIdx.x;
  int lr = tid >> 3, lc = (tid & 7) * 4;
  const float4 v = *(const float4*)&in[(long)(r0 + lr) * C + c0 + lc];
  t[lr][lc] = v.x; t[lr][lc + 1] = v.y; t[lr][lc + 2] = v.z; t[lr][lc + 3] = v.w;
  __syncthreads();
  int oc = tid >> 3, orr = (tid & 7) * 4;
  __hip_bfloat16* o = &out[(long)(c0 + oc) * R + r0 + orr];
  o[0] = __float2bfloat16(t[orr][oc]);
  o[1] = __float2bfloat16(t[orr + 1][oc]);
  o[2] = __float2bfloat16(t[orr + 2][oc]);
  o[3] = __float2bfloat16(t[orr + 3][oc]);
}

// Batched bf16 transpose, strided input -> packed [bz][C][R].
__global__ __launch_bounds__(256) void tconv_bf16(
    const __hip_bfloat16* __restrict__ in, __hip_bfloat16* __restrict__ out,
    int R, int C, int ldin, long sIn) {
  __shared__ __hip_bfloat16 t[32][34];
  int bz = blockIdx.z;
  long ibase = (long)bz * sIn;
  long obase = (long)bz * R * C;
  int c0 = blockIdx.x * 32, r0 = blockIdx.y * 32;
  int tid = threadIdx.x;
  int lr = tid >> 3, lc = (tid & 7) * 4;
  const __hip_bfloat16* ip = &in[ibase + (long)(r0 + lr) * ldin + c0 + lc];
  t[lr][lc] = ip[0]; t[lr][lc + 1] = ip[1]; t[lr][lc + 2] = ip[2]; t[lr][lc + 3] = ip[3];
  __syncthreads();
  int oc = tid >> 3, orr = (tid & 7) * 4;
  __hip_bfloat16* o = &out[obase + (long)(c0 + oc) * R + r0 + orr];
  o[0] = t[orr][oc];
  o[1] = t[orr + 1][oc];
  o[2] = t[orr + 2][oc];
  o[3] = t[orr + 3][oc];
}

// concat 6 bias vectors (x1024) with per-segment scale -> bias6[6144]
struct BC6 {
  const float* b[6];
  float scale[6];
};
__global__ __launch_bounds__(256) void bias_concat(BC6 p, float* __restrict__ o) {
  int idx = blockIdx.x * 256 + threadIdx.x;
  int j = idx >> 10, e = idx & 1023;
  o[idx] = p.b[j][e] * p.scale[j];
}

// ---------------------------------------------------------------------------
// gemm256<BN>: BM=256, BK=64, 512 thr = 8 waves (2M x 4N).
// 4-phase K-loop: ph = {ds_read subtile (+stage issue) -> barrier -> 16 MFMA
// -> barrier}. B-frags shared across the two m-half phases of a ks. stage
// copies issued ph0/ph1; vmcnt(0) at ph3 (copies ~2 phases old). LDS XOR
// chunk-swizzle; 2D XCD chunking (4x2). Split-K via blockIdx.z.
// ---------------------------------------------------------------------------
template <int BN>
__global__ __launch_bounds__(512, 2) void gemm256(
    const __hip_bfloat16* __restrict__ A, const __hip_bfloat16* __restrict__ Bt,
    const float* __restrict__ bias, void* __restrict__ C, int K, int lda,
    int ldb, int ldc, int act, int obf, long sC) {
  constexpr int NR = BN / 64;
  constexpr int ABYTES = 256 * 128;
  constexpr int BBYTES = BN * 128;
  constexpr int BUF = ABYTES + BBYTES;
  __shared__ char lds[2 * BUF];

  int bx, by;
  {
    int wg = blockIdx.y * gridDim.x + blockIdx.x;
    int gx = gridDim.x, gy = gridDim.y;
    if ((gx & 3) == 0 && (gy & 1) == 0) {
      int cw = gx >> 2, ch = gy >> 1;
      int xcd = wg & 7, idx = wg >> 3;
      bx = (xcd & 3) * cw + idx % cw;
      by = (xcd >> 2) * ch + idx / cw;
    } else {
      bx = blockIdx.x;
      by = blockIdx.y;
    }
  }
  const int m0 = by * 256, n0 = bx * BN;
  const int z = blockIdx.z;
  const long kbase = (long)z * K * 2;

  const int tid = threadIdx.x;
  const int lane = tid & 63, wid = tid >> 6;
  const int wm = wid >> 2, wn = wid & 3;
  const int ll = lane & 15, lh = lane >> 4;

  const char* Ag = (const char*)A;
  const char* Bg = (const char*)Bt;
  const int srow = tid >> 3;
  const int scb = (((tid & 7) ^ (srow & 7)) << 4);  // swizzled src chunk
  const int sld = (tid & 7) << 4;                   // linear LDS chunk

  auto stageA = [&](char* base, long kb) {
#pragma unroll
    for (int l = 0; l < 4; ++l) {
      int row = l * 64 + srow;
      async_copy16(base + row * 128 + sld,
                   Ag + ((long)(m0 + row) * lda) * 2 + kb + scb);
    }
  };
  auto stageB = [&](char* base, long kb) {
#pragma unroll
    for (int l = 0; l < BN / 64; ++l) {
      int row = l * 64 + srow;
      async_copy16(base + ABYTES + row * 128 + sld,
                   Bg + ((long)(n0 + row) * ldb) * 2 + kb + scb);
    }
  };

  const int rx = ll & 7;
  const int ck[2] = {((0 + lh) ^ rx) << 4, ((4 + lh) ^ rx) << 4};

  f32x4 acc[8][NR];
#pragma unroll
  for (int m = 0; m < 8; ++m)
#pragma unroll
    for (int n = 0; n < NR; ++n) acc[m][n] = (f32x4){0.f, 0.f, 0.f, 0.f};

  const int nt = K >> 6;
  // prologue: stage tile 0, drain, barrier
  stageA(lds, kbase);
  stageB(lds, kbase);
  asm volatile("s_waitcnt vmcnt(0)" ::: "memory");
  BARRIER;

  for (int t = 0; t < nt; ++t) {
    const int bt = t & 1;
    const char* Ab = lds + bt * BUF;
    const char* Bb = Ab + ABYTES;
    char* nb = lds + (bt ^ 1) * BUF;
    const bool pre = (t + 1 < nt);
    const long kb = kbase + (long)(t + 1) * 128;

    bf16x8 af[4], bf[NR];

    // ---- ph0: A[0..3]ks0 + B ks0 reads; stage A(t+1); MFMA m0-3 ks0
#pragma unroll
    for (int m = 0; m < 4; ++m)
      af[m] = *(const bf16x8*)(Ab + (wm * 128 + m * 16 + ll) * 128 + ck[0]);
#pragma unroll
    for (int n = 0; n < NR; ++n)
      bf[n] = *(const bf16x8*)(Bb + (wn * (BN / 4) + n * 16 + ll) * 128 + ck[0]);
    if (pre) stageA(nb, kb);
    SB0; BARRIER; SB0;
    __builtin_amdgcn_s_setprio(1);
#pragma unroll
    for (int m = 0; m < 4; ++m)
#pragma unroll
      for (int n = 0; n < NR; ++n)
        acc[m][n] = __builtin_amdgcn_mfma_f32_16x16x32_bf16(af[m], bf[n],
                                                            acc[m][n], 0, 0, 0);
    __builtin_amdgcn_s_setprio(0);
    SB0; BARRIER; SB0;

    // ---- ph1: A[4..7]ks0 reads; stage B(t+1); MFMA m4-7 ks0 (bf reused)
#pragma unroll
    for (int m = 0; m < 4; ++m)
      af[m] = *(const bf16x8*)(Ab + (wm * 128 + (m + 4) * 16 + ll) * 128 + ck[0]);
    if (pre) stageB(nb, kb);
    SB0; BARRIER; SB0;
    __builtin_amdgcn_s_setprio(1);
#pragma unroll
    for (int m = 0; m < 4; ++m)
#pragma unroll
      for (int n = 0; n < NR; ++n)
        acc[m + 4][n] = __builtin_amdgcn_mfma_f32_16x16x32_bf16(
            af[m], bf[n], acc[m + 4][n], 0, 0, 0);
    __builtin_amdgcn_s_setprio(0);
    SB0; BARRIER; SB0;

    // ---- ph2: A[0..3]ks1 + B ks1 reads; MFMA m0-3 ks1
#pragma unroll
    for (int m = 0; m < 4; ++m)
      af[m] = *(const bf16x8*)(Ab + (wm * 128 + m * 16 + ll) * 128 + ck[1]);
#pragma unroll
    for (int n = 0; n < NR; ++n)
      bf[n] = *(const bf16x8*)(Bb + (wn * (BN / 4) + n * 16 + ll) * 128 + ck[1]);
    SB0; BARRIER; SB0;
    __builtin_amdgcn_s_setprio(1);
#pragma unroll
    for (int m = 0; m < 4; ++m)
#pragma unroll
      for (int n = 0; n < NR; ++n)
        acc[m][n] = __builtin_amdgcn_mfma_f32_16x16x32_bf16(af[m], bf[n],
                                                            acc[m][n], 0, 0, 0);
    __builtin_amdgcn_s_setprio(0);
    SB0; BARRIER; SB0;

    // ---- ph3: A[4..7]ks1 reads; vmcnt(0) retires stage(t+1); MFMA m4-7 ks1
#pragma unroll
    for (int m = 0; m < 4; ++m)
      af[m] = *(const bf16x8*)(Ab + (wm * 128 + (m + 4) * 16 + ll) * 128 + ck[1]);
    asm volatile("s_waitcnt vmcnt(0)" ::: "memory");
    SB0; BARRIER; SB0;
    __builtin_amdgcn_s_setprio(1);
#pragma unroll
    for (int m = 0; m < 4; ++m)
#pragma unroll
      for (int n = 0; n < NR; ++n)
        acc[m + 4][n] = __builtin_amdgcn_mfma_f32_16x16x32_bf16(
            af[m], bf[n], acc[m + 4][n], 0, 0, 0);
    __builtin_amdgcn_s_setprio(0);
    SB0; BARRIER; SB0;
  }

#pragma unroll
  for (int m = 0; m < 8; ++m) {
    int row = m0 + wm * 128 + m * 16 + lh * 4;
#pragma unroll
    for (int n = 0; n < NR; ++n) {
      int col = n0 + wn * (BN / 4) + n * 16 + ll;
      float bs = bias ? bias[col] : 0.f;
#pragma unroll
      for (int r = 0; r < 4; ++r) {
        float v = acc[m][n][r] + bs;
        if (act) v = v * 0.5f * (1.f + erff(v * 0.70710678118f));
        long cidx = (long)z * sC + (long)(row + r) * ldc + col;
        if (obf)
          ((__hip_bfloat16*)C)[cidx] = __float2bfloat16(v);
        else
          ((float*)C)[cidx] = v;
      }
    }
  }
}

// FFN2 finalize: OUT = sum_z PART[z] + b2 + X2. float4/thread, grid 4096.
__global__ __launch_bounds__(256) void ffn2_reduce(
    const float* __restrict__ P, const float* __restrict__ X2,
    const float* __restrict__ b2, float* __restrict__ OUT) {
  int i = blockIdx.x * 256 + threadIdx.x;
  const long SP = 4194304;
  float4 a = ((const float4*)P)[i];
  float4 b = ((const float4*)(P + SP))[i];
  float4 c = ((const float4*)(P + 2 * SP))[i];
  float4 d = ((const float4*)(P + 3 * SP))[i];
  float4 xr = ((const float4*)X2)[i];
  const float4 bb = *(const float4*)(b2 + ((i & 255) * 4));
  float4 o;
  o.x = a.x + b.x + c.x + d.x + xr.x + bb.x;
  o.y = a.y + b.y + c.y + d.y + xr.y + bb.y;
  o.z = a.z + b.z + c.z + d.z + xr.z + bb.z;
  o.w = a.w + b.w + c.w + d.w + xr.w + bb.w;
  ((float4*)OUT)[i] = o;
}

// ---------------------------------------------------------------------------
// bf16 MFMA GEMM (NT), 128x128 tile, BK=32, 4 waves. XCD swizzle.
// pbc=1: C = E1 + 0.5*((A@Bt^T + bias) + E2[row>>9, col])  (combine fusion).
// ---------------------------------------------------------------------------
__global__ __launch_bounds__(256) void gemm_bf16_nt(
    const __hip_bfloat16* __restrict__ A, const __hip_bfloat16* __restrict__ Bt,
    const float* __restrict__ bias, const float* __restrict__ E1,
    const float* __restrict__ E2, void* __restrict__ C, int K, int lda,
    int ldb, int ldc, long sA, long sB, long sC, long sE, float alpha, int act,
    int obf, int pbc) {
  __shared__ unsigned short AsU[128 * 32];
  __shared__ unsigned short BsU[128 * 32];
  const int tid = threadIdx.x;
  const int lane = tid & 63, wave = tid >> 6;
  const int wr = wave >> 1, wc = wave & 1;

  int nwg = gridDim.x * gridDim.y;
  int wg = blockIdx.y * gridDim.x + blockIdx.x;
  int bx = blockIdx.x, by = blockIdx.y;
  if ((nwg & 7) == 0) {
    int cpx = nwg >> 3;
    int sw = (wg & 7) * cpx + (wg >> 3);
    bx = sw % gridDim.x;
    by = sw / gridDim.x;
  }
  const int m0 = by * 128, n0 = bx * 128;
  const int bz = blockIdx.z;
  const char* Ab = (const char*)(A + (long)bz * sA);
  const char* Bb = (const char*)(Bt + (long)bz * sB);

  f32x4 acc[4][4];
#pragma unroll
  for (int m = 0; m < 4; ++m)
#pragma unroll
    for (int n = 0; n < 4; ++n) acc[m][n] = (f32x4){0.f, 0.f, 0.f, 0.f};

  const int srow = tid >> 2;
  const int scol = (tid & 3) * 16;
  const int wbase = (tid >> 6) * 1024;

  for (int k0 = 0; k0 < K; k0 += 32) {
#pragma unroll
    for (int i = 0; i < 2; ++i) {
      async_copy16((char*)AsU + i * 4096 + wbase,
                   Ab + ((long)(m0 + i * 64 + srow) * lda + k0) * 2 + scol);
      async_copy16((char*)BsU + i * 4096 + wbase,
                   Bb + ((long)(n0 + i * 64 + srow) * ldb + k0) * 2 + scol);
    }
    __syncthreads();

    const int koff = (lane >> 4) * 8;
    bf16x8 a[4], b[4];
#pragma unroll
    for (int m = 0; m < 4; ++m)
      a[m] = *(const bf16x8*)&AsU[(wr * 64 + m * 16 + (lane & 15)) * 32 + koff];
#pragma unroll
    for (int n = 0; n < 4; ++n)
      b[n] = *(const bf16x8*)&BsU[(wc * 64 + n * 16 + (lane & 15)) * 32 + koff];
#pragma unroll
    for (int m = 0; m < 4; ++m)
#pragma unroll
      for (int n = 0; n < 4; ++n)
        acc[m][n] = __builtin_amdgcn_mfma_f32_16x16x32_bf16(a[m], b[n],
                                                            acc[m][n], 0, 0, 0);
    __syncthreads();
  }

#pragma unroll
  for (int m = 0; m < 4; ++m) {
    int row = m0 + wr * 64 + m * 16 + (lane >> 4) * 4;
#pragma unroll
    for (int n = 0; n < 4; ++n) {
      int col = n0 + wc * 64 + n * 16 + (lane & 15);
      float bs = bias ? bias[col] : 0.f;
#pragma unroll
      for (int r = 0; r < 4; ++r) {
        float v = (acc[m][n][r] + bs) * alpha;
        if (pbc) {
          v = E1[(long)(row + r) * ldc + col] +
              0.5f * (v + E2[(long)((row + r) >> 9) * 1024 + col]);
        } else {
          long eidx = (long)bz * sE + (long)(row + r) * ldc + col;
          if (E1) v += E1[eidx];
          if (E2) v += E2[eidx];
        }
        if (act) v = v * 0.5f * (1.f + erff(v * 0.70710678118f));
        long cidx = (long)bz * sC + (long)(row + r) * ldc + col;
        if (obf)
          ((__hip_bfloat16*)C)[cidx] = __float2bfloat16(v);
        else
          ((float*)C)[cidx] = v;
      }
    }
  }
}

// ---------------------------------------------------------------------------
// MFMA attention. Block = (i-tile of 32, h, b); 4 waves. Reads bias+mask raw.
// ---------------------------------------------------------------------------
__global__ __launch_bounds__(256) void attn_mfma(
    const __hip_bfloat16* __restrict__ Q, const __hip_bfloat16* __restrict__ K,
    const __hip_bfloat16* __restrict__ VT, const float* __restrict__ BiasP,
    const float* __restrict__ MaskP, __hip_bfloat16* __restrict__ O,
    int ldqk) {
  __shared__ __hip_bfloat16 P[32][520];
  __shared__ float red[2][32][4];
  const int it = blockIdx.x, h = blockIdx.y, b = blockIdx.z;
  const int i0 = it * 32;
  const int tid = threadIdx.x;
  const int lane = tid & 63, w = tid >> 6;
  const int lh = lane >> 4, ll = lane & 15;

  const long qkb = (long)b * 512 * ldqk + h * 64;

  bf16x8 a[2][2];
#pragma unroll
  for (int m = 0; m < 2; ++m)
#pragma unroll
    for (int ks = 0; ks < 2; ++ks)
      a[m][ks] = *(const bf16x8*)&Q[qkb + (long)(i0 + m * 16 + ll) * ldqk +
                                    ks * 32 + lh * 8];

  f32x4 acc[2][8];
#pragma unroll
  for (int m = 0; m < 2; ++m)
#pragma unroll
    for (int n = 0; n < 8; ++n) acc[m][n] = (f32x4){0.f, 0.f, 0.f, 0.f};

#pragma unroll
  for (int n = 0; n < 8; ++n) {
    const __hip_bfloat16* kp =
        &K[qkb + (long)(w * 128 + n * 16 + ll) * ldqk + lh * 8];
    bf16x8 b0 = *(const bf16x8*)&kp[0];
    bf16x8 b1 = *(const bf16x8*)&kp[32];
#pragma unroll
    for (int m = 0; m < 2; ++m) {
      acc[m][n] =
          __builtin_amdgcn_mfma_f32_16x16x32_bf16(a[m][0], b0, acc[m][n], 0, 0, 0);
      acc[m][n] =
          __builtin_amdgcn_mfma_f32_16x16x32_bf16(a[m][1], b1, acc[m][n], 0, 0, 0);
    }
  }

  const long bmo = ((long)b * 512 + i0) * 512 + w * 128;
#pragma unroll
  for (int m = 0; m < 2; ++m)
#pragma unroll
    for (int r = 0; r < 4; ++r) {
      int row = m * 16 + lh * 4 + r;
#pragma unroll
      for (int n = 0; n < 8; ++n) {
        long gi = bmo + (long)row * 512 + n * 16 + ll;
        acc[m][n][r] += BiasP[gi] + MaskP[gi];
      }
    }

  float rmax[2][4];
#pragma unroll
  for (int m = 0; m < 2; ++m)
#pragma unroll
    for (int r = 0; r < 4; ++r) {
      float v = acc[m][0][r];
#pragma unroll
      for (int n = 1; n < 8; ++n) v = fmaxf(v, acc[m][n][r]);
#pragma unroll
      for (int o = 1; o < 16; o <<= 1) v = fmaxf(v, __shfl_xor(v, o));
      rmax[m][r] = v;
    }
  if (ll == 0) {
#pragma unroll
    for (int m = 0; m < 2; ++m)
#pragma unroll
      for (int r = 0; r < 4; ++r) red[0][m * 16 + lh * 4 + r][w] = rmax[m][r];
  }
  __syncthreads();
#pragma unroll
  for (int m = 0; m < 2; ++m)
#pragma unroll
    for (int r = 0; r < 4; ++r) {
      const float* p = red[0][m * 16 + lh * 4 + r];
      rmax[m][r] = fmaxf(fmaxf(p[0], p[1]), fmaxf(p[2], p[3]));
    }
  float rsum[2][4];
#pragma unroll
  for (int m = 0; m < 2; ++m)
#pragma unroll
    for (int r = 0; r < 4; ++r) {
      float s = 0.f;
#pragma unroll
      for (int n = 0; n < 8; ++n) {
        float e = __expf(acc[m][n][r] - rmax[m][r]);
        acc[m][n][r] = e;
        s += e;
      }
#pragma unroll
      for (int o = 1; o < 16; o <<= 1) s += __shfl_xor(s, o);
      rsum[m][r] = s;
    }
  if (ll == 0) {
#pragma unroll
    for (int m = 0; m < 2; ++m)
#pragma unroll
      for (int r = 0; r < 4; ++r) red[1][m * 16 + lh * 4 + r][w] = rsum[m][r];
  }
  __syncthreads();
#pragma unroll
  for (int m = 0; m < 2; ++m)
#pragma unroll
    for (int r = 0; r < 4; ++r) {
      const float* p = red[1][m * 16 + lh * 4 + r];
      float inv = 1.f / (p[0] + p[1] + p[2] + p[3]);
      int row = m * 16 + lh * 4 + r;
#pragma unroll
      for (int n = 0; n < 8; ++n)
        P[row][w * 128 + n * 16 + ll] = __float2bfloat16(acc[m][n][r] * inv);
    }
  __syncthreads();

  const long vtb = ((long)b * 1024 + h * 64) * 512;
  const long ob = (long)b * 512 * 1024 + h * 64;
  const int mw = (w >> 1) * 16, nw = (w & 1) * 32;
  f32x4 oacc[2];
  oacc[0] = (f32x4){0.f, 0.f, 0.f, 0.f};
  oacc[1] = (f32x4){0.f, 0.f, 0.f, 0.f};
#pragma unroll
  for (int ks = 0; ks < 16; ++ks) {
    int k0 = ks * 32;
    bf16x8 pa = *(const bf16x8*)&P[mw + ll][k0 + lh * 8];
#pragma unroll
    for (int nf = 0; nf < 2; ++nf) {
      bf16x8 vb = *(const bf16x8*)&VT[vtb + (long)(nw + nf * 16 + ll) * 512 +
                                      k0 + lh * 8];
      oacc[nf] =
          __builtin_amdgcn_mfma_f32_16x16x32_bf16(pa, vb, oacc[nf], 0, 0, 0);
    }
  }
#pragma unroll
  for (int nf = 0; nf < 2; ++nf)
#pragma unroll
    for (int r = 0; r < 4; ++r)
      O[ob + (long)(i0 + mw + lh * 4 + r) * 1024 + nw + nf * 16 + ll] =
          __float2bfloat16(oacc[nf][r]);
}

// ---------------------------------------------------------------------------
// Row softmax (512) f32 in -> bf16 out. One block per row.
// ---------------------------------------------------------------------------
__global__ __launch_bounds__(256) void softmax_rows(
    const float* __restrict__ P, __hip_bfloat16* __restrict__ Ob) {
  const float* row = P + (long)blockIdx.x * 512;
  __hip_bfloat16* orow = Ob + (long)blockIdx.x * 512;
  int t = threadIdx.x;
  float v0 = row[t], v1 = row[t + 256];
  float m = fmaxf(v0, v1);
#pragma unroll
  for (int o = 32; o; o >>= 1) m = fmaxf(m, __shfl_xor(m, o));
  __shared__ float red[8];
  int wid = t >> 6, lane = t & 63;
  if (!lane) red[wid] = m;
  __syncthreads();
  m = fmaxf(fmaxf(red[0], red[1]), fmaxf(red[2], red[3]));
  float e0 = __expf(v0 - m), e1 = __expf(v1 - m);
  float s = e0 + e1;
#pragma unroll
  for (int o = 32; o; o >>= 1) s += __shfl_xor(s, o);
  if (!lane) red[4 + wid] = s;
  __syncthreads();
  s = red[4] + red[5] + red[6] + red[7];
  float inv = 1.f / s;
  orow[t] = __float2bfloat16(e0 * inv);
  orow[t + 256] = __float2bfloat16(e1 * inv);
}

// ---------------------------------------------------------------------------
// path gather-mean partials + finalize.
// ---------------------------------------------------------------------------
__global__ __launch_bounds__(256) void path_partial(
    const float* __restrict__ xp, const int* __restrict__ pp,
    float* __restrict__ PP, float* __restrict__ WS) {
  int b = blockIdx.x, hc = blockIdx.y, ic = blockIdx.z;
  int h = hc * 256 + threadIdx.x;
  const int* ppb = pp + b * 512;
  const float* xb = xp + (long)b * 512 * 1024;
  int iA = ic * 64, iB = iA + 64;
  float acc = 0.f;
  for (int i = iA; i < iB; ++i) {
    if (ppb[i] != 1) continue;
    float cur = xb[(long)i * 1024 + h];
    float a;
    if (i == 0) {
      a = 0.5f * (cur + xb[1024 + h]);
    } else if (i == 1) {
      a = (xb[h] + cur + xb[2 * 1024 + h]) * (1.f / 3.f);
    } else {
      int inx = (i + 1 < 512) ? i + 1 : 511;
      float nx = xb[(long)inx * 1024 + h];
      if (ppb[i - 2] == 1) {
        a = 0.5f * (cur + nx);
      } else {
        a = (xb[(long)(i - 1) * 1024 + h] + cur + nx) * (1.f / 3.f);
      }
    }
    acc += a;
  }
  PP[((long)b * 8 + ic) * 1024 + h] = acc;
  if (hc == 0 && threadIdx.x == 0) {
    float c = 0.f;
    for (int i = iA; i < iB; ++i) c += (ppb[i] == 1) ? 1.f : 0.f;
    WS[b * 8 + ic] = c;
  }
}

__global__ __launch_bounds__(256) void path_finalize(
    const float* __restrict__ PP, const float* __restrict__ WS,
    float* __restrict__ PATH) {
  int b = blockIdx.x;
  int h = blockIdx.y * 256 + threadIdx.x;
  float s = 0.f, w = 0.f;
#pragma unroll
  for (int ic = 0; ic < 8; ++ic) {
    s += PP[((long)b * 8 + ic) * 1024 + h];
    w += WS[b * 8 + ic];
  }
  PATH[b * 1024 + h] = s / w;
}

// ---------------------------------------------------------------------------
extern "C" void kernel_launch(void* const* d_in, const int* in_sizes, int n_in,
                              void* d_out, int out_size, void* d_ws,
                              size_t ws_size, hipStream_t stream) {
  const float* x = (const float*)d_in[0];
  const int* pp = (const int*)d_in[1];
  const float* abias = (const float*)d_in[3];
  const float* amask = (const float*)d_in[4];
  const float* agraph = (const float*)d_in[5];
  const float* vgraph = (const float*)d_in[6];
  const float* ln1g = (const float*)d_in[7];
  const float* ln1b = (const float*)d_in[8];
  const float* wq = (const float*)d_in[9];
  const float* bq = (const float*)d_in[10];
  const float* wk = (const float*)d_in[11];
  const float* bk = (const float*)d_in[12];
  const float* wv = (const float*)d_in[13];
  const float* bv = (const float*)d_in[14];
  const float* wo = (const float*)d_in[15];
  const float* bo = (const float*)d_in[16];
  const float* pqw = (const float*)d_in[17];
  const float* pqb = (const float*)d_in[18];
  const float* pkw = (const float*)d_in[19];
  const float* pkb = (const float*)d_in[20];
  const float* pvw = (const float*)d_in[21];
  const float* pvb = (const float*)d_in[22];
  const float* ln2g = (const float*)d_in[23];
  const float* ln2b = (const float*)d_in[24];
  const float* w1 = (const float*)d_in[25];
  const float* b1 = (const float*)d_in[26];
  const float* w2 = (const float*)d_in[27];
  const float* b2 = (const float*)d_in[28];

  char* wsb = (char*)d_ws;
  auto Ybf = (__hip_bfloat16*)(wsb);                  // 0-8 (later Y2b)
  auto QKV = (__hip_bfloat16*)(wsb + (8l << 20));     // 8-56: [4096][6144]
  auto VTb = (__hip_bfloat16*)(wsb + (56l << 20));    // 56-64
  auto PVT = (__hip_bfloat16*)(wsb + (64l << 20));    // 64-72
  auto ATTb = (__hip_bfloat16*)(wsb + (72l << 20));   // 72-80 (later W2T)
  auto PATTb = (__hip_bfloat16*)(wsb + (88l << 20));  // 88-92
  auto PATTf = (float*)(wsb + (92l << 20));           // 92-100
  auto XP = (float*)(wsb + (92l << 20));              // 92-108
  auto WALL = (__hip_bfloat16*)(wsb + (108l << 20));  // 108-120: [6144][1024]
  auto WOT = (__hip_bfloat16*)(wsb + (120l << 20));   // 120-122
  auto W1T = (__hip_bfloat16*)(wsb + (122l << 20));   // 122-130
  auto bias6 = (float*)(wsb + (130l << 20));          // 24KB
  auto PPart = (float*)(wsb + (131l << 20));          // 256KB
  auto WSp = (float*)(wsb + (132l << 20));            // 256B
  auto PATH = (float*)(wsb + (133l << 20));           // 32KB
  auto X2 = (float*)(wsb + (24l << 20));              // 24-40 (QKV dead)
  auto HMID = (__hip_bfloat16*)(wsb + (40l << 20));   // 40-72
  auto W2T = ATTb;
  auto PART = (float*)(wsb + (92l << 20));            // 92-156 (4x16MB f32)
  __hip_bfloat16* Y2b = Ybf;
  float* OUT = (float*)d_out;

  const float qscale = 0.125f;
  const float pscale = 0.03125f;
  const long S2 = 512l * 512;
  const long SQ = 512l * 6144;

  __hip_bfloat16* Qp = QKV;
  __hip_bfloat16* Kp = QKV + 1024;
  __hip_bfloat16* Vp = QKV + 2048;
  __hip_bfloat16* PQp = QKV + 3072;
  __hip_bfloat16* PKp = QKV + 4096;
  __hip_bfloat16* PVp = QKV + 5120;

  // 0) weight transposes + bias concat
  TC7 tp;
  tp.in[0] = wq;  tp.out[0] = WALL;                 tp.scale[0] = qscale;
  tp.in[1] = wk;  tp.out[1] = WALL + 1024 * 1024;   tp.scale[1] = 1.f;
  tp.in[2] = wv;  tp.out[2] = WALL + 2048 * 1024;   tp.scale[2] = 1.f;
  tp.in[3] = pqw; tp.out[3] = WALL + 3072 * 1024;   tp.scale[3] = pscale;
  tp.in[4] = pkw; tp.out[4] = WALL + 4096 * 1024;   tp.scale[4] = 1.f;
  tp.in[5] = pvw; tp.out[5] = WALL + 5120 * 1024;   tp.scale[5] = 1.f;
  tp.in[6] = wo;  tp.out[6] = WOT;                  tp.scale[6] = 1.f;
  tconv7<<<dim3(32, 32, 7), 256, 0, stream>>>(tp);
  tconv_f32_bf16<<<dim3(128, 32), 256, 0, stream>>>(w1, W1T, 1024, 4096);

  BC6 bp;
  bp.b[0] = bq;  bp.scale[0] = qscale;
  bp.b[1] = bk;  bp.scale[1] = 1.f;
  bp.b[2] = bv;  bp.scale[2] = 1.f;
  bp.b[3] = pqb; bp.scale[3] = pscale;
  bp.b[4] = pkb; bp.scale[4] = 1.f;
  bp.b[5] = pvb; bp.scale[5] = 1.f;
  bias_concat<<<24, 256, 0, stream>>>(bp, bias6);

  // 1) LN1 -> Ybf
  ln_rows_bf16<<<4096, 256, 0, stream>>>(x, ln1g, ln1b, Ybf);

  // 2) fused projections via gemm256<256>: M=4096 (y=16), N=6144 (x=24)
  gemm256<256><<<dim3(24, 16, 1), 512, 0, stream>>>(
      Ybf, WALL, bias6, QKV, 1024, 1024, 1024, 6144, 0, 1, 0);

  // 3) transposes: V -> VT, PV -> PVT
  tconv_bf16<<<dim3(32, 16, 8), 256, 0, stream>>>(Vp, VTb, 512, 1024, 6144, SQ);
  tconv_bf16<<<dim3(32, 16, 8), 256, 0, stream>>>(PVp, PVT, 512, 1024, 6144, SQ);

  // 4) path scores + softmax
  gemm_bf16_nt<<<dim3(4, 4, 8), 256, 0, stream>>>(
      PQp, PKp, nullptr, agraph, vgraph, PATTf, 1024, 6144, 6144, 512, SQ, SQ,
      S2, S2, 1.f, 0, 0, 0);
  softmax_rows<<<4096, 256, 0, stream>>>(PATTf, PATTb);

  // 5) MFMA attention -> ATTb (reads bias + mask directly)
  attn_mfma<<<dim3(16, 16, 8), 256, 0, stream>>>(Qp, Kp, VTb, abias, amask,
                                                 ATTb, 6144);

  // 6) XP = PATT @ PVT^T
  gemm_bf16_nt<<<dim3(8, 4, 8), 256, 0, stream>>>(
      PATTb, PVT, nullptr, nullptr, nullptr, XP, 512, 512, 512, 1024, S2,
      512l * 1024, 512l * 1024, 0, 1.f, 0, 0, 0);

  // 7) path gather-mean
  path_partial<<<dim3(8, 4, 8), 256, 0, stream>>>(XP, pp, PPart, WSp);
  path_finalize<<<dim3(8, 4), 256, 0, stream>>>(PPart, WSp, PATH);

  // 8) fused: X2 = x + 0.5*((ATT@wo + bo) + PATH)  (pbc epilogue, f32 out)
  gemm_bf16_nt<<<dim3(8, 32, 1), 256, 0, stream>>>(
      ATTb, WOT, bo, x, PATH, X2, 1024, 1024, 1024, 1024, 0, 0, 0, 0, 1.f, 0,
      0, 1);

  // 8b) W2 transpose into ATTb's slot (ATTb now dead)
  tconv_f32_bf16<<<dim3(32, 128), 256, 0, stream>>>(w2, W2T, 4096, 1024);

  // 10) LN2 -> Y2b
  ln_rows_bf16<<<4096, 256, 0, stream>>>(X2, ln2g, ln2b, Y2b);

  // 11) FFN1 via gemm256<256>: M=4096, N=4096, GELU, bf16 out
  gemm256<256><<<dim3(16, 16, 1), 512, 0, stream>>>(
      Y2b, W1T, b1, HMID, 1024, 1024, 1024, 4096, 1, 1, 0);

  // 12) FFN2 split-K=4 via gemm256<256>: grid (4,16,4) = 256 blocks
  gemm256<256><<<dim3(4, 16, 4), 512, 0, stream>>>(
      HMID, W2T, nullptr, PART, 1024, 4096, 4096, 1024, 0, 0, 4194304);

  // 12b) OUT = sum_z PART[z] + b2 + X2
  ffn2_reduce<<<4096, 256, 0, stream>>>(PART, X2, b2, OUT);
}

// Round 11
// 470.372 us; speedup vs baseline: 10.7791x; 1.0088x over previous
//
#include <hip/hip_runtime.h>
#include <hip/hip_bf16.h>
#include <math.h>

// B=8, S=512, H=1024, NH=16, DK=64, FF=4096.
// Round 11: gemm256 K-loop -> AITER-shaped pipeline: 2 barriers/K-tile,
// counted vmcnt (never 0 in-loop; next tile's loads stay in flight a full
// K-tile), no intra-phase barriers (compiler + 2-wave/SIMD TLP overlap
// ds_read with MFMA). QKV -> BN=192 (512 blocks = 2 exact CU rounds).

typedef __bf16 bf16x8 __attribute__((ext_vector_type(8)));
typedef float f32x4 __attribute__((ext_vector_type(4)));

__device__ __forceinline__ void async_copy16(void* lds, const void* g) {
  __builtin_amdgcn_global_load_lds(
      (__attribute__((address_space(1))) void*)(void*)g,
      (__attribute__((address_space(3))) void*)lds, 16, 0, 0);
}

#define SB0 __builtin_amdgcn_sched_barrier(0)
#define BARRIER __builtin_amdgcn_s_barrier()

// ---------------------------------------------------------------------------
// LayerNorm over last dim (1024) -> bf16. One block (256 thr) per row.
// ---------------------------------------------------------------------------
__global__ __launch_bounds__(256) void ln_rows_bf16(
    const float* __restrict__ X, const float* __restrict__ G,
    const float* __restrict__ Bt, __hip_bfloat16* __restrict__ O) {
  long row = blockIdx.x;
  int t = threadIdx.x;
  const float4 xv = ((const float4*)(X + row * 1024))[t];
  float s = xv.x + xv.y + xv.z + xv.w;
  float q = xv.x * xv.x + xv.y * xv.y + xv.z * xv.z + xv.w * xv.w;
#pragma unroll
  for (int o = 32; o; o >>= 1) {
    s += __shfl_xor(s, o);
    q += __shfl_xor(q, o);
  }
  __shared__ float rs[4], rq[4];
  int wid = t >> 6;
  if ((t & 63) == 0) { rs[wid] = s; rq[wid] = q; }
  __syncthreads();
  s = rs[0] + rs[1] + rs[2] + rs[3];
  q = rq[0] + rq[1] + rq[2] + rq[3];
  float mean = s * (1.f / 1024.f);
  float var = q * (1.f / 1024.f) - mean * mean;
  float rstd = rsqrtf(var + 1e-5f);
  const float4 gv = ((const float4*)G)[t];
  const float4 bv = ((const float4*)Bt)[t];
  __hip_bfloat16* o = O + row * 1024 + t * 4;
  o[0] = __float2bfloat16((xv.x - mean) * rstd * gv.x + bv.x);
  o[1] = __float2bfloat16((xv.y - mean) * rstd * gv.y + bv.y);
  o[2] = __float2bfloat16((xv.z - mean) * rstd * gv.z + bv.z);
  o[3] = __float2bfloat16((xv.w - mean) * rstd * gv.w + bv.w);
}

// ---------------------------------------------------------------------------
// Batched weight transpose-convert: 7x f32 [1024,1024] -> bf16 ^T w/ scale.
// ---------------------------------------------------------------------------
struct TC7 {
  const float* in[7];
  __hip_bfloat16* out[7];
  float scale[7];
};
__global__ __launch_bounds__(256) void tconv7(TC7 p) {
  __shared__ float t[32][33];
  int j = blockIdx.z;
  const float* in = p.in[j];
  __hip_bfloat16* out = p.out[j];
  float sc = p.scale[j];
  int c0 = blockIdx.x * 32, r0 = blockIdx.y * 32;
  int tid = threadIdx.x;
  int lr = tid >> 3, lc = (tid & 7) * 4;
  const float4 v = *(const float4*)&in[(long)(r0 + lr) * 1024 + c0 + lc];
  t[lr][lc] = v.x; t[lr][lc + 1] = v.y; t[lr][lc + 2] = v.z; t[lr][lc + 3] = v.w;
  __syncthreads();
  int oc = tid >> 3, orr = (tid & 7) * 4;
  __hip_bfloat16* o = &out[(long)(c0 + oc) * 1024 + r0 + orr];
  o[0] = __float2bfloat16(t[orr][oc] * sc);
  o[1] = __float2bfloat16(t[orr + 1][oc] * sc);
  o[2] = __float2bfloat16(t[orr + 2][oc] * sc);
  o[3] = __float2bfloat16(t[orr + 3][oc] * sc);
}

// Generic transpose-convert f32 [R,C] -> bf16 [C,R]. grid (C/32, R/32).
__global__ __launch_bounds__(256) void tconv_f32_bf16(
    const float* __restrict__ in, __hip_bfloat16* __restrict__ out, int R,
    int C) {
  __shared__ float t[32][33];
  int c0 = blockIdx.x * 32, r0 = blockIdx.y * 32;
  int tid = threadIdx.x;
  int lr = tid >> 3, lc = (tid & 7) * 4;
  const float4 v = *(const float4*)&in[(long)(r0 + lr) * C + c0 + lc];
  t[lr][lc] = v.x; t[lr][lc + 1] = v.y; t[lr][lc + 2] = v.z; t[lr][lc + 3] = v.w;
  __syncthreads();
  int oc = tid >> 3, orr = (tid & 7) * 4;
  __hip_bfloat16* o = &out[(long)(c0 + oc) * R + r0 + orr];
  o[0] = __float2bfloat16(t[orr][oc]);
  o[1] = __float2bfloat16(t[orr + 1][oc]);
  o[2] = __float2bfloat16(t[orr + 2][oc]);
  o[3] = __float2bfloat16(t[orr + 3][oc]);
}

// Batched bf16 transpose, strided input -> packed [bz][C][R].
__global__ __launch_bounds__(256) void tconv_bf16(
    const __hip_bfloat16* __restrict__ in, __hip_bfloat16* __restrict__ out,
    int R, int C, int ldin, long sIn) {
  __shared__ __hip_bfloat16 t[32][34];
  int bz = blockIdx.z;
  long ibase = (long)bz * sIn;
  long obase = (long)bz * R * C;
  int c0 = blockIdx.x * 32, r0 = blockIdx.y * 32;
  int tid = threadIdx.x;
  int lr = tid >> 3, lc = (tid & 7) * 4;
  const __hip_bfloat16* ip = &in[ibase + (long)(r0 + lr) * ldin + c0 + lc];
  t[lr][lc] = ip[0]; t[lr][lc + 1] = ip[1]; t[lr][lc + 2] = ip[2]; t[lr][lc + 3] = ip[3];
  __syncthreads();
  int oc = tid >> 3, orr = (tid & 7) * 4;
  __hip_bfloat16* o = &out[obase + (long)(c0 + oc) * R + r0 + orr];
  o[0] = t[orr][oc];
  o[1] = t[orr + 1][oc];
  o[2] = t[orr + 2][oc];
  o[3] = t[orr + 3][oc];
}

// concat 6 bias vectors (x1024) with per-segment scale -> bias6[6144]
struct BC6 {
  const float* b[6];
  float scale[6];
};
__global__ __launch_bounds__(256) void bias_concat(BC6 p, float* __restrict__ o) {
  int idx = blockIdx.x * 256 + threadIdx.x;
  int j = idx >> 10, e = idx & 1023;
  o[idx] = p.b[j][e] * p.scale[j];
}

// ---------------------------------------------------------------------------
// gemm256<BN>: BM=256, BK=64, 512 thr = 8 waves (2M x 4N).
// K-loop: {barrier(A) -> issue stage(t+1) -> vmcnt(NL) [tile-t retired,
// t+1 in flight across the whole tile] -> barrier(B) -> 4 read+MFMA
// sub-phases, NO barriers}. LDS XOR chunk-swizzle; 2D XCD chunking.
// Split-K via blockIdx.z: K per-split; writes C + z*sC (f32 when obf=0).
// ---------------------------------------------------------------------------
template <int BN>
__global__ __launch_bounds__(512, 2) void gemm256(
    const __hip_bfloat16* __restrict__ A, const __hip_bfloat16* __restrict__ Bt,
    const float* __restrict__ bias, void* __restrict__ C, int K, int lda,
    int ldb, int ldc, int act, int obf, long sC) {
  constexpr int NR = BN / 64;
  constexpr int ABYTES = 256 * 128;
  constexpr int BBYTES = BN * 128;
  constexpr int BUF = ABYTES + BBYTES;
  __shared__ char lds[2 * BUF];

  int bx, by;
  {
    int wg = blockIdx.y * gridDim.x + blockIdx.x;
    int gx = gridDim.x, gy = gridDim.y;
    if ((gx & 3) == 0 && (gy & 1) == 0) {
      int cw = gx >> 2, ch = gy >> 1;
      int xcd = wg & 7, idx = wg >> 3;
      bx = (xcd & 3) * cw + idx % cw;
      by = (xcd >> 2) * ch + idx / cw;
    } else {
      bx = blockIdx.x;
      by = blockIdx.y;
    }
  }
  const int m0 = by * 256, n0 = bx * BN;
  const int z = blockIdx.z;
  const long kbase = (long)z * K * 2;

  const int tid = threadIdx.x;
  const int lane = tid & 63, wid = tid >> 6;
  const int wm = wid >> 2, wn = wid & 3;
  const int ll = lane & 15, lh = lane >> 4;

  const char* Ag = (const char*)A;
  const char* Bg = (const char*)Bt;
  const int srow = tid >> 3;
  const int scb = (((tid & 7) ^ (srow & 7)) << 4);  // swizzled src chunk
  const int sld = (tid & 7) << 4;                   // linear LDS chunk

  auto stageA = [&](char* base, long kb) {
#pragma unroll
    for (int l = 0; l < 4; ++l) {
      int row = l * 64 + srow;
      async_copy16(base + row * 128 + sld,
                   Ag + ((long)(m0 + row) * lda) * 2 + kb + scb);
    }
  };
  auto stageB = [&](char* base, long kb) {
#pragma unroll
    for (int l = 0; l < BN / 64; ++l) {
      int row = l * 64 + srow;
      async_copy16(base + ABYTES + row * 128 + sld,
                   Bg + ((long)(n0 + row) * ldb) * 2 + kb + scb);
    }
  };

  const int rx = ll & 7;
  const int ck[2] = {((0 + lh) ^ rx) << 4, ((4 + lh) ^ rx) << 4};

  f32x4 acc[8][NR];
#pragma unroll
  for (int m = 0; m < 8; ++m)
#pragma unroll
    for (int n = 0; n < NR; ++n) acc[m][n] = (f32x4){0.f, 0.f, 0.f, 0.f};

  const int nt = K >> 6;
  // prologue: stage tile 0 into buf0 (completion waited in iter 0)
  stageA(lds, kbase);
  stageB(lds, kbase);

  for (int t = 0; t < nt; ++t) {
    const int bt = t & 1;
    const char* Ab = lds + bt * BUF;
    const char* Bb = Ab + ABYTES;
    char* nb = lds + (bt ^ 1) * BUF;
    const bool pre = (t + 1 < nt);

    SB0; BARRIER; SB0;  // (A) all waves done reading buffer bt^1
    if (pre) {
      const long kb = kbase + (long)(t + 1) * 128;
      stageA(nb, kb);
      stageB(nb, kb);
      // retire tile-t loads only; tile-(t+1) stays in flight a full K-tile
      if constexpr (BN == 256)
        asm volatile("s_waitcnt vmcnt(8)" ::: "memory");
      else if constexpr (BN == 192)
        asm volatile("s_waitcnt vmcnt(7)" ::: "memory");
      else
        asm volatile("s_waitcnt vmcnt(6)" ::: "memory");
    } else {
      asm volatile("s_waitcnt vmcnt(0)" ::: "memory");
    }
    SB0; BARRIER; SB0;  // (B) tile-t data visible to all waves

#pragma unroll
    for (int ks = 0; ks < 2; ++ks) {
      bf16x8 bf[NR];
#pragma unroll
      for (int n = 0; n < NR; ++n)
        bf[n] = *(const bf16x8*)(Bb + (wn * (BN / 4) + n * 16 + ll) * 128 +
                                 ck[ks]);
      bf16x8 af[4];
#pragma unroll
      for (int m = 0; m < 4; ++m)
        af[m] = *(const bf16x8*)(Ab + (wm * 128 + m * 16 + ll) * 128 + ck[ks]);
      __builtin_amdgcn_s_setprio(1);
#pragma unroll
      for (int m = 0; m < 4; ++m)
#pragma unroll
        for (int n = 0; n < NR; ++n)
          acc[m][n] = __builtin_amdgcn_mfma_f32_16x16x32_bf16(af[m], bf[n],
                                                              acc[m][n], 0, 0, 0);
      __builtin_amdgcn_s_setprio(0);
#pragma unroll
      for (int m = 0; m < 4; ++m)
        af[m] = *(const bf16x8*)(Ab + (wm * 128 + (m + 4) * 16 + ll) * 128 +
                                 ck[ks]);
      __builtin_amdgcn_s_setprio(1);
#pragma unroll
      for (int m = 0; m < 4; ++m)
#pragma unroll
        for (int n = 0; n < NR; ++n)
          acc[m + 4][n] = __builtin_amdgcn_mfma_f32_16x16x32_bf16(
              af[m], bf[n], acc[m + 4][n], 0, 0, 0);
      __builtin_amdgcn_s_setprio(0);
    }
  }

#pragma unroll
  for (int m = 0; m < 8; ++m) {
    int row = m0 + wm * 128 + m * 16 + lh * 4;
#pragma unroll
    for (int n = 0; n < NR; ++n) {
      int col = n0 + wn * (BN / 4) + n * 16 + ll;
      float bs = bias ? bias[col] : 0.f;
#pragma unroll
      for (int r = 0; r < 4; ++r) {
        float v = acc[m][n][r] + bs;
        if (act) v = v * 0.5f * (1.f + erff(v * 0.70710678118f));
        long cidx = (long)z * sC + (long)(row + r) * ldc + col;
        if (obf)
          ((__hip_bfloat16*)C)[cidx] = __float2bfloat16(v);
        else
          ((float*)C)[cidx] = v;
      }
    }
  }
}

// FFN2 finalize: OUT = sum_z PART[z] + b2 + X2. float4/thread, grid 4096.
__global__ __launch_bounds__(256) void ffn2_reduce(
    const float* __restrict__ P, const float* __restrict__ X2,
    const float* __restrict__ b2, float* __restrict__ OUT) {
  int i = blockIdx.x * 256 + threadIdx.x;
  const long SP = 4194304;
  float4 a = ((const float4*)P)[i];
  float4 b = ((const float4*)(P + SP))[i];
  float4 c = ((const float4*)(P + 2 * SP))[i];
  float4 d = ((const float4*)(P + 3 * SP))[i];
  float4 xr = ((const float4*)X2)[i];
  const float4 bb = *(const float4*)(b2 + ((i & 255) * 4));
  float4 o;
  o.x = a.x + b.x + c.x + d.x + xr.x + bb.x;
  o.y = a.y + b.y + c.y + d.y + xr.y + bb.y;
  o.z = a.z + b.z + c.z + d.z + xr.z + bb.z;
  o.w = a.w + b.w + c.w + d.w + xr.w + bb.w;
  ((float4*)OUT)[i] = o;
}

// ---------------------------------------------------------------------------
// bf16 MFMA GEMM (NT), 128x128 tile, BK=32, 4 waves. XCD swizzle.
// pbc=1: C = E1 + 0.5*((A@Bt^T + bias) + E2[row>>9, col])  (combine fusion).
// ---------------------------------------------------------------------------
__global__ __launch_bounds__(256) void gemm_bf16_nt(
    const __hip_bfloat16* __restrict__ A, const __hip_bfloat16* __restrict__ Bt,
    const float* __restrict__ bias, const float* __restrict__ E1,
    const float* __restrict__ E2, void* __restrict__ C, int K, int lda,
    int ldb, int ldc, long sA, long sB, long sC, long sE, float alpha, int act,
    int obf, int pbc) {
  __shared__ unsigned short AsU[128 * 32];
  __shared__ unsigned short BsU[128 * 32];
  const int tid = threadIdx.x;
  const int lane = tid & 63, wave = tid >> 6;
  const int wr = wave >> 1, wc = wave & 1;

  int nwg = gridDim.x * gridDim.y;
  int wg = blockIdx.y * gridDim.x + blockIdx.x;
  int bx = blockIdx.x, by = blockIdx.y;
  if ((nwg & 7) == 0) {
    int cpx = nwg >> 3;
    int sw = (wg & 7) * cpx + (wg >> 3);
    bx = sw % gridDim.x;
    by = sw / gridDim.x;
  }
  const int m0 = by * 128, n0 = bx * 128;
  const int bz = blockIdx.z;
  const char* Ab = (const char*)(A + (long)bz * sA);
  const char* Bb = (const char*)(Bt + (long)bz * sB);

  f32x4 acc[4][4];
#pragma unroll
  for (int m = 0; m < 4; ++m)
#pragma unroll
    for (int n = 0; n < 4; ++n) acc[m][n] = (f32x4){0.f, 0.f, 0.f, 0.f};

  const int srow = tid >> 2;
  const int scol = (tid & 3) * 16;
  const int wbase = (tid >> 6) * 1024;

  for (int k0 = 0; k0 < K; k0 += 32) {
#pragma unroll
    for (int i = 0; i < 2; ++i) {
      async_copy16((char*)AsU + i * 4096 + wbase,
                   Ab + ((long)(m0 + i * 64 + srow) * lda + k0) * 2 + scol);
      async_copy16((char*)BsU + i * 4096 + wbase,
                   Bb + ((long)(n0 + i * 64 + srow) * ldb + k0) * 2 + scol);
    }
    __syncthreads();

    const int koff = (lane >> 4) * 8;
    bf16x8 a[4], b[4];
#pragma unroll
    for (int m = 0; m < 4; ++m)
      a[m] = *(const bf16x8*)&AsU[(wr * 64 + m * 16 + (lane & 15)) * 32 + koff];
#pragma unroll
    for (int n = 0; n < 4; ++n)
      b[n] = *(const bf16x8*)&BsU[(wc * 64 + n * 16 + (lane & 15)) * 32 + koff];
#pragma unroll
    for (int m = 0; m < 4; ++m)
#pragma unroll
      for (int n = 0; n < 4; ++n)
        acc[m][n] = __builtin_amdgcn_mfma_f32_16x16x32_bf16(a[m], b[n],
                                                            acc[m][n], 0, 0, 0);
    __syncthreads();
  }

#pragma unroll
  for (int m = 0; m < 4; ++m) {
    int row = m0 + wr * 64 + m * 16 + (lane >> 4) * 4;
#pragma unroll
    for (int n = 0; n < 4; ++n) {
      int col = n0 + wc * 64 + n * 16 + (lane & 15);
      float bs = bias ? bias[col] : 0.f;
#pragma unroll
      for (int r = 0; r < 4; ++r) {
        float v = (acc[m][n][r] + bs) * alpha;
        if (pbc) {
          v = E1[(long)(row + r) * ldc + col] +
              0.5f * (v + E2[(long)((row + r) >> 9) * 1024 + col]);
        } else {
          long eidx = (long)bz * sE + (long)(row + r) * ldc + col;
          if (E1) v += E1[eidx];
          if (E2) v += E2[eidx];
        }
        if (act) v = v * 0.5f * (1.f + erff(v * 0.70710678118f));
        long cidx = (long)bz * sC + (long)(row + r) * ldc + col;
        if (obf)
          ((__hip_bfloat16*)C)[cidx] = __float2bfloat16(v);
        else
          ((float*)C)[cidx] = v;
      }
    }
  }
}

// ---------------------------------------------------------------------------
// MFMA attention. Block = (i-tile of 32, h, b); 4 waves. Reads bias+mask raw.
// ---------------------------------------------------------------------------
__global__ __launch_bounds__(256) void attn_mfma(
    const __hip_bfloat16* __restrict__ Q, const __hip_bfloat16* __restrict__ K,
    const __hip_bfloat16* __restrict__ VT, const float* __restrict__ BiasP,
    const float* __restrict__ MaskP, __hip_bfloat16* __restrict__ O,
    int ldqk) {
  __shared__ __hip_bfloat16 P[32][520];
  __shared__ float red[2][32][4];
  const int it = blockIdx.x, h = blockIdx.y, b = blockIdx.z;
  const int i0 = it * 32;
  const int tid = threadIdx.x;
  const int lane = tid & 63, w = tid >> 6;
  const int lh = lane >> 4, ll = lane & 15;

  const long qkb = (long)b * 512 * ldqk + h * 64;

  bf16x8 a[2][2];
#pragma unroll
  for (int m = 0; m < 2; ++m)
#pragma unroll
    for (int ks = 0; ks < 2; ++ks)
      a[m][ks] = *(const bf16x8*)&Q[qkb + (long)(i0 + m * 16 + ll) * ldqk +
                                    ks * 32 + lh * 8];

  f32x4 acc[2][8];
#pragma unroll
  for (int m = 0; m < 2; ++m)
#pragma unroll
    for (int n = 0; n < 8; ++n) acc[m][n] = (f32x4){0.f, 0.f, 0.f, 0.f};

#pragma unroll
  for (int n = 0; n < 8; ++n) {
    const __hip_bfloat16* kp =
        &K[qkb + (long)(w * 128 + n * 16 + ll) * ldqk + lh * 8];
    bf16x8 b0 = *(const bf16x8*)&kp[0];
    bf16x8 b1 = *(const bf16x8*)&kp[32];
#pragma unroll
    for (int m = 0; m < 2; ++m) {
      acc[m][n] =
          __builtin_amdgcn_mfma_f32_16x16x32_bf16(a[m][0], b0, acc[m][n], 0, 0, 0);
      acc[m][n] =
          __builtin_amdgcn_mfma_f32_16x16x32_bf16(a[m][1], b1, acc[m][n], 0, 0, 0);
    }
  }

  const long bmo = ((long)b * 512 + i0) * 512 + w * 128;
#pragma unroll
  for (int m = 0; m < 2; ++m)
#pragma unroll
    for (int r = 0; r < 4; ++r) {
      int row = m * 16 + lh * 4 + r;
#pragma unroll
      for (int n = 0; n < 8; ++n) {
        long gi = bmo + (long)row * 512 + n * 16 + ll;
        acc[m][n][r] += BiasP[gi] + MaskP[gi];
      }
    }

  float rmax[2][4];
#pragma unroll
  for (int m = 0; m < 2; ++m)
#pragma unroll
    for (int r = 0; r < 4; ++r) {
      float v = acc[m][0][r];
#pragma unroll
      for (int n = 1; n < 8; ++n) v = fmaxf(v, acc[m][n][r]);
#pragma unroll
      for (int o = 1; o < 16; o <<= 1) v = fmaxf(v, __shfl_xor(v, o));
      rmax[m][r] = v;
    }
  if (ll == 0) {
#pragma unroll
    for (int m = 0; m < 2; ++m)
#pragma unroll
      for (int r = 0; r < 4; ++r) red[0][m * 16 + lh * 4 + r][w] = rmax[m][r];
  }
  __syncthreads();
#pragma unroll
  for (int m = 0; m < 2; ++m)
#pragma unroll
    for (int r = 0; r < 4; ++r) {
      const float* p = red[0][m * 16 + lh * 4 + r];
      rmax[m][r] = fmaxf(fmaxf(p[0], p[1]), fmaxf(p[2], p[3]));
    }
  float rsum[2][4];
#pragma unroll
  for (int m = 0; m < 2; ++m)
#pragma unroll
    for (int r = 0; r < 4; ++r) {
      float s = 0.f;
#pragma unroll
      for (int n = 0; n < 8; ++n) {
        float e = __expf(acc[m][n][r] - rmax[m][r]);
        acc[m][n][r] = e;
        s += e;
      }
#pragma unroll
      for (int o = 1; o < 16; o <<= 1) s += __shfl_xor(s, o);
      rsum[m][r] = s;
    }
  if (ll == 0) {
#pragma unroll
    for (int m = 0; m < 2; ++m)
#pragma unroll
      for (int r = 0; r < 4; ++r) red[1][m * 16 + lh * 4 + r][w] = rsum[m][r];
  }
  __syncthreads();
#pragma unroll
  for (int m = 0; m < 2; ++m)
#pragma unroll
    for (int r = 0; r < 4; ++r) {
      const float* p = red[1][m * 16 + lh * 4 + r];
      float inv = 1.f / (p[0] + p[1] + p[2] + p[3]);
      int row = m * 16 + lh * 4 + r;
#pragma unroll
      for (int n = 0; n < 8; ++n)
        P[row][w * 128 + n * 16 + ll] = __float2bfloat16(acc[m][n][r] * inv);
    }
  __syncthreads();

  const long vtb = ((long)b * 1024 + h * 64) * 512;
  const long ob = (long)b * 512 * 1024 + h * 64;
  const int mw = (w >> 1) * 16, nw = (w & 1) * 32;
  f32x4 oacc[2];
  oacc[0] = (f32x4){0.f, 0.f, 0.f, 0.f};
  oacc[1] = (f32x4){0.f, 0.f, 0.f, 0.f};
#pragma unroll
  for (int ks = 0; ks < 16; ++ks) {
    int k0 = ks * 32;
    bf16x8 pa = *(const bf16x8*)&P[mw + ll][k0 + lh * 8];
#pragma unroll
    for (int nf = 0; nf < 2; ++nf) {
      bf16x8 vb = *(const bf16x8*)&VT[vtb + (long)(nw + nf * 16 + ll) * 512 +
                                      k0 + lh * 8];
      oacc[nf] =
          __builtin_amdgcn_mfma_f32_16x16x32_bf16(pa, vb, oacc[nf], 0, 0, 0);
    }
  }
#pragma unroll
  for (int nf = 0; nf < 2; ++nf)
#pragma unroll
    for (int r = 0; r < 4; ++r)
      O[ob + (long)(i0 + mw + lh * 4 + r) * 1024 + nw + nf * 16 + ll] =
          __float2bfloat16(oacc[nf][r]);
}

// ---------------------------------------------------------------------------
// Row softmax (512) f32 in -> bf16 out. One block per row.
// ---------------------------------------------------------------------------
__global__ __launch_bounds__(256) void softmax_rows(
    const float* __restrict__ P, __hip_bfloat16* __restrict__ Ob) {
  const float* row = P + (long)blockIdx.x * 512;
  __hip_bfloat16* orow = Ob + (long)blockIdx.x * 512;
  int t = threadIdx.x;
  float v0 = row[t], v1 = row[t + 256];
  float m = fmaxf(v0, v1);
#pragma unroll
  for (int o = 32; o; o >>= 1) m = fmaxf(m, __shfl_xor(m, o));
  __shared__ float red[8];
  int wid = t >> 6, lane = t & 63;
  if (!lane) red[wid] = m;
  __syncthreads();
  m = fmaxf(fmaxf(red[0], red[1]), fmaxf(red[2], red[3]));
  float e0 = __expf(v0 - m), e1 = __expf(v1 - m);
  float s = e0 + e1;
#pragma unroll
  for (int o = 32; o; o >>= 1) s += __shfl_xor(s, o);
  if (!lane) red[4 + wid] = s;
  __syncthreads();
  s = red[4] + red[5] + red[6] + red[7];
  float inv = 1.f / s;
  orow[t] = __float2bfloat16(e0 * inv);
  orow[t + 256] = __float2bfloat16(e1 * inv);
}

// ---------------------------------------------------------------------------
// path gather-mean partials + finalize.
// ---------------------------------------------------------------------------
__global__ __launch_bounds__(256) void path_partial(
    const float* __restrict__ xp, const int* __restrict__ pp,
    float* __restrict__ PP, float* __restrict__ WS) {
  int b = blockIdx.x, hc = blockIdx.y, ic = blockIdx.z;
  int h = hc * 256 + threadIdx.x;
  const int* ppb = pp + b * 512;
  const float* xb = xp + (long)b * 512 * 1024;
  int iA = ic * 64, iB = iA + 64;
  float acc = 0.f;
  for (int i = iA; i < iB; ++i) {
    if (ppb[i] != 1) continue;
    float cur = xb[(long)i * 1024 + h];
    float a;
    if (i == 0) {
      a = 0.5f * (cur + xb[1024 + h]);
    } else if (i == 1) {
      a = (xb[h] + cur + xb[2 * 1024 + h]) * (1.f / 3.f);
    } else {
      int inx = (i + 1 < 512) ? i + 1 : 511;
      float nx = xb[(long)inx * 1024 + h];
      if (ppb[i - 2] == 1) {
        a = 0.5f * (cur + nx);
      } else {
        a = (xb[(long)(i - 1) * 1024 + h] + cur + nx) * (1.f / 3.f);
      }
    }
    acc += a;
  }
  PP[((long)b * 8 + ic) * 1024 + h] = acc;
  if (hc == 0 && threadIdx.x == 0) {
    float c = 0.f;
    for (int i = iA; i < iB; ++i) c += (ppb[i] == 1) ? 1.f : 0.f;
    WS[b * 8 + ic] = c;
  }
}

__global__ __launch_bounds__(256) void path_finalize(
    const float* __restrict__ PP, const float* __restrict__ WS,
    float* __restrict__ PATH) {
  int b = blockIdx.x;
  int h = blockIdx.y * 256 + threadIdx.x;
  float s = 0.f, w = 0.f;
#pragma unroll
  for (int ic = 0; ic < 8; ++ic) {
    s += PP[((long)b * 8 + ic) * 1024 + h];
    w += WS[b * 8 + ic];
  }
  PATH[b * 1024 + h] = s / w;
}

// ---------------------------------------------------------------------------
extern "C" void kernel_launch(void* const* d_in, const int* in_sizes, int n_in,
                              void* d_out, int out_size, void* d_ws,
                              size_t ws_size, hipStream_t stream) {
  const float* x = (const float*)d_in[0];
  const int* pp = (const int*)d_in[1];
  const float* abias = (const float*)d_in[3];
  const float* amask = (const float*)d_in[4];
  const float* agraph = (const float*)d_in[5];
  const float* vgraph = (const float*)d_in[6];
  const float* ln1g = (const float*)d_in[7];
  const float* ln1b = (const float*)d_in[8];
  const float* wq = (const float*)d_in[9];
  const float* bq = (const float*)d_in[10];
  const float* wk = (const float*)d_in[11];
  const float* bk = (const float*)d_in[12];
  const float* wv = (const float*)d_in[13];
  const float* bv = (const float*)d_in[14];
  const float* wo = (const float*)d_in[15];
  const float* bo = (const float*)d_in[16];
  const float* pqw = (const float*)d_in[17];
  const float* pqb = (const float*)d_in[18];
  const float* pkw = (const float*)d_in[19];
  const float* pkb = (const float*)d_in[20];
  const float* pvw = (const float*)d_in[21];
  const float* pvb = (const float*)d_in[22];
  const float* ln2g = (const float*)d_in[23];
  const float* ln2b = (const float*)d_in[24];
  const float* w1 = (const float*)d_in[25];
  const float* b1 = (const float*)d_in[26];
  const float* w2 = (const float*)d_in[27];
  const float* b2 = (const float*)d_in[28];

  char* wsb = (char*)d_ws;
  auto Ybf = (__hip_bfloat16*)(wsb);                  // 0-8 (later Y2b)
  auto QKV = (__hip_bfloat16*)(wsb + (8l << 20));     // 8-56: [4096][6144]
  auto VTb = (__hip_bfloat16*)(wsb + (56l << 20));    // 56-64
  auto PVT = (__hip_bfloat16*)(wsb + (64l << 20));    // 64-72
  auto ATTb = (__hip_bfloat16*)(wsb + (72l << 20));   // 72-80 (later W2T)
  auto PATTb = (__hip_bfloat16*)(wsb + (88l << 20));  // 88-92
  auto PATTf = (float*)(wsb + (92l << 20));           // 92-100
  auto XP = (float*)(wsb + (92l << 20));              // 92-108
  auto WALL = (__hip_bfloat16*)(wsb + (108l << 20));  // 108-120: [6144][1024]
  auto WOT = (__hip_bfloat16*)(wsb + (120l << 20));   // 120-122
  auto W1T = (__hip_bfloat16*)(wsb + (122l << 20));   // 122-130
  auto bias6 = (float*)(wsb + (130l << 20));          // 24KB
  auto PPart = (float*)(wsb + (131l << 20));          // 256KB
  auto WSp = (float*)(wsb + (132l << 20));            // 256B
  auto PATH = (float*)(wsb + (133l << 20));           // 32KB
  auto X2 = (float*)(wsb + (24l << 20));              // 24-40 (QKV dead)
  auto HMID = (__hip_bfloat16*)(wsb + (40l << 20));   // 40-72
  auto W2T = ATTb;
  auto PART = (float*)(wsb + (92l << 20));            // 92-156 (4x16MB f32)
  __hip_bfloat16* Y2b = Ybf;
  float* OUT = (float*)d_out;

  const float qscale = 0.125f;
  const float pscale = 0.03125f;
  const long S2 = 512l * 512;
  const long SQ = 512l * 6144;

  __hip_bfloat16* Qp = QKV;
  __hip_bfloat16* Kp = QKV + 1024;
  __hip_bfloat16* Vp = QKV + 2048;
  __hip_bfloat16* PQp = QKV + 3072;
  __hip_bfloat16* PKp = QKV + 4096;
  __hip_bfloat16* PVp = QKV + 5120;

  // 0) weight transposes + bias concat
  TC7 tp;
  tp.in[0] = wq;  tp.out[0] = WALL;                 tp.scale[0] = qscale;
  tp.in[1] = wk;  tp.out[1] = WALL + 1024 * 1024;   tp.scale[1] = 1.f;
  tp.in[2] = wv;  tp.out[2] = WALL + 2048 * 1024;   tp.scale[2] = 1.f;
  tp.in[3] = pqw; tp.out[3] = WALL + 3072 * 1024;   tp.scale[3] = pscale;
  tp.in[4] = pkw; tp.out[4] = WALL + 4096 * 1024;   tp.scale[4] = 1.f;
  tp.in[5] = pvw; tp.out[5] = WALL + 5120 * 1024;   tp.scale[5] = 1.f;
  tp.in[6] = wo;  tp.out[6] = WOT;                  tp.scale[6] = 1.f;
  tconv7<<<dim3(32, 32, 7), 256, 0, stream>>>(tp);
  tconv_f32_bf16<<<dim3(128, 32), 256, 0, stream>>>(w1, W1T, 1024, 4096);

  BC6 bp;
  bp.b[0] = bq;  bp.scale[0] = qscale;
  bp.b[1] = bk;  bp.scale[1] = 1.f;
  bp.b[2] = bv;  bp.scale[2] = 1.f;
  bp.b[3] = pqb; bp.scale[3] = pscale;
  bp.b[4] = pkb; bp.scale[4] = 1.f;
  bp.b[5] = pvb; bp.scale[5] = 1.f;
  bias_concat<<<24, 256, 0, stream>>>(bp, bias6);

  // 1) LN1 -> Ybf
  ln_rows_bf16<<<4096, 256, 0, stream>>>(x, ln1g, ln1b, Ybf);

  // 2) fused projections via gemm256<192>: M=4096 (y=16), N=6144 (x=32)
  //    512 blocks = 2 exact CU rounds.
  gemm256<192><<<dim3(32, 16, 1), 512, 0, stream>>>(
      Ybf, WALL, bias6, QKV, 1024, 1024, 1024, 6144, 0, 1, 0);

  // 3) transposes: V -> VT, PV -> PVT
  tconv_bf16<<<dim3(32, 16, 8), 256, 0, stream>>>(Vp, VTb, 512, 1024, 6144, SQ);
  tconv_bf16<<<dim3(32, 16, 8), 256, 0, stream>>>(PVp, PVT, 512, 1024, 6144, SQ);

  // 4) path scores + softmax
  gemm_bf16_nt<<<dim3(4, 4, 8), 256, 0, stream>>>(
      PQp, PKp, nullptr, agraph, vgraph, PATTf, 1024, 6144, 6144, 512, SQ, SQ,
      S2, S2, 1.f, 0, 0, 0);
  softmax_rows<<<4096, 256, 0, stream>>>(PATTf, PATTb);

  // 5) MFMA attention -> ATTb (reads bias + mask directly)
  attn_mfma<<<dim3(16, 16, 8), 256, 0, stream>>>(Qp, Kp, VTb, abias, amask,
                                                 ATTb, 6144);

  // 6) XP = PATT @ PVT^T
  gemm_bf16_nt<<<dim3(8, 4, 8), 256, 0, stream>>>(
      PATTb, PVT, nullptr, nullptr, nullptr, XP, 512, 512, 512, 1024, S2,
      512l * 1024, 512l * 1024, 0, 1.f, 0, 0, 0);

  // 7) path gather-mean
  path_partial<<<dim3(8, 4, 8), 256, 0, stream>>>(XP, pp, PPart, WSp);
  path_finalize<<<dim3(8, 4), 256, 0, stream>>>(PPart, WSp, PATH);

  // 8) fused: X2 = x + 0.5*((ATT@wo + bo) + PATH)  (pbc epilogue, f32 out)
  gemm_bf16_nt<<<dim3(8, 32, 1), 256, 0, stream>>>(
      ATTb, WOT, bo, x, PATH, X2, 1024, 1024, 1024, 1024, 0, 0, 0, 0, 1.f, 0,
      0, 1);

  // 8b) W2 transpose into ATTb's slot (ATTb now dead)
  tconv_f32_bf16<<<dim3(32, 128), 256, 0, stream>>>(w2, W2T, 4096, 1024);

  // 10) LN2 -> Y2b
  ln_rows_bf16<<<4096, 256, 0, stream>>>(X2, ln2g, ln2b, Y2b);

  // 11) FFN1 via gemm256<256>: M=4096, N=4096, GELU, bf16 out
  gemm256<256><<<dim3(16, 16, 1), 512, 0, stream>>>(
      Y2b, W1T, b1, HMID, 1024, 1024, 1024, 4096, 1, 1, 0);

  // 12) FFN2 split-K=4 via gemm256<256>: grid (4,16,4) = 256 blocks
  gemm256<256><<<dim3(4, 16, 4), 512, 0, stream>>>(
      HMID, W2T, nullptr, PART, 1024, 4096, 4096, 1024, 0, 0, 4194304);

  // 12b) OUT = sum_z PART[z] + b2 + X2
  ffn2_reduce<<<4096, 256, 0, stream>>>(PART, X2, b2, OUT);
}

// Round 12
// 452.350 us; speedup vs baseline: 11.2086x; 1.0398x over previous
//
#include <hip/hip_runtime.h>
#include <hip/hip_bf16.h>
#include <math.h>

// B=8, S=512, H=1024, NH=16, DK=64, FF=4096.
// Round 12: gemm_bf16_nt gets (1) the round-11 counted-vmcnt double-buffer
// pipeline (was full-drain per K-step; path-scores GEMM showed MfmaUtil 1.9%
// at 79us), (2) split-K via z-packing (path GEMM: 128 -> 256 blocks,
// f32 partials summed inside softmax). gemm256 unchanged from round 11.

typedef __bf16 bf16x8 __attribute__((ext_vector_type(8)));
typedef float f32x4 __attribute__((ext_vector_type(4)));

__device__ __forceinline__ void async_copy16(void* lds, const void* g) {
  __builtin_amdgcn_global_load_lds(
      (__attribute__((address_space(1))) void*)(void*)g,
      (__attribute__((address_space(3))) void*)lds, 16, 0, 0);
}

#define SB0 __builtin_amdgcn_sched_barrier(0)
#define BARRIER __builtin_amdgcn_s_barrier()

// ---------------------------------------------------------------------------
// LayerNorm over last dim (1024) -> bf16. One block (256 thr) per row.
// ---------------------------------------------------------------------------
__global__ __launch_bounds__(256) void ln_rows_bf16(
    const float* __restrict__ X, const float* __restrict__ G,
    const float* __restrict__ Bt, __hip_bfloat16* __restrict__ O) {
  long row = blockIdx.x;
  int t = threadIdx.x;
  const float4 xv = ((const float4*)(X + row * 1024))[t];
  float s = xv.x + xv.y + xv.z + xv.w;
  float q = xv.x * xv.x + xv.y * xv.y + xv.z * xv.z + xv.w * xv.w;
#pragma unroll
  for (int o = 32; o; o >>= 1) {
    s += __shfl_xor(s, o);
    q += __shfl_xor(q, o);
  }
  __shared__ float rs[4], rq[4];
  int wid = t >> 6;
  if ((t & 63) == 0) { rs[wid] = s; rq[wid] = q; }
  __syncthreads();
  s = rs[0] + rs[1] + rs[2] + rs[3];
  q = rq[0] + rq[1] + rq[2] + rq[3];
  float mean = s * (1.f / 1024.f);
  float var = q * (1.f / 1024.f) - mean * mean;
  float rstd = rsqrtf(var + 1e-5f);
  const float4 gv = ((const float4*)G)[t];
  const float4 bv = ((const float4*)Bt)[t];
  __hip_bfloat16* o = O + row * 1024 + t * 4;
  o[0] = __float2bfloat16((xv.x - mean) * rstd * gv.x + bv.x);
  o[1] = __float2bfloat16((xv.y - mean) * rstd * gv.y + bv.y);
  o[2] = __float2bfloat16((xv.z - mean) * rstd * gv.z + bv.z);
  o[3] = __float2bfloat16((xv.w - mean) * rstd * gv.w + bv.w);
}

// ---------------------------------------------------------------------------
// Batched weight transpose-convert: 7x f32 [1024,1024] -> bf16 ^T w/ scale.
// ---------------------------------------------------------------------------
struct TC7 {
  const float* in[7];
  __hip_bfloat16* out[7];
  float scale[7];
};
__global__ __launch_bounds__(256) void tconv7(TC7 p) {
  __shared__ float t[32][33];
  int j = blockIdx.z;
  const float* in = p.in[j];
  __hip_bfloat16* out = p.out[j];
  float sc = p.scale[j];
  int c0 = blockIdx.x * 32, r0 = blockIdx.y * 32;
  int tid = threadIdx.x;
  int lr = tid >> 3, lc = (tid & 7) * 4;
  const float4 v = *(const float4*)&in[(long)(r0 + lr) * 1024 + c0 + lc];
  t[lr][lc] = v.x; t[lr][lc + 1] = v.y; t[lr][lc + 2] = v.z; t[lr][lc + 3] = v.w;
  __syncthreads();
  int oc = tid >> 3, orr = (tid & 7) * 4;
  __hip_bfloat16* o = &out[(long)(c0 + oc) * 1024 + r0 + orr];
  o[0] = __float2bfloat16(t[orr][oc] * sc);
  o[1] = __float2bfloat16(t[orr + 1][oc] * sc);
  o[2] = __float2bfloat16(t[orr + 2][oc] * sc);
  o[3] = __float2bfloat16(t[orr + 3][oc] * sc);
}

// Generic transpose-convert f32 [R,C] -> bf16 [C,R]. grid (C/32, R/32).
__global__ __launch_bounds__(256) void tconv_f32_bf16(
    const float* __restrict__ in, __hip_bfloat16* __restrict__ out, int R,
    int C) {
  __shared__ float t[32][33];
  int c0 = blockIdx.x * 32, r0 = blockIdx.y * 32;
  int tid = threadIdx.x;
  int lr = tid >> 3, lc = (tid & 7) * 4;
  const float4 v = *(const float4*)&in[(long)(r0 + lr) * C + c0 + lc];
  t[lr][lc] = v.x; t[lr][lc + 1] = v.y; t[lr][lc + 2] = v.z; t[lr][lc + 3] = v.w;
  __syncthreads();
  int oc = tid >> 3, orr = (tid & 7) * 4;
  __hip_bfloat16* o = &out[(long)(c0 + oc) * R + r0 + orr];
  o[0] = __float2bfloat16(t[orr][oc]);
  o[1] = __float2bfloat16(t[orr + 1][oc]);
  o[2] = __float2bfloat16(t[orr + 2][oc]);
  o[3] = __float2bfloat16(t[orr + 3][oc]);
}

// Batched bf16 transpose, strided input -> packed [bz][C][R].
__global__ __launch_bounds__(256) void tconv_bf16(
    const __hip_bfloat16* __restrict__ in, __hip_bfloat16* __restrict__ out,
    int R, int C, int ldin, long sIn) {
  __shared__ __hip_bfloat16 t[32][34];
  int bz = blockIdx.z;
  long ibase = (long)bz * sIn;
  long obase = (long)bz * R * C;
  int c0 = blockIdx.x * 32, r0 = blockIdx.y * 32;
  int tid = threadIdx.x;
  int lr = tid >> 3, lc = (tid & 7) * 4;
  const __hip_bfloat16* ip = &in[ibase + (long)(r0 + lr) * ldin + c0 + lc];
  t[lr][lc] = ip[0]; t[lr][lc + 1] = ip[1]; t[lr][lc + 2] = ip[2]; t[lr][lc + 3] = ip[3];
  __syncthreads();
  int oc = tid >> 3, orr = (tid & 7) * 4;
  __hip_bfloat16* o = &out[obase + (long)(c0 + oc) * R + r0 + orr];
  o[0] = t[orr][oc];
  o[1] = t[orr + 1][oc];
  o[2] = t[orr + 2][oc];
  o[3] = t[orr + 3][oc];
}

// concat 6 bias vectors (x1024) with per-segment scale -> bias6[6144]
struct BC6 {
  const float* b[6];
  float scale[6];
};
__global__ __launch_bounds__(256) void bias_concat(BC6 p, float* __restrict__ o) {
  int idx = blockIdx.x * 256 + threadIdx.x;
  int j = idx >> 10, e = idx & 1023;
  o[idx] = p.b[j][e] * p.scale[j];
}

// ---------------------------------------------------------------------------
// gemm256<BN>: BM=256, BK=64, 512 thr = 8 waves (2M x 4N).
// K-loop: {barrier(A) -> issue stage(t+1) -> counted vmcnt -> barrier(B) ->
// read+MFMA, no intra barriers}. LDS XOR chunk-swizzle; 2D XCD chunking.
// Split-K via blockIdx.z: K per-split; writes C + z*sC (f32 when obf=0).
// ---------------------------------------------------------------------------
template <int BN>
__global__ __launch_bounds__(512, 2) void gemm256(
    const __hip_bfloat16* __restrict__ A, const __hip_bfloat16* __restrict__ Bt,
    const float* __restrict__ bias, void* __restrict__ C, int K, int lda,
    int ldb, int ldc, int act, int obf, long sC) {
  constexpr int NR = BN / 64;
  constexpr int ABYTES = 256 * 128;
  constexpr int BBYTES = BN * 128;
  constexpr int BUF = ABYTES + BBYTES;
  __shared__ char lds[2 * BUF];

  int bx, by;
  {
    int wg = blockIdx.y * gridDim.x + blockIdx.x;
    int gx = gridDim.x, gy = gridDim.y;
    if ((gx & 3) == 0 && (gy & 1) == 0) {
      int cw = gx >> 2, ch = gy >> 1;
      int xcd = wg & 7, idx = wg >> 3;
      bx = (xcd & 3) * cw + idx % cw;
      by = (xcd >> 2) * ch + idx / cw;
    } else {
      bx = blockIdx.x;
      by = blockIdx.y;
    }
  }
  const int m0 = by * 256, n0 = bx * BN;
  const int z = blockIdx.z;
  const long kbase = (long)z * K * 2;

  const int tid = threadIdx.x;
  const int lane = tid & 63, wid = tid >> 6;
  const int wm = wid >> 2, wn = wid & 3;
  const int ll = lane & 15, lh = lane >> 4;

  const char* Ag = (const char*)A;
  const char* Bg = (const char*)Bt;
  const int srow = tid >> 3;
  const int scb = (((tid & 7) ^ (srow & 7)) << 4);
  const int sld = (tid & 7) << 4;

  auto stageA = [&](char* base, long kb) {
#pragma unroll
    for (int l = 0; l < 4; ++l) {
      int row = l * 64 + srow;
      async_copy16(base + row * 128 + sld,
                   Ag + ((long)(m0 + row) * lda) * 2 + kb + scb);
    }
  };
  auto stageB = [&](char* base, long kb) {
#pragma unroll
    for (int l = 0; l < BN / 64; ++l) {
      int row = l * 64 + srow;
      async_copy16(base + ABYTES + row * 128 + sld,
                   Bg + ((long)(n0 + row) * ldb) * 2 + kb + scb);
    }
  };

  const int rx = ll & 7;
  const int ck[2] = {((0 + lh) ^ rx) << 4, ((4 + lh) ^ rx) << 4};

  f32x4 acc[8][NR];
#pragma unroll
  for (int m = 0; m < 8; ++m)
#pragma unroll
    for (int n = 0; n < NR; ++n) acc[m][n] = (f32x4){0.f, 0.f, 0.f, 0.f};

  const int nt = K >> 6;
  stageA(lds, kbase);
  stageB(lds, kbase);

  for (int t = 0; t < nt; ++t) {
    const int bt = t & 1;
    const char* Ab = lds + bt * BUF;
    const char* Bb = Ab + ABYTES;
    char* nb = lds + (bt ^ 1) * BUF;
    const bool pre = (t + 1 < nt);

    SB0; BARRIER; SB0;
    if (pre) {
      const long kb = kbase + (long)(t + 1) * 128;
      stageA(nb, kb);
      stageB(nb, kb);
      if constexpr (BN == 256)
        asm volatile("s_waitcnt vmcnt(8)" ::: "memory");
      else if constexpr (BN == 192)
        asm volatile("s_waitcnt vmcnt(7)" ::: "memory");
      else
        asm volatile("s_waitcnt vmcnt(6)" ::: "memory");
    } else {
      asm volatile("s_waitcnt vmcnt(0)" ::: "memory");
    }
    SB0; BARRIER; SB0;

#pragma unroll
    for (int ks = 0; ks < 2; ++ks) {
      bf16x8 bf[NR];
#pragma unroll
      for (int n = 0; n < NR; ++n)
        bf[n] = *(const bf16x8*)(Bb + (wn * (BN / 4) + n * 16 + ll) * 128 +
                                 ck[ks]);
      bf16x8 af[4];
#pragma unroll
      for (int m = 0; m < 4; ++m)
        af[m] = *(const bf16x8*)(Ab + (wm * 128 + m * 16 + ll) * 128 + ck[ks]);
      __builtin_amdgcn_s_setprio(1);
#pragma unroll
      for (int m = 0; m < 4; ++m)
#pragma unroll
        for (int n = 0; n < NR; ++n)
          acc[m][n] = __builtin_amdgcn_mfma_f32_16x16x32_bf16(af[m], bf[n],
                                                              acc[m][n], 0, 0, 0);
      __builtin_amdgcn_s_setprio(0);
#pragma unroll
      for (int m = 0; m < 4; ++m)
        af[m] = *(const bf16x8*)(Ab + (wm * 128 + (m + 4) * 16 + ll) * 128 +
                                 ck[ks]);
      __builtin_amdgcn_s_setprio(1);
#pragma unroll
      for (int m = 0; m < 4; ++m)
#pragma unroll
        for (int n = 0; n < NR; ++n)
          acc[m + 4][n] = __builtin_amdgcn_mfma_f32_16x16x32_bf16(
              af[m], bf[n], acc[m + 4][n], 0, 0, 0);
      __builtin_amdgcn_s_setprio(0);
    }
  }

#pragma unroll
  for (int m = 0; m < 8; ++m) {
    int row = m0 + wm * 128 + m * 16 + lh * 4;
#pragma unroll
    for (int n = 0; n < NR; ++n) {
      int col = n0 + wn * (BN / 4) + n * 16 + ll;
      float bs = bias ? bias[col] : 0.f;
#pragma unroll
      for (int r = 0; r < 4; ++r) {
        float v = acc[m][n][r] + bs;
        if (act) v = v * 0.5f * (1.f + erff(v * 0.70710678118f));
        long cidx = (long)z * sC + (long)(row + r) * ldc + col;
        if (obf)
          ((__hip_bfloat16*)C)[cidx] = __float2bfloat16(v);
        else
          ((float*)C)[cidx] = v;
      }
    }
  }
}

// FFN2 finalize: OUT = sum_z PART[z] + b2 + X2. float4/thread, grid 4096.
__global__ __launch_bounds__(256) void ffn2_reduce(
    const float* __restrict__ P, const float* __restrict__ X2,
    const float* __restrict__ b2, float* __restrict__ OUT) {
  int i = blockIdx.x * 256 + threadIdx.x;
  const long SP = 4194304;
  float4 a = ((const float4*)P)[i];
  float4 b = ((const float4*)(P + SP))[i];
  float4 c = ((const float4*)(P + 2 * SP))[i];
  float4 d = ((const float4*)(P + 3 * SP))[i];
  float4 xr = ((const float4*)X2)[i];
  const float4 bb = *(const float4*)(b2 + ((i & 255) * 4));
  float4 o;
  o.x = a.x + b.x + c.x + d.x + xr.x + bb.x;
  o.y = a.y + b.y + c.y + d.y + xr.y + bb.y;
  o.z = a.z + b.z + c.z + d.z + xr.z + bb.z;
  o.w = a.w + b.w + c.w + d.w + xr.w + bb.w;
  ((float4*)OUT)[i] = o;
}

// ---------------------------------------------------------------------------
// bf16 MFMA GEMM (NT), 128x128 tile, BK=32, 4 waves. Double-buffered LDS,
// counted vmcnt(4) pipeline (round-11 structure). XCD swizzle.
// Split-K via z-packing: blockIdx.z = batch*ksplit + sk; K is per-split;
// bias/E1/E2 applied only on sk==0; partial sk writes C + sk*sSplit.
// pbc=1: C = E1 + 0.5*((A@Bt^T + bias) + E2[row>>9, col]).
// ---------------------------------------------------------------------------
__global__ __launch_bounds__(256) void gemm_bf16_nt(
    const __hip_bfloat16* __restrict__ A, const __hip_bfloat16* __restrict__ Bt,
    const float* __restrict__ bias, const float* __restrict__ E1,
    const float* __restrict__ E2, void* __restrict__ C, int K, int lda,
    int ldb, int ldc, long sA, long sB, long sC, long sE, float alpha, int act,
    int obf, int pbc, int ksplit, long sSplit) {
  __shared__ unsigned short AsU[2][128 * 32];
  __shared__ unsigned short BsU[2][128 * 32];
  const int tid = threadIdx.x;
  const int lane = tid & 63, wave = tid >> 6;
  const int wr = wave >> 1, wc = wave & 1;

  int nwg = gridDim.x * gridDim.y;
  int wg = blockIdx.y * gridDim.x + blockIdx.x;
  int bx = blockIdx.x, by = blockIdx.y;
  if ((nwg & 7) == 0) {
    int cpx = nwg >> 3;
    int sw = (wg & 7) * cpx + (wg >> 3);
    bx = sw % gridDim.x;
    by = sw / gridDim.x;
  }
  const int m0 = by * 128, n0 = bx * 128;
  const int bz = blockIdx.z / ksplit;
  const int sk = blockIdx.z % ksplit;
  if (sk != 0) { bias = nullptr; E1 = nullptr; E2 = nullptr; }
  const int kcol0 = sk * K;  // element offset of this split's K range
  const char* Ab = (const char*)(A + (long)bz * sA);
  const char* Bb = (const char*)(Bt + (long)bz * sB);

  f32x4 acc[4][4];
#pragma unroll
  for (int m = 0; m < 4; ++m)
#pragma unroll
    for (int n = 0; n < 4; ++n) acc[m][n] = (f32x4){0.f, 0.f, 0.f, 0.f};

  const int srow = tid >> 2;
  const int scol = (tid & 3) * 16;
  const int wbase = (tid >> 6) * 1024;

  auto stage = [&](int buf, int k0) {
    int kk = kcol0 + k0;
#pragma unroll
    for (int i = 0; i < 2; ++i) {
      async_copy16((char*)AsU[buf] + i * 4096 + wbase,
                   Ab + ((long)(m0 + i * 64 + srow) * lda + kk) * 2 + scol);
      async_copy16((char*)BsU[buf] + i * 4096 + wbase,
                   Bb + ((long)(n0 + i * 64 + srow) * ldb + kk) * 2 + scol);
    }
  };

  const int ntk = K >> 5;
  stage(0, 0);

  for (int t = 0; t < ntk; ++t) {
    const int bt = t & 1;
    SB0; BARRIER; SB0;  // (A) all waves done reading buffer bt^1
    if (t + 1 < ntk) {
      stage(bt ^ 1, (t + 1) * 32);
      asm volatile("s_waitcnt vmcnt(4)" ::: "memory");  // retire tile t only
    } else {
      asm volatile("s_waitcnt vmcnt(0)" ::: "memory");
    }
    SB0; BARRIER; SB0;  // (B) tile-t data visible to all waves

    const int koff = (lane >> 4) * 8;
    bf16x8 a[4], b[4];
#pragma unroll
    for (int m = 0; m < 4; ++m)
      a[m] = *(const bf16x8*)&AsU[bt][(wr * 64 + m * 16 + (lane & 15)) * 32 +
                                      koff];
#pragma unroll
    for (int n = 0; n < 4; ++n)
      b[n] = *(const bf16x8*)&BsU[bt][(wc * 64 + n * 16 + (lane & 15)) * 32 +
                                      koff];
    __builtin_amdgcn_s_setprio(1);
#pragma unroll
    for (int m = 0; m < 4; ++m)
#pragma unroll
      for (int n = 0; n < 4; ++n)
        acc[m][n] = __builtin_amdgcn_mfma_f32_16x16x32_bf16(a[m], b[n],
                                                            acc[m][n], 0, 0, 0);
    __builtin_amdgcn_s_setprio(0);
  }

#pragma unroll
  for (int m = 0; m < 4; ++m) {
    int row = m0 + wr * 64 + m * 16 + (lane >> 4) * 4;
#pragma unroll
    for (int n = 0; n < 4; ++n) {
      int col = n0 + wc * 64 + n * 16 + (lane & 15);
      float bs = bias ? bias[col] : 0.f;
#pragma unroll
      for (int r = 0; r < 4; ++r) {
        float v = (acc[m][n][r] + bs) * alpha;
        if (pbc) {
          v = E1[(long)(row + r) * ldc + col] +
              0.5f * (v + E2[(long)((row + r) >> 9) * 1024 + col]);
        } else {
          long eidx = (long)bz * sE + (long)(row + r) * ldc + col;
          if (E1) v += E1[eidx];
          if (E2) v += E2[eidx];
        }
        if (act) v = v * 0.5f * (1.f + erff(v * 0.70710678118f));
        long cidx = (long)bz * sC + (long)sk * sSplit +
                    (long)(row + r) * ldc + col;
        if (obf)
          ((__hip_bfloat16*)C)[cidx] = __float2bfloat16(v);
        else
          ((float*)C)[cidx] = v;
      }
    }
  }
}

// ---------------------------------------------------------------------------
// MFMA attention. Block = (i-tile of 32, h, b); 4 waves. Reads bias+mask raw.
// ---------------------------------------------------------------------------
__global__ __launch_bounds__(256) void attn_mfma(
    const __hip_bfloat16* __restrict__ Q, const __hip_bfloat16* __restrict__ K,
    const __hip_bfloat16* __restrict__ VT, const float* __restrict__ BiasP,
    const float* __restrict__ MaskP, __hip_bfloat16* __restrict__ O,
    int ldqk) {
  __shared__ __hip_bfloat16 P[32][520];
  __shared__ float red[2][32][4];
  const int it = blockIdx.x, h = blockIdx.y, b = blockIdx.z;
  const int i0 = it * 32;
  const int tid = threadIdx.x;
  const int lane = tid & 63, w = tid >> 6;
  const int lh = lane >> 4, ll = lane & 15;

  const long qkb = (long)b * 512 * ldqk + h * 64;

  bf16x8 a[2][2];
#pragma unroll
  for (int m = 0; m < 2; ++m)
#pragma unroll
    for (int ks = 0; ks < 2; ++ks)
      a[m][ks] = *(const bf16x8*)&Q[qkb + (long)(i0 + m * 16 + ll) * ldqk +
                                    ks * 32 + lh * 8];

  f32x4 acc[2][8];
#pragma unroll
  for (int m = 0; m < 2; ++m)
#pragma unroll
    for (int n = 0; n < 8; ++n) acc[m][n] = (f32x4){0.f, 0.f, 0.f, 0.f};

#pragma unroll
  for (int n = 0; n < 8; ++n) {
    const __hip_bfloat16* kp =
        &K[qkb + (long)(w * 128 + n * 16 + ll) * ldqk + lh * 8];
    bf16x8 b0 = *(const bf16x8*)&kp[0];
    bf16x8 b1 = *(const bf16x8*)&kp[32];
#pragma unroll
    for (int m = 0; m < 2; ++m) {
      acc[m][n] =
          __builtin_amdgcn_mfma_f32_16x16x32_bf16(a[m][0], b0, acc[m][n], 0, 0, 0);
      acc[m][n] =
          __builtin_amdgcn_mfma_f32_16x16x32_bf16(a[m][1], b1, acc[m][n], 0, 0, 0);
    }
  }

  const long bmo = ((long)b * 512 + i0) * 512 + w * 128;
#pragma unroll
  for (int m = 0; m < 2; ++m)
#pragma unroll
    for (int r = 0; r < 4; ++r) {
      int row = m * 16 + lh * 4 + r;
#pragma unroll
      for (int n = 0; n < 8; ++n) {
        long gi = bmo + (long)row * 512 + n * 16 + ll;
        acc[m][n][r] += BiasP[gi] + MaskP[gi];
      }
    }

  float rmax[2][4];
#pragma unroll
  for (int m = 0; m < 2; ++m)
#pragma unroll
    for (int r = 0; r < 4; ++r) {
      float v = acc[m][0][r];
#pragma unroll
      for (int n = 1; n < 8; ++n) v = fmaxf(v, acc[m][n][r]);
#pragma unroll
      for (int o = 1; o < 16; o <<= 1) v = fmaxf(v, __shfl_xor(v, o));
      rmax[m][r] = v;
    }
  if (ll == 0) {
#pragma unroll
    for (int m = 0; m < 2; ++m)
#pragma unroll
      for (int r = 0; r < 4; ++r) red[0][m * 16 + lh * 4 + r][w] = rmax[m][r];
  }
  __syncthreads();
#pragma unroll
  for (int m = 0; m < 2; ++m)
#pragma unroll
    for (int r = 0; r < 4; ++r) {
      const float* p = red[0][m * 16 + lh * 4 + r];
      rmax[m][r] = fmaxf(fmaxf(p[0], p[1]), fmaxf(p[2], p[3]));
    }
  float rsum[2][4];
#pragma unroll
  for (int m = 0; m < 2; ++m)
#pragma unroll
    for (int r = 0; r < 4; ++r) {
      float s = 0.f;
#pragma unroll
      for (int n = 0; n < 8; ++n) {
        float e = __expf(acc[m][n][r] - rmax[m][r]);
        acc[m][n][r] = e;
        s += e;
      }
#pragma unroll
      for (int o = 1; o < 16; o <<= 1) s += __shfl_xor(s, o);
      rsum[m][r] = s;
    }
  if (ll == 0) {
#pragma unroll
    for (int m = 0; m < 2; ++m)
#pragma unroll
      for (int r = 0; r < 4; ++r) red[1][m * 16 + lh * 4 + r][w] = rsum[m][r];
  }
  __syncthreads();
#pragma unroll
  for (int m = 0; m < 2; ++m)
#pragma unroll
    for (int r = 0; r < 4; ++r) {
      const float* p = red[1][m * 16 + lh * 4 + r];
      float inv = 1.f / (p[0] + p[1] + p[2] + p[3]);
      int row = m * 16 + lh * 4 + r;
#pragma unroll
      for (int n = 0; n < 8; ++n)
        P[row][w * 128 + n * 16 + ll] = __float2bfloat16(acc[m][n][r] * inv);
    }
  __syncthreads();

  const long vtb = ((long)b * 1024 + h * 64) * 512;
  const long ob = (long)b * 512 * 1024 + h * 64;
  const int mw = (w >> 1) * 16, nw = (w & 1) * 32;
  f32x4 oacc[2];
  oacc[0] = (f32x4){0.f, 0.f, 0.f, 0.f};
  oacc[1] = (f32x4){0.f, 0.f, 0.f, 0.f};
#pragma unroll
  for (int ks = 0; ks < 16; ++ks) {
    int k0 = ks * 32;
    bf16x8 pa = *(const bf16x8*)&P[mw + ll][k0 + lh * 8];
#pragma unroll
    for (int nf = 0; nf < 2; ++nf) {
      bf16x8 vb = *(const bf16x8*)&VT[vtb + (long)(nw + nf * 16 + ll) * 512 +
                                      k0 + lh * 8];
      oacc[nf] =
          __builtin_amdgcn_mfma_f32_16x16x32_bf16(pa, vb, oacc[nf], 0, 0, 0);
    }
  }
#pragma unroll
  for (int nf = 0; nf < 2; ++nf)
#pragma unroll
    for (int r = 0; r < 4; ++r)
      O[ob + (long)(i0 + mw + lh * 4 + r) * 1024 + nw + nf * 16 + ll] =
          __float2bfloat16(oacc[nf][r]);
}

// ---------------------------------------------------------------------------
// Row softmax over 512 of (P0[row] + P1[row]) -> bf16. One block per row.
// ---------------------------------------------------------------------------
__global__ __launch_bounds__(256) void softmax_rows2(
    const float* __restrict__ P0, const float* __restrict__ P1,
    __hip_bfloat16* __restrict__ Ob) {
  const float* r0 = P0 + (long)blockIdx.x * 512;
  const float* r1 = P1 + (long)blockIdx.x * 512;
  __hip_bfloat16* orow = Ob + (long)blockIdx.x * 512;
  int t = threadIdx.x;
  float v0 = r0[t] + r1[t], v1 = r0[t + 256] + r1[t + 256];
  float m = fmaxf(v0, v1);
#pragma unroll
  for (int o = 32; o; o >>= 1) m = fmaxf(m, __shfl_xor(m, o));
  __shared__ float red[8];
  int wid = t >> 6, lane = t & 63;
  if (!lane) red[wid] = m;
  __syncthreads();
  m = fmaxf(fmaxf(red[0], red[1]), fmaxf(red[2], red[3]));
  float e0 = __expf(v0 - m), e1 = __expf(v1 - m);
  float s = e0 + e1;
#pragma unroll
  for (int o = 32; o; o >>= 1) s += __shfl_xor(s, o);
  if (!lane) red[4 + wid] = s;
  __syncthreads();
  s = red[4] + red[5] + red[6] + red[7];
  float inv = 1.f / s;
  orow[t] = __float2bfloat16(e0 * inv);
  orow[t + 256] = __float2bfloat16(e1 * inv);
}

// ---------------------------------------------------------------------------
// path gather-mean partials + finalize.
// ---------------------------------------------------------------------------
__global__ __launch_bounds__(256) void path_partial(
    const float* __restrict__ xp, const int* __restrict__ pp,
    float* __restrict__ PP, float* __restrict__ WS) {
  int b = blockIdx.x, hc = blockIdx.y, ic = blockIdx.z;
  int h = hc * 256 + threadIdx.x;
  const int* ppb = pp + b * 512;
  const float* xb = xp + (long)b * 512 * 1024;
  int iA = ic * 64, iB = iA + 64;
  float acc = 0.f;
  for (int i = iA; i < iB; ++i) {
    if (ppb[i] != 1) continue;
    float cur = xb[(long)i * 1024 + h];
    float a;
    if (i == 0) {
      a = 0.5f * (cur + xb[1024 + h]);
    } else if (i == 1) {
      a = (xb[h] + cur + xb[2 * 1024 + h]) * (1.f / 3.f);
    } else {
      int inx = (i + 1 < 512) ? i + 1 : 511;
      float nx = xb[(long)inx * 1024 + h];
      if (ppb[i - 2] == 1) {
        a = 0.5f * (cur + nx);
      } else {
        a = (xb[(long)(i - 1) * 1024 + h] + cur + nx) * (1.f / 3.f);
      }
    }
    acc += a;
  }
  PP[((long)b * 8 + ic) * 1024 + h] = acc;
  if (hc == 0 && threadIdx.x == 0) {
    float c = 0.f;
    for (int i = iA; i < iB; ++i) c += (ppb[i] == 1) ? 1.f : 0.f;
    WS[b * 8 + ic] = c;
  }
}

__global__ __launch_bounds__(256) void path_finalize(
    const float* __restrict__ PP, const float* __restrict__ WS,
    float* __restrict__ PATH) {
  int b = blockIdx.x;
  int h = blockIdx.y * 256 + threadIdx.x;
  float s = 0.f, w = 0.f;
#pragma unroll
  for (int ic = 0; ic < 8; ++ic) {
    s += PP[((long)b * 8 + ic) * 1024 + h];
    w += WS[b * 8 + ic];
  }
  PATH[b * 1024 + h] = s / w;
}

// ---------------------------------------------------------------------------
extern "C" void kernel_launch(void* const* d_in, const int* in_sizes, int n_in,
                              void* d_out, int out_size, void* d_ws,
                              size_t ws_size, hipStream_t stream) {
  const float* x = (const float*)d_in[0];
  const int* pp = (const int*)d_in[1];
  const float* abias = (const float*)d_in[3];
  const float* amask = (const float*)d_in[4];
  const float* agraph = (const float*)d_in[5];
  const float* vgraph = (const float*)d_in[6];
  const float* ln1g = (const float*)d_in[7];
  const float* ln1b = (const float*)d_in[8];
  const float* wq = (const float*)d_in[9];
  const float* bq = (const float*)d_in[10];
  const float* wk = (const float*)d_in[11];
  const float* bk = (const float*)d_in[12];
  const float* wv = (const float*)d_in[13];
  const float* bv = (const float*)d_in[14];
  const float* wo = (const float*)d_in[15];
  const float* bo = (const float*)d_in[16];
  const float* pqw = (const float*)d_in[17];
  const float* pqb = (const float*)d_in[18];
  const float* pkw = (const float*)d_in[19];
  const float* pkb = (const float*)d_in[20];
  const float* pvw = (const float*)d_in[21];
  const float* pvb = (const float*)d_in[22];
  const float* ln2g = (const float*)d_in[23];
  const float* ln2b = (const float*)d_in[24];
  const float* w1 = (const float*)d_in[25];
  const float* b1 = (const float*)d_in[26];
  const float* w2 = (const float*)d_in[27];
  const float* b2 = (const float*)d_in[28];

  char* wsb = (char*)d_ws;
  auto Ybf = (__hip_bfloat16*)(wsb);                  // 0-8 (later Y2b)
  auto QKV = (__hip_bfloat16*)(wsb + (8l << 20));     // 8-56: [4096][6144]
  auto VTb = (__hip_bfloat16*)(wsb + (56l << 20));    // 56-64
  auto PVT = (__hip_bfloat16*)(wsb + (64l << 20));    // 64-72
  auto ATTb = (__hip_bfloat16*)(wsb + (72l << 20));   // 72-80 (later W2T)
  auto PATTb = (__hip_bfloat16*)(wsb + (88l << 20));  // 88-92
  auto PATTf = (float*)(wsb + (92l << 20));           // 92-100 (partial0)
  auto XP = (float*)(wsb + (92l << 20));              // 92-108
  auto WALL = (__hip_bfloat16*)(wsb + (108l << 20));  // 108-120: [6144][1024]
  auto WOT = (__hip_bfloat16*)(wsb + (120l << 20));   // 120-122
  auto W1T = (__hip_bfloat16*)(wsb + (122l << 20));   // 122-130
  auto bias6 = (float*)(wsb + (130l << 20));          // 24KB
  auto PPart = (float*)(wsb + (131l << 20));          // 256KB
  auto WSp = (float*)(wsb + (132l << 20));            // 256B
  auto PATH = (float*)(wsb + (133l << 20));           // 32KB
  auto X2 = (float*)(wsb + (24l << 20));              // 24-40 (QKV dead)
  auto HMID = (__hip_bfloat16*)(wsb + (40l << 20));   // 40-72
  auto W2T = ATTb;
  auto PART = (float*)(wsb + (92l << 20));            // 92-156 (4x16MB f32)
  __hip_bfloat16* Y2b = Ybf;
  float* OUT = (float*)d_out;

  const float qscale = 0.125f;
  const float pscale = 0.03125f;
  const long S2 = 512l * 512;
  const long SQ = 512l * 6144;
  const long SPLT = 8l * S2;  // 2,097,152 floats: path partial stride

  __hip_bfloat16* Qp = QKV;
  __hip_bfloat16* Kp = QKV + 1024;
  __hip_bfloat16* Vp = QKV + 2048;
  __hip_bfloat16* PQp = QKV + 3072;
  __hip_bfloat16* PKp = QKV + 4096;
  __hip_bfloat16* PVp = QKV + 5120;

  // 0) weight transposes + bias concat
  TC7 tp;
  tp.in[0] = wq;  tp.out[0] = WALL;                 tp.scale[0] = qscale;
  tp.in[1] = wk;  tp.out[1] = WALL + 1024 * 1024;   tp.scale[1] = 1.f;
  tp.in[2] = wv;  tp.out[2] = WALL + 2048 * 1024;   tp.scale[2] = 1.f;
  tp.in[3] = pqw; tp.out[3] = WALL + 3072 * 1024;   tp.scale[3] = pscale;
  tp.in[4] = pkw; tp.out[4] = WALL + 4096 * 1024;   tp.scale[4] = 1.f;
  tp.in[5] = pvw; tp.out[5] = WALL + 5120 * 1024;   tp.scale[5] = 1.f;
  tp.in[6] = wo;  tp.out[6] = WOT;                  tp.scale[6] = 1.f;
  tconv7<<<dim3(32, 32, 7), 256, 0, stream>>>(tp);
  tconv_f32_bf16<<<dim3(128, 32), 256, 0, stream>>>(w1, W1T, 1024, 4096);

  BC6 bp;
  bp.b[0] = bq;  bp.scale[0] = qscale;
  bp.b[1] = bk;  bp.scale[1] = 1.f;
  bp.b[2] = bv;  bp.scale[2] = 1.f;
  bp.b[3] = pqb; bp.scale[3] = pscale;
  bp.b[4] = pkb; bp.scale[4] = 1.f;
  bp.b[5] = pvb; bp.scale[5] = 1.f;
  bias_concat<<<24, 256, 0, stream>>>(bp, bias6);

  // 1) LN1 -> Ybf
  ln_rows_bf16<<<4096, 256, 0, stream>>>(x, ln1g, ln1b, Ybf);

  // 2) fused projections via gemm256<192>: 512 blocks = 2 exact CU rounds
  gemm256<192><<<dim3(32, 16, 1), 512, 0, stream>>>(
      Ybf, WALL, bias6, QKV, 1024, 1024, 1024, 6144, 0, 1, 0);

  // 3) transposes: V -> VT, PV -> PVT
  tconv_bf16<<<dim3(32, 16, 8), 256, 0, stream>>>(Vp, VTb, 512, 1024, 6144, SQ);
  tconv_bf16<<<dim3(32, 16, 8), 256, 0, stream>>>(PVp, PVT, 512, 1024, 6144, SQ);

  // 4) path scores split-K=2 (z = b*2+sk; 256 blocks) + softmax over partials
  gemm_bf16_nt<<<dim3(4, 4, 16), 256, 0, stream>>>(
      PQp, PKp, nullptr, agraph, vgraph, PATTf, 512, 6144, 6144, 512, SQ, SQ,
      S2, S2, 1.f, 0, 0, 0, 2, SPLT);
  softmax_rows2<<<4096, 256, 0, stream>>>(PATTf, PATTf + SPLT, PATTb);

  // 5) MFMA attention -> ATTb (reads bias + mask directly)
  attn_mfma<<<dim3(16, 16, 8), 256, 0, stream>>>(Qp, Kp, VTb, abias, amask,
                                                 ATTb, 6144);

  // 6) XP = PATT @ PVT^T
  gemm_bf16_nt<<<dim3(8, 4, 8), 256, 0, stream>>>(
      PATTb, PVT, nullptr, nullptr, nullptr, XP, 512, 512, 512, 1024, S2,
      512l * 1024, 512l * 1024, 0, 1.f, 0, 0, 0, 1, 0);

  // 7) path gather-mean
  path_partial<<<dim3(8, 4, 8), 256, 0, stream>>>(XP, pp, PPart, WSp);
  path_finalize<<<dim3(8, 4), 256, 0, stream>>>(PPart, WSp, PATH);

  // 8) fused: X2 = x + 0.5*((ATT@wo + bo) + PATH)  (pbc epilogue, f32 out)
  gemm_bf16_nt<<<dim3(8, 32, 1), 256, 0, stream>>>(
      ATTb, WOT, bo, x, PATH, X2, 1024, 1024, 1024, 1024, 0, 0, 0, 0, 1.f, 0,
      0, 1, 1, 0);

  // 8b) W2 transpose into ATTb's slot (ATTb now dead)
  tconv_f32_bf16<<<dim3(32, 128), 256, 0, stream>>>(w2, W2T, 4096, 1024);

  // 10) LN2 -> Y2b
  ln_rows_bf16<<<4096, 256, 0, stream>>>(X2, ln2g, ln2b, Y2b);

  // 11) FFN1 via gemm256<256>: M=4096, N=4096, GELU, bf16 out
  gemm256<256><<<dim3(16, 16, 1), 512, 0, stream>>>(
      Y2b, W1T, b1, HMID, 1024, 1024, 1024, 4096, 1, 1, 0);

  // 12) FFN2 split-K=4 via gemm256<256>: grid (4,16,4) = 256 blocks
  gemm256<256><<<dim3(4, 16, 4), 512, 0, stream>>>(
      HMID, W2T, nullptr, PART, 1024, 4096, 4096, 1024, 0, 0, 4194304);

  // 12b) OUT = sum_z PART[z] + b2 + X2
  ffn2_reduce<<<4096, 256, 0, stream>>>(PART, X2, b2, OUT);
}